// Round 4
// baseline (857.881 us; speedup 1.0000x reference)
//
#include <hip/hip_runtime.h>
#include <hip/hip_bf16.h>

#define N_NODES 50000
#define N_EDGES 800000
#define D_IN 64
#define NIN 144
#define N_CLASSES 128

// bf16 bit helpers (round-to-nearest-even pack, shift unpack)
__device__ __forceinline__ unsigned short f2b(float f) {
    unsigned u = __float_as_uint(f);
    return (unsigned short)((u + 0x7FFF + ((u >> 16) & 1)) >> 16);
}
__device__ __forceinline__ float b2f(unsigned short b) {
    return __uint_as_float(((unsigned)b) << 16);
}

// ---------------- CSR build ----------------

__global__ void k_hist(const int* __restrict__ dst, int* __restrict__ deg) {
    int e = blockIdx.x * 256 + threadIdx.x;
    if (e < N_EDGES) atomicAdd(&deg[dst[e]], 1);
}

// exclusive scan of deg[0..N) in place, off[N]=E. single block, 1024 threads.
__global__ void k_scan(int* __restrict__ off) {
    __shared__ int part[1024];
    int t = threadIdx.x;
    const int chunk = (N_NODES + 1023) / 1024;  // 49
    int beg = t * chunk; if (beg > N_NODES) beg = N_NODES;
    int end = beg + chunk; if (end > N_NODES) end = N_NODES;
    int s = 0;
    for (int i = beg; i < end; ++i) s += off[i];
    part[t] = s;
    __syncthreads();
    for (int d = 1; d < 1024; d <<= 1) {
        int v = (t >= d) ? part[t - d] : 0;
        __syncthreads();
        part[t] += v;
        __syncthreads();
    }
    int run = (t == 0) ? 0 : part[t - 1];
    for (int i = beg; i < end; ++i) { int c = off[i]; off[i] = run; run += c; }
    if (t == 1023) off[N_NODES] = part[1023];   // == N_EDGES
}

// pack src (16 bits, N<65536) + edge weight (bf16) into one u32 per edge
__global__ void k_place(const int* __restrict__ src, const int* __restrict__ dst,
                        const float* __restrict__ ea,
                        const int* __restrict__ off, int* __restrict__ cnt,
                        unsigned* __restrict__ epack) {
    int e = blockIdx.x * 256 + threadIdx.x;
    if (e < N_EDGES) {
        int d = dst[e];
        int p = off[d] + atomicAdd(&cnt[d], 1);
        epack[p] = (((unsigned)f2b(ea[e])) << 16) | (unsigned)src[e];
    }
}

// ---------------- block-1 dense branches (in=64) ----------------
// writes: hL[n,0:64) relu-branch | xw[n,0:64) spect pre-agg (bf16) | hR[n,0:16) product

__global__ __launch_bounds__(256) void k_dense1(
    const float* __restrict__ x,
    const float* __restrict__ W11, const float* __restrict__ b11,
    const float* __restrict__ Wc1,
    const float* __restrict__ W12, const float* __restrict__ b12,
    const float* __restrict__ W13, const float* __restrict__ b13,
    float* __restrict__ hL, float* __restrict__ hR,
    unsigned short* __restrict__ xwb) {
    __shared__ float xs[16 * 64];
    int tid = threadIdx.x;
    int nb = blockIdx.x * 16;
    for (int i = tid; i < 16 * 64; i += 256) xs[i] = x[nb * 64 + i];
    __syncthreads();
    for (int task = tid; task < 16 * 144; task += 256) {
        int nl = task / 144;
        int j  = task - nl * 144;
        int n  = nb + nl;
        const float* xr = &xs[nl * 64];
        if (j < 64) {
            float a = 0.f;
            #pragma unroll
            for (int k = 0; k < 64; ++k) a += xr[k] * W11[k * 64 + j];
            hL[n * 128 + j] = fmaxf(a + b11[j], 0.f);
        } else if (j < 128) {
            int jj = j - 64;
            float a = 0.f;
            #pragma unroll
            for (int k = 0; k < 64; ++k) a += xr[k] * Wc1[k * 64 + jj];
            xwb[n * 64 + jj] = f2b(a);
        } else {
            int jj = j - 128;
            float a = 0.f, b = 0.f;
            #pragma unroll
            for (int k = 0; k < 64; ++k) {
                float xv = xr[k];
                a += xv * W12[k * 16 + jj];
                b += xv * W13[k * 16 + jj];
            }
            hR[n * 16 + jj] = fmaxf(a + b12[jj], 0.f) * fmaxf(b + b13[jj], 0.f);
        }
    }
}

// ---------------- aggregation: wave per dst node, lane = feature ----------------

__global__ __launch_bounds__(256) void k_agg(
    const unsigned short* __restrict__ xwb, const int* __restrict__ off,
    const unsigned* __restrict__ epack,
    const float* __restrict__ bc, float* __restrict__ hL) {
    int node = blockIdx.x * 4 + (threadIdx.x >> 6);
    int lane = threadIdx.x & 63;
    if (node >= N_NODES) return;
    int b = off[node], e = off[node + 1];
    float acc = 0.f;
    for (int i = b; i < e; ++i) {
        unsigned u = epack[i];
        acc += b2f((unsigned short)(u >> 16)) * b2f(xwb[(u & 0xFFFFu) * 64 + lane]);
    }
    hL[node * 128 + 64 + lane] = fmaxf(acc + bc[lane], 0.f);
}

// ---------------- block-2 dense branches (in=144) ----------------
// in-place safe: block stages its own 16 rows fully before writing them

__global__ __launch_bounds__(256) void k_dense2(
    const float* __restrict__ hLin, const float* __restrict__ hRin,
    const float* __restrict__ W21, const float* __restrict__ b21,
    const float* __restrict__ Wc2,
    const float* __restrict__ W22, const float* __restrict__ b22,
    const float* __restrict__ W23, const float* __restrict__ b23,
    float* __restrict__ hL, float* __restrict__ hR,
    unsigned short* __restrict__ xwb) {
    __shared__ float hs[16 * 144];
    int tid = threadIdx.x;
    int nb = blockIdx.x * 16;
    for (int i = tid; i < 16 * 144; i += 256) {
        int nl = i / 144, k = i - nl * 144;
        hs[i] = (k < 128) ? hLin[(nb + nl) * 128 + k] : hRin[(nb + nl) * 16 + (k - 128)];
    }
    __syncthreads();
    for (int task = tid; task < 16 * 144; task += 256) {
        int nl = task / 144;
        int j  = task - nl * 144;
        int n  = nb + nl;
        const float* xr = &hs[nl * 144];
        if (j < 64) {
            float a = 0.f;
            for (int k = 0; k < 144; ++k) a += xr[k] * W21[k * 64 + j];
            hL[n * 128 + j] = fmaxf(a + b21[j], 0.f);
        } else if (j < 128) {
            int jj = j - 64;
            float a = 0.f;
            for (int k = 0; k < 144; ++k) a += xr[k] * Wc2[k * 64 + jj];
            xwb[n * 64 + jj] = f2b(a);
        } else {
            int jj = j - 128;
            float a = 0.f, b = 0.f;
            for (int k = 0; k < 144; ++k) {
                float xv = xr[k];
                a += xv * W22[k * 16 + jj];
                b += xv * W23[k * 16 + jj];
            }
            hR[n * 16 + jj] = fmaxf(a + b22[jj], 0.f) * fmaxf(b + b23[jj], 0.f);
        }
    }
}

// ---------------- classifier + log_softmax (f32 output) ----------------
// Wf staged in LDS as bf16 (40 KB total LDS); out == hL is safe: each row is
// fully read into LDS before its overwrite, per-block rows disjoint.

__global__ __launch_bounds__(256) void k_cls(
    const float* __restrict__ hL, const float* __restrict__ hR,
    const float* __restrict__ Wf, const float* __restrict__ bfb,
    float* __restrict__ out) {
    __shared__ unsigned short wfs[NIN * N_CLASSES];  // 36864 B
    __shared__ float rows[4][NIN];
    __shared__ float bfl[N_CLASSES];
    int tid = threadIdx.x;
    for (int i = tid; i < NIN * N_CLASSES; i += 256) wfs[i] = f2b(Wf[i]);
    if (tid < N_CLASSES) bfl[tid] = bfb[tid];
    __syncthreads();
    int wave = tid >> 6, lane = tid & 63;
    for (int it = 0; it < 8; ++it) {
        int node = blockIdx.x * 32 + it * 4 + wave;
        if (node < N_NODES) {
            for (int k = lane; k < 128; k += 64) rows[wave][k] = hL[node * 128 + k];
            if (lane < 16) rows[wave][128 + lane] = hR[node * 16 + lane];
        }
        __syncthreads();
        if (node < N_NODES) {
            float a0 = bfl[lane], a1 = bfl[64 + lane];
            for (int k = 0; k < NIN; ++k) {
                float hv = rows[wave][k];
                a0 += hv * b2f(wfs[k * N_CLASSES + lane]);
                a1 += hv * b2f(wfs[k * N_CLASSES + 64 + lane]);
            }
            float m = fmaxf(a0, a1);
            for (int o = 1; o < 64; o <<= 1) m = fmaxf(m, __shfl_xor(m, o));
            float s = __expf(a0 - m) + __expf(a1 - m);
            for (int o = 1; o < 64; o <<= 1) s += __shfl_xor(s, o);
            float ls = __logf(s) + m;
            out[node * N_CLASSES + lane]      = a0 - ls;
            out[node * N_CLASSES + 64 + lane] = a1 - ls;
        }
        __syncthreads();
    }
}

// ---------------- launch ----------------

extern "C" void kernel_launch(void* const* d_in, const int* in_sizes, int n_in,
                              void* d_out, int out_size, void* d_ws, size_t ws_size,
                              hipStream_t stream) {
    const float* x   = (const float*)d_in[0];
    const int*   ei  = (const int*)d_in[1];      // [2, E] int32 (proven rounds 1-3)
    const float* ea  = (const float*)d_in[2];
    const float* Wc1 = (const float*)d_in[3];
    const float* bc1 = (const float*)d_in[4];
    const float* Wc2 = (const float*)d_in[5];
    const float* bc2 = (const float*)d_in[6];
    const float* W11 = (const float*)d_in[7];
    const float* b11 = (const float*)d_in[8];
    const float* W12 = (const float*)d_in[9];
    const float* b12 = (const float*)d_in[10];
    const float* W13 = (const float*)d_in[11];
    const float* b13 = (const float*)d_in[12];
    const float* W21 = (const float*)d_in[13];
    const float* b21 = (const float*)d_in[14];
    const float* W22 = (const float*)d_in[15];
    const float* b22 = (const float*)d_in[16];
    const float* W23 = (const float*)d_in[17];
    const float* b23 = (const float*)d_in[18];
    const float* Wf  = (const float*)d_in[19];
    const float* bfb = (const float*)d_in[20];

    const int* esrc = ei;
    const int* edst = ei + N_EDGES;

    // hL[N,128] f32 lives in d_out (25.6 MB, write-before-read every call).
    float* hL = (float*)d_out;

    // compact workspace: 12.6 MiB total
    int*            off   = (int*)d_ws;                       // N+1
    int*            cnt   = off + (N_NODES + 1);              // N
    unsigned*       epack = (unsigned*)(cnt + N_NODES);       // E
    unsigned short* xwb   = (unsigned short*)(epack + N_EDGES); // N*64 bf16
    float*          hR    = (float*)(xwb + (size_t)N_NODES * 64); // N*16 f32

    hipMemsetAsync(off, 0, (size_t)(2 * N_NODES + 1) * sizeof(int), stream);
    k_hist <<<(N_EDGES + 255) / 256, 256, 0, stream>>>(edst, off);
    k_scan <<<1, 1024, 0, stream>>>(off);
    k_place<<<(N_EDGES + 255) / 256, 256, 0, stream>>>(esrc, edst, ea, off, cnt, epack);

    k_dense1<<<N_NODES / 16, 256, 0, stream>>>(x, W11, b11, Wc1, W12, b12, W13, b13, hL, hR, xwb);
    k_agg   <<<N_NODES / 4, 256, 0, stream>>>(xwb, off, epack, bc1, hL);
    k_dense2<<<N_NODES / 16, 256, 0, stream>>>(hL, hR, W21, b21, Wc2, W22, b22, W23, b23, hL, hR, xwb);
    k_agg   <<<N_NODES / 4, 256, 0, stream>>>(xwb, off, epack, bc2, hL);
    k_cls   <<<(N_NODES + 31) / 32, 256, 0, stream>>>(hL, hR, Wf, bfb, (float*)d_out);
}

// Round 5
// 588.683 us; speedup vs baseline: 1.4573x; 1.4573x over previous
//
#include <hip/hip_runtime.h>
#include <hip/hip_bf16.h>

#define N_NODES 50000
#define N_EDGES 800000
#define D_IN 64
#define NIN 144
#define N_CLASSES 128

// bf16 bit helpers (round-to-nearest-even pack, shift unpack)
__device__ __forceinline__ unsigned short f2b(float f) {
    unsigned u = __float_as_uint(f);
    return (unsigned short)((u + 0x7FFF + ((u >> 16) & 1)) >> 16);
}
__device__ __forceinline__ float b2f(unsigned short b) {
    return __uint_as_float(((unsigned)b) << 16);
}

// ---------------- CSR build ----------------

__global__ void k_hist(const int* __restrict__ dst, int* __restrict__ deg) {
    int e = blockIdx.x * 256 + threadIdx.x;
    if (e < N_EDGES) atomicAdd(&deg[dst[e]], 1);
}

__global__ void k_scan(int* __restrict__ off) {
    __shared__ int part[1024];
    int t = threadIdx.x;
    const int chunk = (N_NODES + 1023) / 1024;  // 49
    int beg = t * chunk; if (beg > N_NODES) beg = N_NODES;
    int end = beg + chunk; if (end > N_NODES) end = N_NODES;
    int s = 0;
    for (int i = beg; i < end; ++i) s += off[i];
    part[t] = s;
    __syncthreads();
    for (int d = 1; d < 1024; d <<= 1) {
        int v = (t >= d) ? part[t - d] : 0;
        __syncthreads();
        part[t] += v;
        __syncthreads();
    }
    int run = (t == 0) ? 0 : part[t - 1];
    for (int i = beg; i < end; ++i) { int c = off[i]; off[i] = run; run += c; }
    if (t == 1023) off[N_NODES] = part[1023];
}

__global__ void k_place(const int* __restrict__ src, const int* __restrict__ dst,
                        const float* __restrict__ ea,
                        const int* __restrict__ off, int* __restrict__ cnt,
                        unsigned* __restrict__ epack) {
    int e = blockIdx.x * 256 + threadIdx.x;
    if (e < N_EDGES) {
        int d = dst[e];
        int p = off[d] + atomicAdd(&cnt[d], 1);
        epack[p] = (((unsigned)f2b(ea[e])) << 16) | (unsigned)src[e];
    }
}

// ---------------- register-blocked dense layer 1 (K=64, 160 out cols) ----------------
// 320 threads; tile 64 nodes; micro-tile 4 nodes x 8 cols per thread.
// cols 0-63: relu(x@W11+b11) -> hL[:,0:64); 64-127: x@Wc1 -> xwb bf16;
// 128-143: relu(x@W12+b12); 144-159: relu(x@W13+b13); product -> hR.

__global__ __launch_bounds__(320) void k_dense1(
    const float* __restrict__ x,
    const float* __restrict__ W11, const float* __restrict__ b11,
    const float* __restrict__ Wc1,
    const float* __restrict__ W12, const float* __restrict__ b12,
    const float* __restrict__ W13, const float* __restrict__ b13,
    float* __restrict__ hL, float* __restrict__ hR,
    unsigned short* __restrict__ xwb) {
    __shared__ float At[64 * 68];    // A^T [k][node], pad 68
    __shared__ float Wl[16 * 160];   // weight chunk [kk][col]
    __shared__ float Ps[2 * 64 * 16];
    int t = threadIdx.x;
    int nb = blockIdx.x * 64;
    for (int i = t; i < 64 * 64; i += 320) {
        int n = i >> 6, k = i & 63;
        int gn = nb + n;
        At[k * 68 + n] = (gn < N_NODES) ? x[gn * 64 + k] : 0.f;
    }
    int tr = t / 20, tc = t - tr * 20;
    int n0 = tr * 4, j0 = tc * 8;
    float bias[8];
    #pragma unroll
    for (int j = 0; j < 8; ++j) {
        int col = j0 + j;
        bias[j] = (col < 64) ? b11[col]
                : (col < 128) ? 0.f
                : (col < 144) ? b12[col - 128] : b13[col - 144];
    }
    float acc[4][8];
    #pragma unroll
    for (int i = 0; i < 4; ++i)
        #pragma unroll
        for (int j = 0; j < 8; ++j) acc[i][j] = 0.f;

    for (int k0 = 0; k0 < 64; k0 += 16) {
        __syncthreads();
        for (int i = t; i < 16 * 160; i += 320) {
            int kk = i / 160, j = i - kk * 160;
            int gk = k0 + kk;
            float w = (j < 64) ? W11[gk * 64 + j]
                    : (j < 128) ? Wc1[gk * 64 + (j - 64)]
                    : (j < 144) ? W12[gk * 16 + (j - 128)]
                                : W13[gk * 16 + (j - 144)];
            Wl[kk * 160 + j] = w;
        }
        __syncthreads();
        #pragma unroll
        for (int kk = 0; kk < 16; ++kk) {
            int k = k0 + kk;
            float4 a  = *(const float4*)&At[k * 68 + n0];
            float4 b0 = *(const float4*)&Wl[kk * 160 + j0];
            float4 b1 = *(const float4*)&Wl[kk * 160 + j0 + 4];
            float av[4] = {a.x, a.y, a.z, a.w};
            float bv[8] = {b0.x, b0.y, b0.z, b0.w, b1.x, b1.y, b1.z, b1.w};
            #pragma unroll
            for (int i = 0; i < 4; ++i)
                #pragma unroll
                for (int j = 0; j < 8; ++j) acc[i][j] += av[i] * bv[j];
        }
    }
    // epilogue
    if (j0 < 64) {
        #pragma unroll
        for (int i = 0; i < 4; ++i) {
            int gn = nb + n0 + i;
            if (gn < N_NODES) {
                float4 o0, o1;
                o0.x = fmaxf(acc[i][0] + bias[0], 0.f); o0.y = fmaxf(acc[i][1] + bias[1], 0.f);
                o0.z = fmaxf(acc[i][2] + bias[2], 0.f); o0.w = fmaxf(acc[i][3] + bias[3], 0.f);
                o1.x = fmaxf(acc[i][4] + bias[4], 0.f); o1.y = fmaxf(acc[i][5] + bias[5], 0.f);
                o1.z = fmaxf(acc[i][6] + bias[6], 0.f); o1.w = fmaxf(acc[i][7] + bias[7], 0.f);
                *(float4*)&hL[gn * 128 + j0]     = o0;
                *(float4*)&hL[gn * 128 + j0 + 4] = o1;
            }
        }
    } else if (j0 < 128) {
        #pragma unroll
        for (int i = 0; i < 4; ++i) {
            int gn = nb + n0 + i;
            if (gn < N_NODES) {
                #pragma unroll
                for (int j = 0; j < 8; ++j)
                    xwb[gn * 64 + (j0 - 64) + j] = f2b(acc[i][j]);
            }
        }
    } else {
        int sel = (j0 < 144) ? 0 : 1;
        int jb = j0 - 128 - sel * 16;
        #pragma unroll
        for (int i = 0; i < 4; ++i)
            #pragma unroll
            for (int j = 0; j < 8; ++j)
                Ps[(sel * 64 + n0 + i) * 16 + jb + j] = fmaxf(acc[i][j] + bias[j], 0.f);
    }
    __syncthreads();
    for (int task = t; task < 64 * 16; task += 320) {
        int n = task >> 4, jj = task & 15;
        int gn = nb + n;
        if (gn < N_NODES) hR[gn * 16 + jj] = Ps[n * 16 + jj] * Ps[(64 + n) * 16 + jj];
    }
}

// ---------------- register-blocked dense layer 2 (K=144, 160 out cols) ----------------

__global__ __launch_bounds__(320) void k_dense2(
    const float* __restrict__ hLin, const float* __restrict__ hRin,
    const float* __restrict__ W21, const float* __restrict__ b21,
    const float* __restrict__ Wc2,
    const float* __restrict__ W22, const float* __restrict__ b22,
    const float* __restrict__ W23, const float* __restrict__ b23,
    float* __restrict__ hL, float* __restrict__ hR,
    unsigned short* __restrict__ xwb) {
    __shared__ float At[144 * 68];   // 39168 B
    __shared__ float Wl[16 * 160];   // 10240 B
    __shared__ float Ps[2 * 64 * 16];// 8192 B
    int t = threadIdx.x;
    int nb = blockIdx.x * 64;
    for (int i = t; i < 64 * 144; i += 320) {
        int n = i / 144, k = i - n * 144;
        int gn = nb + n;
        float v = 0.f;
        if (gn < N_NODES) v = (k < 128) ? hLin[gn * 128 + k] : hRin[gn * 16 + (k - 128)];
        At[k * 68 + n] = v;
    }
    int tr = t / 20, tc = t - tr * 20;
    int n0 = tr * 4, j0 = tc * 8;
    float bias[8];
    #pragma unroll
    for (int j = 0; j < 8; ++j) {
        int col = j0 + j;
        bias[j] = (col < 64) ? b21[col]
                : (col < 128) ? 0.f
                : (col < 144) ? b22[col - 128] : b23[col - 144];
    }
    float acc[4][8];
    #pragma unroll
    for (int i = 0; i < 4; ++i)
        #pragma unroll
        for (int j = 0; j < 8; ++j) acc[i][j] = 0.f;

    for (int k0 = 0; k0 < 144; k0 += 16) {
        __syncthreads();
        for (int i = t; i < 16 * 160; i += 320) {
            int kk = i / 160, j = i - kk * 160;
            int gk = k0 + kk;
            float w = (j < 64) ? W21[gk * 64 + j]
                    : (j < 128) ? Wc2[gk * 64 + (j - 64)]
                    : (j < 144) ? W22[gk * 16 + (j - 128)]
                                : W23[gk * 16 + (j - 144)];
            Wl[kk * 160 + j] = w;
        }
        __syncthreads();
        #pragma unroll
        for (int kk = 0; kk < 16; ++kk) {
            int k = k0 + kk;
            float4 a  = *(const float4*)&At[k * 68 + n0];
            float4 b0 = *(const float4*)&Wl[kk * 160 + j0];
            float4 b1 = *(const float4*)&Wl[kk * 160 + j0 + 4];
            float av[4] = {a.x, a.y, a.z, a.w};
            float bv[8] = {b0.x, b0.y, b0.z, b0.w, b1.x, b1.y, b1.z, b1.w};
            #pragma unroll
            for (int i = 0; i < 4; ++i)
                #pragma unroll
                for (int j = 0; j < 8; ++j) acc[i][j] += av[i] * bv[j];
        }
    }
    if (j0 < 64) {
        #pragma unroll
        for (int i = 0; i < 4; ++i) {
            int gn = nb + n0 + i;
            if (gn < N_NODES) {
                float4 o0, o1;
                o0.x = fmaxf(acc[i][0] + bias[0], 0.f); o0.y = fmaxf(acc[i][1] + bias[1], 0.f);
                o0.z = fmaxf(acc[i][2] + bias[2], 0.f); o0.w = fmaxf(acc[i][3] + bias[3], 0.f);
                o1.x = fmaxf(acc[i][4] + bias[4], 0.f); o1.y = fmaxf(acc[i][5] + bias[5], 0.f);
                o1.z = fmaxf(acc[i][6] + bias[6], 0.f); o1.w = fmaxf(acc[i][7] + bias[7], 0.f);
                *(float4*)&hL[gn * 128 + j0]     = o0;
                *(float4*)&hL[gn * 128 + j0 + 4] = o1;
            }
        }
    } else if (j0 < 128) {
        #pragma unroll
        for (int i = 0; i < 4; ++i) {
            int gn = nb + n0 + i;
            if (gn < N_NODES) {
                #pragma unroll
                for (int j = 0; j < 8; ++j)
                    xwb[gn * 64 + (j0 - 64) + j] = f2b(acc[i][j]);
            }
        }
    } else {
        int sel = (j0 < 144) ? 0 : 1;
        int jb = j0 - 128 - sel * 16;
        #pragma unroll
        for (int i = 0; i < 4; ++i)
            #pragma unroll
            for (int j = 0; j < 8; ++j)
                Ps[(sel * 64 + n0 + i) * 16 + jb + j] = fmaxf(acc[i][j] + bias[j], 0.f);
    }
    __syncthreads();
    for (int task = t; task < 64 * 16; task += 320) {
        int n = task >> 4, jj = task & 15;
        int gn = nb + n;
        if (gn < N_NODES) hR[gn * 16 + jj] = Ps[n * 16 + jj] * Ps[(64 + n) * 16 + jj];
    }
}

// ---------------- aggregation: wave per dst node, 2 edges/iter ----------------

__global__ __launch_bounds__(256) void k_agg(
    const unsigned short* __restrict__ xwb, const int* __restrict__ off,
    const unsigned* __restrict__ epack,
    const float* __restrict__ bc, float* __restrict__ hL) {
    int node = blockIdx.x * 4 + (threadIdx.x >> 6);
    int lane = threadIdx.x & 63;
    if (node >= N_NODES) return;
    const unsigned* xw32 = (const unsigned*)xwb;
    int b = off[node], e = off[node + 1];
    int half = lane >> 5;
    int c = lane & 31;
    float acc0 = 0.f, acc1 = 0.f;
    for (int i = b + half; i < e; i += 2) {
        unsigned u = epack[i];
        float ew = b2f((unsigned short)(u >> 16));
        unsigned wv = xw32[(u & 0xFFFFu) * 32 + c];
        acc0 += ew * b2f((unsigned short)(wv & 0xFFFFu));
        acc1 += ew * b2f((unsigned short)(wv >> 16));
    }
    acc0 += __shfl_xor(acc0, 32);
    acc1 += __shfl_xor(acc1, 32);
    if (half == 0) {
        int f0 = 2 * c;
        float2 o;
        o.x = fmaxf(acc0 + bc[f0], 0.f);
        o.y = fmaxf(acc1 + bc[f0 + 1], 0.f);
        *(float2*)&hL[node * 128 + 64 + f0] = o;
    }
}

// ---------------- classifier GEMM + log_softmax (f32, Wf in LDS chunks) ----------------
// 256 threads; tile 64 nodes x 128 cols; micro 4x8. Logits staged into the
// (dead) At buffer, then wave-per-node softmax. out == hL safe: block reads
// only its own rows, fully staged before overwrite.

__global__ __launch_bounds__(256) void k_cls(
    const float* __restrict__ hL, const float* __restrict__ hR,
    const float* __restrict__ Wf, const float* __restrict__ bfb,
    float* __restrict__ out) {
    __shared__ float At[144 * 68];   // 39168 B ; reused as logits Ls[64][128]
    __shared__ float Wl[8 * 128];    // 4096 B
    int t = threadIdx.x;
    int nb = blockIdx.x * 64;
    for (int i = t; i < 64 * 144; i += 256) {
        int n = i / 144, k = i - n * 144;
        int gn = nb + n;
        float v = 0.f;
        if (gn < N_NODES) v = (k < 128) ? hL[gn * 128 + k] : hR[gn * 16 + (k - 128)];
        At[k * 68 + n] = v;
    }
    int tr = t >> 4, tc = t & 15;
    int n0 = tr * 4, j0 = tc * 8;
    float bias[8];
    #pragma unroll
    for (int j = 0; j < 8; ++j) bias[j] = bfb[j0 + j];
    float acc[4][8];
    #pragma unroll
    for (int i = 0; i < 4; ++i)
        #pragma unroll
        for (int j = 0; j < 8; ++j) acc[i][j] = 0.f;

    for (int k0 = 0; k0 < 144; k0 += 8) {
        __syncthreads();
        for (int i = t; i < 8 * 128; i += 256) {
            int kk = i >> 7, j = i & 127;
            Wl[i] = Wf[(k0 + kk) * 128 + j];
        }
        __syncthreads();
        #pragma unroll
        for (int kk = 0; kk < 8; ++kk) {
            int k = k0 + kk;
            float4 a  = *(const float4*)&At[k * 68 + n0];
            float4 b0 = *(const float4*)&Wl[kk * 128 + j0];
            float4 b1 = *(const float4*)&Wl[kk * 128 + j0 + 4];
            float av[4] = {a.x, a.y, a.z, a.w};
            float bv[8] = {b0.x, b0.y, b0.z, b0.w, b1.x, b1.y, b1.z, b1.w};
            #pragma unroll
            for (int i = 0; i < 4; ++i)
                #pragma unroll
                for (int j = 0; j < 8; ++j) acc[i][j] += av[i] * bv[j];
        }
    }
    __syncthreads();   // all At reads done; reuse as logits
    float* Ls = At;
    #pragma unroll
    for (int i = 0; i < 4; ++i)
        #pragma unroll
        for (int j = 0; j < 8; ++j)
            Ls[(n0 + i) * 128 + j0 + j] = acc[i][j] + bias[j];
    __syncthreads();
    int wave = t >> 6, lane = t & 63;
    for (int rep = 0; rep < 16; ++rep) {
        int nl = wave * 16 + rep;
        int gn = nb + nl;
        if (gn < N_NODES) {
            float v0 = Ls[nl * 128 + lane];
            float v1 = Ls[nl * 128 + 64 + lane];
            float m = fmaxf(v0, v1);
            for (int o = 1; o < 64; o <<= 1) m = fmaxf(m, __shfl_xor(m, o));
            float s = __expf(v0 - m) + __expf(v1 - m);
            for (int o = 1; o < 64; o <<= 1) s += __shfl_xor(s, o);
            float ls = __logf(s) + m;
            out[gn * 128 + lane]      = v0 - ls;
            out[gn * 128 + 64 + lane] = v1 - ls;
        }
    }
}

// ---------------- launch ----------------

extern "C" void kernel_launch(void* const* d_in, const int* in_sizes, int n_in,
                              void* d_out, int out_size, void* d_ws, size_t ws_size,
                              hipStream_t stream) {
    const float* x   = (const float*)d_in[0];
    const int*   ei  = (const int*)d_in[1];
    const float* ea  = (const float*)d_in[2];
    const float* Wc1 = (const float*)d_in[3];
    const float* bc1 = (const float*)d_in[4];
    const float* Wc2 = (const float*)d_in[5];
    const float* bc2 = (const float*)d_in[6];
    const float* W11 = (const float*)d_in[7];
    const float* b11 = (const float*)d_in[8];
    const float* W12 = (const float*)d_in[9];
    const float* b12 = (const float*)d_in[10];
    const float* W13 = (const float*)d_in[11];
    const float* b13 = (const float*)d_in[12];
    const float* W21 = (const float*)d_in[13];
    const float* b21 = (const float*)d_in[14];
    const float* W22 = (const float*)d_in[15];
    const float* b22 = (const float*)d_in[16];
    const float* W23 = (const float*)d_in[17];
    const float* b23 = (const float*)d_in[18];
    const float* Wf  = (const float*)d_in[19];
    const float* bfb = (const float*)d_in[20];

    const int* esrc = ei;
    const int* edst = ei + N_EDGES;

    float* hL = (float*)d_out;   // [N,128] f32 scratch in d_out (write-before-read)

    int*            off   = (int*)d_ws;                           // N+1
    int*            cnt   = off + (N_NODES + 1);                  // N
    unsigned*       epack = (unsigned*)(cnt + N_NODES);           // E
    unsigned short* xwb   = (unsigned short*)(epack + N_EDGES);   // N*64 bf16
    float*          hR    = (float*)(xwb + (size_t)N_NODES * 64); // N*16 f32

    hipMemsetAsync(off, 0, (size_t)(2 * N_NODES + 1) * sizeof(int), stream);
    k_hist <<<(N_EDGES + 255) / 256, 256, 0, stream>>>(edst, off);
    k_scan <<<1, 1024, 0, stream>>>(off);
    k_place<<<(N_EDGES + 255) / 256, 256, 0, stream>>>(esrc, edst, ea, off, cnt, epack);

    const int GD = (N_NODES + 63) / 64;   // 782
    k_dense1<<<GD, 320, 0, stream>>>(x, W11, b11, Wc1, W12, b12, W13, b13, hL, hR, xwb);
    k_agg   <<<(N_NODES + 3) / 4, 256, 0, stream>>>(xwb, off, epack, bc1, hL);
    k_dense2<<<GD, 320, 0, stream>>>(hL, hR, W21, b21, Wc2, W22, b22, W23, b23, hL, hR, xwb);
    k_agg   <<<(N_NODES + 3) / 4, 256, 0, stream>>>(xwb, off, epack, bc2, hL);
    k_cls   <<<GD, 256, 0, stream>>>(hL, hR, Wf, bfb, (float*)d_out);
}

// Round 6
// 471.199 us; speedup vs baseline: 1.8206x; 1.2493x over previous
//
#include <hip/hip_runtime.h>
#include <hip/hip_bf16.h>

#define N_NODES 50000
#define N_EDGES 800000
#define D_IN 64
#define NIN 144
#define N_CLASSES 128

// bf16 bit helpers (round-to-nearest-even pack, shift unpack)
__device__ __forceinline__ unsigned short f2b(float f) {
    unsigned u = __float_as_uint(f);
    return (unsigned short)((u + 0x7FFF + ((u >> 16) & 1)) >> 16);
}
__device__ __forceinline__ float b2f(unsigned short b) {
    return __uint_as_float(((unsigned)b) << 16);
}

// ---------------- CSR build ----------------

__global__ void k_hist(const int* __restrict__ dst, int* __restrict__ deg) {
    int e = blockIdx.x * 256 + threadIdx.x;
    if (e < N_EDGES) atomicAdd(&deg[dst[e]], 1);
}

__global__ void k_scan(int* __restrict__ off) {
    __shared__ int part[1024];
    int t = threadIdx.x;
    const int chunk = (N_NODES + 1023) / 1024;  // 49
    int beg = t * chunk; if (beg > N_NODES) beg = N_NODES;
    int end = beg + chunk; if (end > N_NODES) end = N_NODES;
    int s = 0;
    for (int i = beg; i < end; ++i) s += off[i];
    part[t] = s;
    __syncthreads();
    for (int d = 1; d < 1024; d <<= 1) {
        int v = (t >= d) ? part[t - d] : 0;
        __syncthreads();
        part[t] += v;
        __syncthreads();
    }
    int run = (t == 0) ? 0 : part[t - 1];
    for (int i = beg; i < end; ++i) { int c = off[i]; off[i] = run; run += c; }
    if (t == 1023) off[N_NODES] = part[1023];
}

__global__ void k_place(const int* __restrict__ src, const int* __restrict__ dst,
                        const float* __restrict__ ea,
                        const int* __restrict__ off, int* __restrict__ cnt,
                        unsigned* __restrict__ epack) {
    int e = blockIdx.x * 256 + threadIdx.x;
    if (e < N_EDGES) {
        int d = dst[e];
        int p = off[d] + atomicAdd(&cnt[d], 1);
        epack[p] = (((unsigned)f2b(ea[e])) << 16) | (unsigned)src[e];
    }
}

// ---------------- register-blocked dense layer 1 (K=64, 160 out cols) ----------------
// 320 threads; tile 64 nodes; micro 4 nodes x 8 cols; tr = t&15 (node grp),
// tc = t>>4 (col grp) -> wave-internal LDS reads are broadcast / contiguous.
// K staged in 16-chunks: LDS = 4.3 + 10.2 + 8.2 KB -> ~4 blocks/CU.

__global__ __launch_bounds__(320) void k_dense1(
    const float* __restrict__ x,
    const float* __restrict__ W11, const float* __restrict__ b11,
    const float* __restrict__ Wc1,
    const float* __restrict__ W12, const float* __restrict__ b12,
    const float* __restrict__ W13, const float* __restrict__ b13,
    float* __restrict__ hL, float* __restrict__ hR,
    unsigned short* __restrict__ xwb) {
    __shared__ float As[16 * 68];
    __shared__ float Wl[16 * 160];
    __shared__ float Ps[2 * 64 * 16];
    int t = threadIdx.x;
    int nb = blockIdx.x * 64;
    int tr = t & 15, tc = t >> 4;      // tc in [0,20)
    int n0 = tr * 4, j0 = tc * 8;
    float bias[8];
    #pragma unroll
    for (int j = 0; j < 8; ++j) {
        int col = j0 + j;
        bias[j] = (col < 64) ? b11[col]
                : (col < 128) ? 0.f
                : (col < 144) ? b12[col - 128] : b13[col - 144];
    }
    float acc[4][8];
    #pragma unroll
    for (int i = 0; i < 4; ++i)
        #pragma unroll
        for (int j = 0; j < 8; ++j) acc[i][j] = 0.f;

    for (int k0 = 0; k0 < 64; k0 += 16) {
        __syncthreads();
        for (int i = t; i < 64 * 16; i += 320) {
            int n = i >> 4, kk = i & 15;
            int gn = nb + n;
            As[kk * 68 + n] = (gn < N_NODES) ? x[gn * 64 + k0 + kk] : 0.f;
        }
        for (int i = t; i < 16 * 160; i += 320) {
            int kk = i / 160, j = i - kk * 160;
            int gk = k0 + kk;
            Wl[i] = (j < 64) ? W11[gk * 64 + j]
                  : (j < 128) ? Wc1[gk * 64 + (j - 64)]
                  : (j < 144) ? W12[gk * 16 + (j - 128)]
                              : W13[gk * 16 + (j - 144)];
        }
        __syncthreads();
        #pragma unroll
        for (int kk = 0; kk < 16; ++kk) {
            float4 a  = *(const float4*)&As[kk * 68 + n0];
            float4 b0 = *(const float4*)&Wl[kk * 160 + j0];
            float4 b1 = *(const float4*)&Wl[kk * 160 + j0 + 4];
            float av[4] = {a.x, a.y, a.z, a.w};
            float bv[8] = {b0.x, b0.y, b0.z, b0.w, b1.x, b1.y, b1.z, b1.w};
            #pragma unroll
            for (int i = 0; i < 4; ++i)
                #pragma unroll
                for (int j = 0; j < 8; ++j) acc[i][j] += av[i] * bv[j];
        }
    }
    if (j0 < 64) {
        #pragma unroll
        for (int i = 0; i < 4; ++i) {
            int gn = nb + n0 + i;
            if (gn < N_NODES) {
                float4 o0, o1;
                o0.x = fmaxf(acc[i][0] + bias[0], 0.f); o0.y = fmaxf(acc[i][1] + bias[1], 0.f);
                o0.z = fmaxf(acc[i][2] + bias[2], 0.f); o0.w = fmaxf(acc[i][3] + bias[3], 0.f);
                o1.x = fmaxf(acc[i][4] + bias[4], 0.f); o1.y = fmaxf(acc[i][5] + bias[5], 0.f);
                o1.z = fmaxf(acc[i][6] + bias[6], 0.f); o1.w = fmaxf(acc[i][7] + bias[7], 0.f);
                *(float4*)&hL[gn * 128 + j0]     = o0;
                *(float4*)&hL[gn * 128 + j0 + 4] = o1;
            }
        }
    } else if (j0 < 128) {
        #pragma unroll
        for (int i = 0; i < 4; ++i) {
            int gn = nb + n0 + i;
            if (gn < N_NODES) {
                #pragma unroll
                for (int j = 0; j < 8; ++j)
                    xwb[gn * 64 + (j0 - 64) + j] = f2b(acc[i][j]);
            }
        }
    } else {
        int sel = (j0 < 144) ? 0 : 1;
        int jb = j0 - 128 - sel * 16;
        #pragma unroll
        for (int i = 0; i < 4; ++i)
            #pragma unroll
            for (int j = 0; j < 8; ++j)
                Ps[(sel * 64 + n0 + i) * 16 + jb + j] = fmaxf(acc[i][j] + bias[j], 0.f);
    }
    __syncthreads();
    for (int task = t; task < 64 * 16; task += 320) {
        int n = task >> 4, jj = task & 15;
        int gn = nb + n;
        if (gn < N_NODES) hR[gn * 16 + jj] = Ps[n * 16 + jj] * Ps[(64 + n) * 16 + jj];
    }
}

// ---------------- register-blocked dense layer 2 (K=144, 160 out cols) ----------------

__global__ __launch_bounds__(320) void k_dense2(
    const float* __restrict__ hLin, const float* __restrict__ hRin,
    const float* __restrict__ W21, const float* __restrict__ b21,
    const float* __restrict__ Wc2,
    const float* __restrict__ W22, const float* __restrict__ b22,
    const float* __restrict__ W23, const float* __restrict__ b23,
    float* __restrict__ hL, float* __restrict__ hR,
    unsigned short* __restrict__ xwb) {
    __shared__ float As[16 * 68];
    __shared__ float Wl[16 * 160];
    __shared__ float Ps[2 * 64 * 16];
    int t = threadIdx.x;
    int nb = blockIdx.x * 64;
    int tr = t & 15, tc = t >> 4;
    int n0 = tr * 4, j0 = tc * 8;
    float bias[8];
    #pragma unroll
    for (int j = 0; j < 8; ++j) {
        int col = j0 + j;
        bias[j] = (col < 64) ? b21[col]
                : (col < 128) ? 0.f
                : (col < 144) ? b22[col - 128] : b23[col - 144];
    }
    float acc[4][8];
    #pragma unroll
    for (int i = 0; i < 4; ++i)
        #pragma unroll
        for (int j = 0; j < 8; ++j) acc[i][j] = 0.f;

    for (int k0 = 0; k0 < 144; k0 += 16) {
        __syncthreads();
        for (int i = t; i < 64 * 16; i += 320) {
            int n = i >> 4, kk = i & 15;
            int gn = nb + n;
            int k = k0 + kk;
            float v = 0.f;
            if (gn < N_NODES) v = (k < 128) ? hLin[gn * 128 + k] : hRin[gn * 16 + (k - 128)];
            As[kk * 68 + n] = v;
        }
        for (int i = t; i < 16 * 160; i += 320) {
            int kk = i / 160, j = i - kk * 160;
            int gk = k0 + kk;
            Wl[i] = (j < 64) ? W21[gk * 64 + j]
                  : (j < 128) ? Wc2[gk * 64 + (j - 64)]
                  : (j < 144) ? W22[gk * 16 + (j - 128)]
                              : W23[gk * 16 + (j - 144)];
        }
        __syncthreads();
        #pragma unroll
        for (int kk = 0; kk < 16; ++kk) {
            float4 a  = *(const float4*)&As[kk * 68 + n0];
            float4 b0 = *(const float4*)&Wl[kk * 160 + j0];
            float4 b1 = *(const float4*)&Wl[kk * 160 + j0 + 4];
            float av[4] = {a.x, a.y, a.z, a.w};
            float bv[8] = {b0.x, b0.y, b0.z, b0.w, b1.x, b1.y, b1.z, b1.w};
            #pragma unroll
            for (int i = 0; i < 4; ++i)
                #pragma unroll
                for (int j = 0; j < 8; ++j) acc[i][j] += av[i] * bv[j];
        }
    }
    if (j0 < 64) {
        #pragma unroll
        for (int i = 0; i < 4; ++i) {
            int gn = nb + n0 + i;
            if (gn < N_NODES) {
                float4 o0, o1;
                o0.x = fmaxf(acc[i][0] + bias[0], 0.f); o0.y = fmaxf(acc[i][1] + bias[1], 0.f);
                o0.z = fmaxf(acc[i][2] + bias[2], 0.f); o0.w = fmaxf(acc[i][3] + bias[3], 0.f);
                o1.x = fmaxf(acc[i][4] + bias[4], 0.f); o1.y = fmaxf(acc[i][5] + bias[5], 0.f);
                o1.z = fmaxf(acc[i][6] + bias[6], 0.f); o1.w = fmaxf(acc[i][7] + bias[7], 0.f);
                *(float4*)&hL[gn * 128 + j0]     = o0;
                *(float4*)&hL[gn * 128 + j0 + 4] = o1;
            }
        }
    } else if (j0 < 128) {
        #pragma unroll
        for (int i = 0; i < 4; ++i) {
            int gn = nb + n0 + i;
            if (gn < N_NODES) {
                #pragma unroll
                for (int j = 0; j < 8; ++j)
                    xwb[gn * 64 + (j0 - 64) + j] = f2b(acc[i][j]);
            }
        }
    } else {
        int sel = (j0 < 144) ? 0 : 1;
        int jb = j0 - 128 - sel * 16;
        #pragma unroll
        for (int i = 0; i < 4; ++i)
            #pragma unroll
            for (int j = 0; j < 8; ++j)
                Ps[(sel * 64 + n0 + i) * 16 + jb + j] = fmaxf(acc[i][j] + bias[j], 0.f);
    }
    __syncthreads();
    for (int task = t; task < 64 * 16; task += 320) {
        int n = task >> 4, jj = task & 15;
        int gn = nb + n;
        if (gn < N_NODES) hR[gn * 16 + jj] = Ps[n * 16 + jj] * Ps[(64 + n) * 16 + jj];
    }
}

// ---------------- aggregation: wave per dst node, 2 edges/iter ----------------

__global__ __launch_bounds__(256) void k_agg(
    const unsigned short* __restrict__ xwb, const int* __restrict__ off,
    const unsigned* __restrict__ epack,
    const float* __restrict__ bc, float* __restrict__ hL) {
    int node = blockIdx.x * 4 + (threadIdx.x >> 6);
    int lane = threadIdx.x & 63;
    if (node >= N_NODES) return;
    const unsigned* xw32 = (const unsigned*)xwb;
    int b = off[node], e = off[node + 1];
    int half = lane >> 5;
    int c = lane & 31;
    float acc0 = 0.f, acc1 = 0.f;
    for (int i = b + half; i < e; i += 2) {
        unsigned u = epack[i];
        float ew = b2f((unsigned short)(u >> 16));
        unsigned wv = xw32[(u & 0xFFFFu) * 32 + c];
        acc0 += ew * b2f((unsigned short)(wv & 0xFFFFu));
        acc1 += ew * b2f((unsigned short)(wv >> 16));
    }
    acc0 += __shfl_xor(acc0, 32);
    acc1 += __shfl_xor(acc1, 32);
    if (half == 0) {
        int f0 = 2 * c;
        float2 o;
        o.x = fmaxf(acc0 + bc[f0], 0.f);
        o.y = fmaxf(acc1 + bc[f0 + 1], 0.f);
        *(float2*)&hL[node * 128 + 64 + f0] = o;
    }
}

// ---------------- classifier GEMM + log_softmax ----------------
// 256 threads (16x16 micro-map), K chunks of 8; logits in padded LDS Ls[64][132].
// out == hL safe: block reads only its own rows (during chunk staging), writes
// only after all reads.

__global__ __launch_bounds__(256) void k_cls(
    const float* __restrict__ hL, const float* __restrict__ hR,
    const float* __restrict__ Wf, const float* __restrict__ bfb,
    float* __restrict__ out) {
    __shared__ float As[8 * 68];      // 2176 B
    __shared__ float Wl[8 * 128];     // 4096 B
    __shared__ float Ls[64 * 132];    // 33792 B
    int t = threadIdx.x;
    int nb = blockIdx.x * 64;
    int tr = t & 15, tc = t >> 4;     // 16 x 16
    int n0 = tr * 4, j0 = tc * 8;
    float bias[8];
    #pragma unroll
    for (int j = 0; j < 8; ++j) bias[j] = bfb[j0 + j];
    float acc[4][8];
    #pragma unroll
    for (int i = 0; i < 4; ++i)
        #pragma unroll
        for (int j = 0; j < 8; ++j) acc[i][j] = 0.f;

    for (int k0 = 0; k0 < 144; k0 += 8) {
        __syncthreads();
        for (int i = t; i < 64 * 8; i += 256) {
            int n = i >> 3, kk = i & 7;
            int gn = nb + n;
            int k = k0 + kk;
            float v = 0.f;
            if (gn < N_NODES) v = (k < 128) ? hL[gn * 128 + k] : hR[gn * 16 + (k - 128)];
            As[kk * 68 + n] = v;
        }
        for (int i = t; i < 8 * 128; i += 256) {
            int kk = i >> 7, j = i & 127;
            Wl[i] = Wf[(k0 + kk) * 128 + j];
        }
        __syncthreads();
        #pragma unroll
        for (int kk = 0; kk < 8; ++kk) {
            float4 a  = *(const float4*)&As[kk * 68 + n0];
            float4 b0 = *(const float4*)&Wl[kk * 128 + j0];
            float4 b1 = *(const float4*)&Wl[kk * 128 + j0 + 4];
            float av[4] = {a.x, a.y, a.z, a.w};
            float bv[8] = {b0.x, b0.y, b0.z, b0.w, b1.x, b1.y, b1.z, b1.w};
            #pragma unroll
            for (int i = 0; i < 4; ++i)
                #pragma unroll
                for (int j = 0; j < 8; ++j) acc[i][j] += av[i] * bv[j];
        }
    }
    __syncthreads();
    #pragma unroll
    for (int i = 0; i < 4; ++i) {
        float4 o0, o1;
        o0.x = acc[i][0] + bias[0]; o0.y = acc[i][1] + bias[1];
        o0.z = acc[i][2] + bias[2]; o0.w = acc[i][3] + bias[3];
        o1.x = acc[i][4] + bias[4]; o1.y = acc[i][5] + bias[5];
        o1.z = acc[i][6] + bias[6]; o1.w = acc[i][7] + bias[7];
        *(float4*)&Ls[(n0 + i) * 132 + j0]     = o0;
        *(float4*)&Ls[(n0 + i) * 132 + j0 + 4] = o1;
    }
    __syncthreads();
    int wave = t >> 6, lane = t & 63;
    for (int rep = 0; rep < 16; ++rep) {
        int nl = wave * 16 + rep;
        int gn = nb + nl;
        if (gn < N_NODES) {
            float v0 = Ls[nl * 132 + lane];
            float v1 = Ls[nl * 132 + 64 + lane];
            float m = fmaxf(v0, v1);
            for (int o = 1; o < 64; o <<= 1) m = fmaxf(m, __shfl_xor(m, o));
            float s = __expf(v0 - m) + __expf(v1 - m);
            for (int o = 1; o < 64; o <<= 1) s += __shfl_xor(s, o);
            float ls = __logf(s) + m;
            out[gn * 128 + lane]      = v0 - ls;
            out[gn * 128 + 64 + lane] = v1 - ls;
        }
    }
}

// ---------------- launch ----------------

extern "C" void kernel_launch(void* const* d_in, const int* in_sizes, int n_in,
                              void* d_out, int out_size, void* d_ws, size_t ws_size,
                              hipStream_t stream) {
    const float* x   = (const float*)d_in[0];
    const int*   ei  = (const int*)d_in[1];
    const float* ea  = (const float*)d_in[2];
    const float* Wc1 = (const float*)d_in[3];
    const float* bc1 = (const float*)d_in[4];
    const float* Wc2 = (const float*)d_in[5];
    const float* bc2 = (const float*)d_in[6];
    const float* W11 = (const float*)d_in[7];
    const float* b11 = (const float*)d_in[8];
    const float* W12 = (const float*)d_in[9];
    const float* b12 = (const float*)d_in[10];
    const float* W13 = (const float*)d_in[11];
    const float* b13 = (const float*)d_in[12];
    const float* W21 = (const float*)d_in[13];
    const float* b21 = (const float*)d_in[14];
    const float* W22 = (const float*)d_in[15];
    const float* b22 = (const float*)d_in[16];
    const float* W23 = (const float*)d_in[17];
    const float* b23 = (const float*)d_in[18];
    const float* Wf  = (const float*)d_in[19];
    const float* bfb = (const float*)d_in[20];

    const int* esrc = ei;
    const int* edst = ei + N_EDGES;

    float* hL = (float*)d_out;   // [N,128] f32 scratch in d_out (write-before-read)

    int*            off   = (int*)d_ws;                           // N+1
    int*            cnt   = off + (N_NODES + 1);                  // N
    unsigned*       epack = (unsigned*)(cnt + N_NODES);           // E
    unsigned short* xwb   = (unsigned short*)(epack + N_EDGES);   // N*64 bf16
    float*          hR    = (float*)(xwb + (size_t)N_NODES * 64); // N*16 f32

    hipMemsetAsync(off, 0, (size_t)(2 * N_NODES + 1) * sizeof(int), stream);
    k_hist <<<(N_EDGES + 255) / 256, 256, 0, stream>>>(edst, off);
    k_scan <<<1, 1024, 0, stream>>>(off);
    k_place<<<(N_EDGES + 255) / 256, 256, 0, stream>>>(esrc, edst, ea, off, cnt, epack);

    const int GD = (N_NODES + 63) / 64;   // 782
    k_dense1<<<GD, 320, 0, stream>>>(x, W11, b11, Wc1, W12, b12, W13, b13, hL, hR, xwb);
    k_agg   <<<(N_NODES + 3) / 4, 256, 0, stream>>>(xwb, off, epack, bc1, hL);
    k_dense2<<<GD, 320, 0, stream>>>(hL, hR, W21, b21, Wc2, W22, b22, W23, b23, hL, hR, xwb);
    k_agg   <<<(N_NODES + 3) / 4, 256, 0, stream>>>(xwb, off, epack, bc2, hL);
    k_cls   <<<GD, 256, 0, stream>>>(hL, hR, Wf, bfb, (float*)d_out);
}

// Round 7
// 434.874 us; speedup vs baseline: 1.9727x; 1.0835x over previous
//
#include <hip/hip_runtime.h>
#include <hip/hip_bf16.h>

#define N_NODES 50000
#define N_EDGES 800000
#define D_IN 64
#define NIN 144
#define N_CLASSES 128

// bf16 bit helpers (round-to-nearest-even pack, shift unpack)
__device__ __forceinline__ unsigned short f2b(float f) {
    unsigned u = __float_as_uint(f);
    return (unsigned short)((u + 0x7FFF + ((u >> 16) & 1)) >> 16);
}
__device__ __forceinline__ float b2f(unsigned short b) {
    return __uint_as_float(((unsigned)b) << 16);
}

// ---------------- CSR build ----------------

__global__ void k_hist(const int* __restrict__ dst, int* __restrict__ deg) {
    int e = blockIdx.x * 256 + threadIdx.x;
    if (e < N_EDGES) atomicAdd(&deg[dst[e]], 1);
}

__global__ void k_scan(int* __restrict__ off) {
    __shared__ int part[1024];
    int t = threadIdx.x;
    const int chunk = (N_NODES + 1023) / 1024;  // 49
    int beg = t * chunk; if (beg > N_NODES) beg = N_NODES;
    int end = beg + chunk; if (end > N_NODES) end = N_NODES;
    int s = 0;
    for (int i = beg; i < end; ++i) s += off[i];
    part[t] = s;
    __syncthreads();
    for (int d = 1; d < 1024; d <<= 1) {
        int v = (t >= d) ? part[t - d] : 0;
        __syncthreads();
        part[t] += v;
        __syncthreads();
    }
    int run = (t == 0) ? 0 : part[t - 1];
    for (int i = beg; i < end; ++i) { int c = off[i]; off[i] = run; run += c; }
    if (t == 1023) off[N_NODES] = part[1023];
}

__global__ void k_place(const int* __restrict__ src, const int* __restrict__ dst,
                        const float* __restrict__ ea,
                        const int* __restrict__ off, int* __restrict__ cnt,
                        unsigned* __restrict__ epack) {
    int e = blockIdx.x * 256 + threadIdx.x;
    if (e < N_EDGES) {
        int d = dst[e];
        int p = off[d] + atomicAdd(&cnt[d], 1);
        epack[p] = (((unsigned)f2b(ea[e])) << 16) | (unsigned)src[e];
    }
}

// ---------------- pipelined register-blocked dense (K=64 or 144, 160 cols) ----------------
// 320 threads; tile 32 nodes; micro 2 nodes x 8 cols (tr=t&15 node grp, tc=t>>4 col grp).
// K chunks of 16, software-pipelined: prefetch chunk c+1 into regs while computing c.
// LDS ~16.6 KB. Grid 1563 -> ~6 blocks/CU.

template<int K>
__global__ __launch_bounds__(320) void k_dense(
    const float* __restrict__ inL, const float* __restrict__ inR,
    const float* __restrict__ W1, const float* __restrict__ b1,
    const float* __restrict__ Wc,
    const float* __restrict__ W2, const float* __restrict__ b2,
    const float* __restrict__ W3, const float* __restrict__ b3,
    float* __restrict__ hL, float* __restrict__ hR,
    unsigned short* __restrict__ xwb) {
    __shared__ float As[16 * 36];     // 2304 B  [kk][node]
    __shared__ float Wl[16 * 160];    // 10240 B [kk][col]
    __shared__ float Ps[2 * 32 * 16]; // 4096 B
    constexpr int NC = K / 16;
    int t = threadIdx.x;
    int nb = blockIdx.x * 32;
    int tr = t & 15, tc = t >> 4;     // tc in [0,20)
    int n0 = tr * 2, j0 = tc * 8;

    float bias[8];
    #pragma unroll
    for (int j = 0; j < 8; ++j) {
        int col = j0 + j;
        bias[j] = (col < 64) ? b1[col]
                : (col < 128) ? 0.f
                : (col < 144) ? b2[col - 128] : b3[col - 144];
    }
    float acc[2][8];
    #pragma unroll
    for (int i = 0; i < 2; ++i)
        #pragma unroll
        for (int j = 0; j < 8; ++j) acc[i][j] = 0.f;

    float areg[2], wreg[8];
    auto loadA = [&](int c) {
        #pragma unroll
        for (int r = 0; r < 2; ++r) {
            int i = t + r * 320;
            float v = 0.f;
            if (i < 512) {
                int n = i >> 4, kk = i & 15;
                int gn = nb + n, k = c * 16 + kk;
                if (gn < N_NODES) {
                    if constexpr (K == 64) v = inL[gn * 64 + k];
                    else v = (k < 128) ? inL[gn * 128 + k] : inR[gn * 16 + (k - 128)];
                }
            }
            areg[r] = v;
        }
    };
    auto loadW = [&](int c) {
        #pragma unroll
        for (int r = 0; r < 8; ++r) {
            int i = t + r * 320;
            int kk = i / 160, j = i - kk * 160;
            int gk = c * 16 + kk;
            wreg[r] = (j < 64) ? W1[gk * 64 + j]
                    : (j < 128) ? Wc[gk * 64 + (j - 64)]
                    : (j < 144) ? W2[gk * 16 + (j - 128)]
                                : W3[gk * 16 + (j - 144)];
        }
    };
    auto store = [&]() {
        #pragma unroll
        for (int r = 0; r < 2; ++r) {
            int i = t + r * 320;
            if (i < 512) { int n = i >> 4, kk = i & 15; As[kk * 36 + n] = areg[r]; }
        }
        #pragma unroll
        for (int r = 0; r < 8; ++r) Wl[t + r * 320] = wreg[r];   // flat == [kk][col]
    };

    loadA(0); loadW(0);
    store();
    __syncthreads();
    for (int c = 0; c < NC; ++c) {
        if (c + 1 < NC) { loadA(c + 1); loadW(c + 1); }
        #pragma unroll
        for (int kk = 0; kk < 16; ++kk) {
            float2 a   = *(const float2*)&As[kk * 36 + n0];
            float4 b0v = *(const float4*)&Wl[kk * 160 + j0];
            float4 b1v = *(const float4*)&Wl[kk * 160 + j0 + 4];
            float bv[8] = {b0v.x, b0v.y, b0v.z, b0v.w, b1v.x, b1v.y, b1v.z, b1v.w};
            #pragma unroll
            for (int j = 0; j < 8; ++j) {
                acc[0][j] += a.x * bv[j];
                acc[1][j] += a.y * bv[j];
            }
        }
        __syncthreads();
        if (c + 1 < NC) { store(); __syncthreads(); }
    }

    if (j0 < 64) {
        #pragma unroll
        for (int i = 0; i < 2; ++i) {
            int gn = nb + n0 + i;
            if (gn < N_NODES) {
                float4 o0, o1;
                o0.x = fmaxf(acc[i][0] + bias[0], 0.f); o0.y = fmaxf(acc[i][1] + bias[1], 0.f);
                o0.z = fmaxf(acc[i][2] + bias[2], 0.f); o0.w = fmaxf(acc[i][3] + bias[3], 0.f);
                o1.x = fmaxf(acc[i][4] + bias[4], 0.f); o1.y = fmaxf(acc[i][5] + bias[5], 0.f);
                o1.z = fmaxf(acc[i][6] + bias[6], 0.f); o1.w = fmaxf(acc[i][7] + bias[7], 0.f);
                *(float4*)&hL[gn * 128 + j0]     = o0;
                *(float4*)&hL[gn * 128 + j0 + 4] = o1;
            }
        }
    } else if (j0 < 128) {
        #pragma unroll
        for (int i = 0; i < 2; ++i) {
            int gn = nb + n0 + i;
            if (gn < N_NODES) {
                #pragma unroll
                for (int j = 0; j < 8; ++j)
                    xwb[gn * 64 + (j0 - 64) + j] = f2b(acc[i][j]);
            }
        }
    } else {
        int sel = (j0 < 144) ? 0 : 1;
        int jb = j0 - 128 - sel * 16;
        #pragma unroll
        for (int i = 0; i < 2; ++i)
            #pragma unroll
            for (int j = 0; j < 8; ++j)
                Ps[(sel * 32 + n0 + i) * 16 + jb + j] = fmaxf(acc[i][j] + bias[j], 0.f);
    }
    __syncthreads();
    for (int task = t; task < 32 * 16; task += 320) {
        int n = task >> 4, jj = task & 15;
        int gn = nb + n;
        if (gn < N_NODES) hR[gn * 16 + jj] = Ps[n * 16 + jj] * Ps[(32 + n) * 16 + jj];
    }
}

// ---------------- aggregation: wave per dst node, 4 edges/iter ----------------
// quarter q handles edge b+iter*4+q; 16 lanes x uint2 (4 bf16 feats) per edge.

__global__ __launch_bounds__(256) void k_agg(
    const unsigned short* __restrict__ xwb, const int* __restrict__ off,
    const unsigned* __restrict__ epack,
    const float* __restrict__ bc, float* __restrict__ hL) {
    int node = blockIdx.x * 4 + (threadIdx.x >> 6);
    int lane = threadIdx.x & 63;
    if (node >= N_NODES) return;
    const uint2* xw64 = (const uint2*)xwb;   // 16 uint2 per node row
    int b = off[node], e = off[node + 1];
    int q = lane >> 4, c = lane & 15;
    float a0 = 0.f, a1 = 0.f, a2 = 0.f, a3 = 0.f;
    for (int i = b + q; i < e; i += 4) {
        unsigned u = epack[i];
        float ew = b2f((unsigned short)(u >> 16));
        uint2 wv = xw64[(u & 0xFFFFu) * 16 + c];
        a0 += ew * b2f((unsigned short)(wv.x & 0xFFFFu));
        a1 += ew * b2f((unsigned short)(wv.x >> 16));
        a2 += ew * b2f((unsigned short)(wv.y & 0xFFFFu));
        a3 += ew * b2f((unsigned short)(wv.y >> 16));
    }
    a0 += __shfl_xor(a0, 16); a0 += __shfl_xor(a0, 32);
    a1 += __shfl_xor(a1, 16); a1 += __shfl_xor(a1, 32);
    a2 += __shfl_xor(a2, 16); a2 += __shfl_xor(a2, 32);
    a3 += __shfl_xor(a3, 16); a3 += __shfl_xor(a3, 32);
    if (q == 0) {
        int f0 = 4 * c;
        float4 bv = *(const float4*)&bc[f0];
        float4 o;
        o.x = fmaxf(a0 + bv.x, 0.f);
        o.y = fmaxf(a1 + bv.y, 0.f);
        o.z = fmaxf(a2 + bv.z, 0.f);
        o.w = fmaxf(a3 + bv.w, 0.f);
        *(float4*)&hL[node * 128 + 64 + f0] = o;
    }
}

// ---------------- classifier GEMM + log_softmax (pipelined, logits in regs) ----------------
// 256 threads; tile 32 nodes; micro 2x8; K chunks of 16 pipelined.
// Softmax via 32x16 max/sum LDS reductions; out written from regs.
// out == hL safe: block reads only its own 32 rows (all chunk loads precede
// epilogue), writes only its own rows.

__global__ __launch_bounds__(256) void k_cls(
    const float* __restrict__ hL, const float* __restrict__ hR,
    const float* __restrict__ Wf, const float* __restrict__ bfb,
    float* __restrict__ out) {
    __shared__ float As[16 * 36];     // 2304 B
    __shared__ float Wl[16 * 128];    // 8192 B
    __shared__ float Mred[32 * 16];   // 2048 B
    __shared__ float Sred[32 * 16];   // 2048 B
    int t = threadIdx.x;
    int nb = blockIdx.x * 32;
    int tr = t & 15, tc = t >> 4;     // 16 x 16
    int n0 = tr * 2, j0 = tc * 8;
    float bias[8];
    #pragma unroll
    for (int j = 0; j < 8; ++j) bias[j] = bfb[j0 + j];
    float acc[2][8];
    #pragma unroll
    for (int i = 0; i < 2; ++i)
        #pragma unroll
        for (int j = 0; j < 8; ++j) acc[i][j] = 0.f;

    float areg[2], wreg[8];
    auto loadA = [&](int c) {
        #pragma unroll
        for (int r = 0; r < 2; ++r) {
            int i = t + r * 256;
            int n = i >> 4, kk = i & 15;
            int gn = nb + n, k = c * 16 + kk;
            float v = 0.f;
            if (gn < N_NODES) v = (k < 128) ? hL[gn * 128 + k] : hR[gn * 16 + (k - 128)];
            areg[r] = v;
        }
    };
    auto loadW = [&](int c) {
        #pragma unroll
        for (int r = 0; r < 8; ++r) {
            int i = t + r * 256;
            int kk = i >> 7, j = i & 127;
            wreg[r] = Wf[(c * 16 + kk) * 128 + j];
        }
    };
    auto store = [&]() {
        #pragma unroll
        for (int r = 0; r < 2; ++r) {
            int i = t + r * 256;
            int n = i >> 4, kk = i & 15;
            As[kk * 36 + n] = areg[r];
        }
        #pragma unroll
        for (int r = 0; r < 8; ++r) Wl[t + r * 256] = wreg[r];
    };

    loadA(0); loadW(0);
    store();
    __syncthreads();
    for (int c = 0; c < 9; ++c) {
        if (c + 1 < 9) { loadA(c + 1); loadW(c + 1); }
        #pragma unroll
        for (int kk = 0; kk < 16; ++kk) {
            float2 a   = *(const float2*)&As[kk * 36 + n0];
            float4 b0v = *(const float4*)&Wl[kk * 128 + j0];
            float4 b1v = *(const float4*)&Wl[kk * 128 + j0 + 4];
            float bv[8] = {b0v.x, b0v.y, b0v.z, b0v.w, b1v.x, b1v.y, b1v.z, b1v.w};
            #pragma unroll
            for (int j = 0; j < 8; ++j) {
                acc[0][j] += a.x * bv[j];
                acc[1][j] += a.y * bv[j];
            }
        }
        __syncthreads();
        if (c + 1 < 9) { store(); __syncthreads(); }
    }

    // logits = acc + bias (stay in regs). Row reductions across the 16 tc-threads.
    float lmax[2], lsum[2];
    #pragma unroll
    for (int i = 0; i < 2; ++i) {
        float m = acc[i][0] + bias[0];
        #pragma unroll
        for (int j = 1; j < 8; ++j) m = fmaxf(m, acc[i][j] + bias[j]);
        Mred[(n0 + i) * 16 + tc] = m;
    }
    __syncthreads();
    #pragma unroll
    for (int i = 0; i < 2; ++i) {
        float m = Mred[(n0 + i) * 16];
        #pragma unroll
        for (int qq = 1; qq < 16; ++qq) m = fmaxf(m, Mred[(n0 + i) * 16 + qq]);
        lmax[i] = m;
        float s = 0.f;
        #pragma unroll
        for (int j = 0; j < 8; ++j) s += __expf(acc[i][j] + bias[j] - m);
        Sred[(n0 + i) * 16 + tc] = s;
    }
    __syncthreads();
    #pragma unroll
    for (int i = 0; i < 2; ++i) {
        float s = 0.f;
        #pragma unroll
        for (int qq = 0; qq < 16; ++qq) s += Sred[(n0 + i) * 16 + qq];
        lsum[i] = s;
    }
    #pragma unroll
    for (int i = 0; i < 2; ++i) {
        int gn = nb + n0 + i;
        if (gn < N_NODES) {
            float ls = __logf(lsum[i]) + lmax[i];
            float4 o0, o1;
            o0.x = acc[i][0] + bias[0] - ls; o0.y = acc[i][1] + bias[1] - ls;
            o0.z = acc[i][2] + bias[2] - ls; o0.w = acc[i][3] + bias[3] - ls;
            o1.x = acc[i][4] + bias[4] - ls; o1.y = acc[i][5] + bias[5] - ls;
            o1.z = acc[i][6] + bias[6] - ls; o1.w = acc[i][7] + bias[7] - ls;
            *(float4*)&out[gn * 128 + j0]     = o0;
            *(float4*)&out[gn * 128 + j0 + 4] = o1;
        }
    }
}

// ---------------- launch ----------------

extern "C" void kernel_launch(void* const* d_in, const int* in_sizes, int n_in,
                              void* d_out, int out_size, void* d_ws, size_t ws_size,
                              hipStream_t stream) {
    const float* x   = (const float*)d_in[0];
    const int*   ei  = (const int*)d_in[1];
    const float* ea  = (const float*)d_in[2];
    const float* Wc1 = (const float*)d_in[3];
    const float* bc1 = (const float*)d_in[4];
    const float* Wc2 = (const float*)d_in[5];
    const float* bc2 = (const float*)d_in[6];
    const float* W11 = (const float*)d_in[7];
    const float* b11 = (const float*)d_in[8];
    const float* W12 = (const float*)d_in[9];
    const float* b12 = (const float*)d_in[10];
    const float* W13 = (const float*)d_in[11];
    const float* b13 = (const float*)d_in[12];
    const float* W21 = (const float*)d_in[13];
    const float* b21 = (const float*)d_in[14];
    const float* W22 = (const float*)d_in[15];
    const float* b22 = (const float*)d_in[16];
    const float* W23 = (const float*)d_in[17];
    const float* b23 = (const float*)d_in[18];
    const float* Wf  = (const float*)d_in[19];
    const float* bfb = (const float*)d_in[20];

    const int* esrc = ei;
    const int* edst = ei + N_EDGES;

    float* hL = (float*)d_out;   // [N,128] f32 scratch in d_out (write-before-read)

    // workspace carve (off padded to N+2 so epack/xwb stay 8B-aligned)
    int*            off   = (int*)d_ws;                            // N+2
    int*            cnt   = off + (N_NODES + 2);                   // N
    unsigned*       epack = (unsigned*)(cnt + N_NODES);            // E
    unsigned short* xwb   = (unsigned short*)(epack + N_EDGES);    // N*64 bf16 (8B-aligned)
    float*          hR    = (float*)(xwb + (size_t)N_NODES * 64);  // N*16 f32

    hipMemsetAsync(off, 0, (size_t)(2 * N_NODES + 2) * sizeof(int), stream);
    k_hist <<<(N_EDGES + 255) / 256, 256, 0, stream>>>(edst, off);
    k_scan <<<1, 1024, 0, stream>>>(off);
    k_place<<<(N_EDGES + 255) / 256, 256, 0, stream>>>(esrc, edst, ea, off, cnt, epack);

    const int GD = (N_NODES + 31) / 32;   // 1563
    k_dense<64> <<<GD, 320, 0, stream>>>(x, nullptr, W11, b11, Wc1, W12, b12, W13, b13, hL, hR, xwb);
    k_agg       <<<(N_NODES + 3) / 4, 256, 0, stream>>>(xwb, off, epack, bc1, hL);
    k_dense<144><<<GD, 320, 0, stream>>>(hL, hR, W21, b21, Wc2, W22, b22, W23, b23, hL, hR, xwb);
    k_agg       <<<(N_NODES + 3) / 4, 256, 0, stream>>>(xwb, off, epack, bc2, hL);
    k_cls       <<<GD, 256, 0, stream>>>(hL, hR, Wf, bfb, (float*)d_out);
}

// Round 8
// 371.737 us; speedup vs baseline: 2.3078x; 1.1698x over previous
//
#include <hip/hip_runtime.h>
#include <hip/hip_bf16.h>

#define N_NODES 50000
#define N_EDGES 800000

typedef __attribute__((ext_vector_type(8))) short bf16x8;   // MFMA A/B frag (4 VGPR)
typedef __attribute__((ext_vector_type(4))) float f32x4;    // MFMA C/D frag

// bf16 bit helpers (round-to-nearest-even pack, shift unpack)
__device__ __forceinline__ unsigned short f2b(float f) {
    unsigned u = __float_as_uint(f);
    return (unsigned short)((u + 0x7FFF + ((u >> 16) & 1)) >> 16);
}
__device__ __forceinline__ float b2f(unsigned short b) {
    return __uint_as_float(((unsigned)b) << 16);
}

// ---------------- CSR build ----------------

__global__ void k_hist(const int* __restrict__ dst, int* __restrict__ deg) {
    int e = blockIdx.x * 256 + threadIdx.x;
    if (e < N_EDGES) atomicAdd(&deg[dst[e]], 1);
}

__global__ void k_scan(int* __restrict__ off) {
    __shared__ int part[1024];
    int t = threadIdx.x;
    const int chunk = (N_NODES + 1023) / 1024;  // 49
    int beg = t * chunk; if (beg > N_NODES) beg = N_NODES;
    int end = beg + chunk; if (end > N_NODES) end = N_NODES;
    int s = 0;
    for (int i = beg; i < end; ++i) s += off[i];
    part[t] = s;
    __syncthreads();
    for (int d = 1; d < 1024; d <<= 1) {
        int v = (t >= d) ? part[t - d] : 0;
        __syncthreads();
        part[t] += v;
        __syncthreads();
    }
    int run = (t == 0) ? 0 : part[t - 1];
    for (int i = beg; i < end; ++i) { int c = off[i]; off[i] = run; run += c; }
    if (t == 1023) off[N_NODES] = part[1023];
}

__global__ void k_place(const int* __restrict__ src, const int* __restrict__ dst,
                        const float* __restrict__ ea,
                        const int* __restrict__ off, int* __restrict__ cnt,
                        unsigned* __restrict__ epack) {
    int e = blockIdx.x * 256 + threadIdx.x;
    if (e < N_EDGES) {
        int d = dst[e];
        int p = off[d] + atomicAdd(&cnt[d], 1);
        epack[p] = (((unsigned)f2b(ea[e])) << 16) | (unsigned)src[e];
    }
}

// ---------------- MFMA dense layers ----------------
// Block = 256 thr = 4 waves; wave owns one 16-row M-tile, all 160 out cols
// (10 n-tiles of 16). Weights staged once per block as B^T bf16 in LDS
// (row n, K-padded); A-frags read straight from global. One barrier total.
// k-map used for BOTH A and B frags: lane l covers k = ks*32 + (l>>4)*8 + i
// (same map on both operands => result independent of HW's true k-interleave).
// D-frag (verified m89/m91): col = lane&15, row = (lane>>4)*4 + reg.

template<int KREAL>
__global__ __launch_bounds__(256) void k_dense(
    const float* __restrict__ xf,              // KREAL=64: x f32 [N][64]
    const unsigned short* hb_in,               // KREAL=144: h bf16 [N][144]
    const float* __restrict__ W1, const float* __restrict__ b1,
    const float* __restrict__ Wc,
    const float* __restrict__ W2, const float* __restrict__ b2,
    const float* __restrict__ W3, const float* __restrict__ b3,
    unsigned short* hb,                        // out: h cols 0-63, 128-143
    unsigned short* xwb) {                     // out: xw bf16 [N][64]
    constexpr int KPAD = (KREAL == 64) ? 72 : 168;
    constexpr int KS = (KREAL + 31) / 32;      // 2 or 5 k-steps
    __shared__ unsigned short Bl[160 * KPAD];
    int t = threadIdx.x;
    // stage B^T: Bl[n][k] = W(k, col n) bf16; zero-fill k >= KREAL
    for (int i = t; i < 160 * KPAD; i += 256) {
        int k = i / 160, n = i - k * 160;
        float w = 0.f;
        if (k < KREAL)
            w = (n < 64) ? W1[k * 64 + n]
              : (n < 128) ? Wc[k * 64 + (n - 64)]
              : (n < 144) ? W2[k * 16 + (n - 128)]
                          : W3[k * 16 + (n - 144)];
        Bl[n * KPAD + k] = f2b(w);
    }
    __syncthreads();
    int wv = t >> 6, ln = t & 63;
    int tile = blockIdx.x * 4 + wv;
    if (tile * 16 >= N_NODES) return;          // 50000 = 3125*16, tiles full
    int c = ln & 15, g = ln >> 4;
    int arow = tile * 16 + c;                  // A-row this lane reads
    float bia[4];
    #pragma unroll
    for (int j = 0; j < 4; ++j) bia[j] = b1[j * 16 + c];
    float b8 = b2[c], b9 = b3[c];

    f32x4 acc[10];
    #pragma unroll
    for (int nt = 0; nt < 10; ++nt) acc[nt] = f32x4{0.f, 0.f, 0.f, 0.f};

    const unsigned short* bp = &Bl[c * KPAD + g * 8];
    #pragma unroll
    for (int ks = 0; ks < KS; ++ks) {
        int kb = ks * 32 + g * 8;
        bf16x8 a = {0, 0, 0, 0, 0, 0, 0, 0};
        if constexpr (KREAL == 64) {
            const float* rp = xf + (size_t)arow * 64 + kb;
            float4 q0 = *(const float4*)rp;
            float4 q1 = *(const float4*)(rp + 4);
            union { bf16x8 v; unsigned short u[8]; } af;
            af.u[0] = f2b(q0.x); af.u[1] = f2b(q0.y); af.u[2] = f2b(q0.z); af.u[3] = f2b(q0.w);
            af.u[4] = f2b(q1.x); af.u[5] = f2b(q1.y); af.u[6] = f2b(q1.z); af.u[7] = f2b(q1.w);
            a = af.v;
        } else {
            if (kb < 144) a = *(const bf16x8*)(hb_in + (size_t)arow * 144 + kb);
        }
        #pragma unroll
        for (int nt = 0; nt < 10; ++nt) {
            bf16x8 b = *(const bf16x8*)(bp + nt * 16 * KPAD + ks * 32);
            acc[nt] = __builtin_amdgcn_mfma_f32_16x16x32_bf16(a, b, acc[nt], 0, 0, 0);
        }
    }
    // epilogue: lane holds col c of rows tile*16 + g*4 + r
    #pragma unroll
    for (int r = 0; r < 4; ++r) {
        int orow = tile * 16 + g * 4 + r;
        size_t hbase = (size_t)orow * 144;
        #pragma unroll
        for (int nt = 0; nt < 4; ++nt)
            hb[hbase + nt * 16 + c] = f2b(fmaxf(acc[nt][r] + bia[nt], 0.f));
        #pragma unroll
        for (int nt = 4; nt < 8; ++nt)
            xwb[(size_t)orow * 64 + (nt - 4) * 16 + c] = f2b(acc[nt][r]);
        float p = fmaxf(acc[8][r] + b8, 0.f) * fmaxf(acc[9][r] + b9, 0.f);
        hb[hbase + 128 + c] = f2b(p);
    }
}

// ---------------- aggregation: wave per dst node, 4 edges/iter ----------------

__global__ __launch_bounds__(256) void k_agg(
    const unsigned short* __restrict__ xwb, const int* __restrict__ off,
    const unsigned* __restrict__ epack,
    const float* __restrict__ bc, unsigned short* __restrict__ hb) {
    int node = blockIdx.x * 4 + (threadIdx.x >> 6);
    int lane = threadIdx.x & 63;
    if (node >= N_NODES) return;
    const uint2* xw64 = (const uint2*)xwb;   // 16 uint2 per node row
    int b = off[node], e = off[node + 1];
    int q = lane >> 4, c = lane & 15;
    float a0 = 0.f, a1 = 0.f, a2 = 0.f, a3 = 0.f;
    for (int i = b + q; i < e; i += 4) {
        unsigned u = epack[i];
        float ew = b2f((unsigned short)(u >> 16));
        uint2 wv = xw64[(u & 0xFFFFu) * 16 + c];
        a0 += ew * b2f((unsigned short)(wv.x & 0xFFFFu));
        a1 += ew * b2f((unsigned short)(wv.x >> 16));
        a2 += ew * b2f((unsigned short)(wv.y & 0xFFFFu));
        a3 += ew * b2f((unsigned short)(wv.y >> 16));
    }
    a0 += __shfl_xor(a0, 16); a0 += __shfl_xor(a0, 32);
    a1 += __shfl_xor(a1, 16); a1 += __shfl_xor(a1, 32);
    a2 += __shfl_xor(a2, 16); a2 += __shfl_xor(a2, 32);
    a3 += __shfl_xor(a3, 16); a3 += __shfl_xor(a3, 32);
    if (q == 0) {
        int f0 = 4 * c;
        float4 bv = *(const float4*)&bc[f0];
        ushort4 o;
        o.x = f2b(fmaxf(a0 + bv.x, 0.f));
        o.y = f2b(fmaxf(a1 + bv.y, 0.f));
        o.z = f2b(fmaxf(a2 + bv.z, 0.f));
        o.w = f2b(fmaxf(a3 + bv.w, 0.f));
        *(ushort4*)&hb[(size_t)node * 144 + 64 + f0] = o;
    }
}

// ---------------- classifier MFMA GEMM + log_softmax ----------------
// Same structure, N=128 (8 n-tiles). Row m's 128 logits live in the 16 lanes
// of m's lane-group (col c+16*nt in acc[nt][r]) -> 16-lane shuffle softmax.

__global__ __launch_bounds__(256) void k_cls(
    const unsigned short* __restrict__ hb,
    const float* __restrict__ Wf, const float* __restrict__ bfb,
    float* __restrict__ out) {
    constexpr int KPAD = 168;
    __shared__ unsigned short Bl[128 * KPAD];   // 43008 B
    int t = threadIdx.x;
    for (int i = t; i < 128 * KPAD; i += 256) {
        int k = i >> 7, n = i & 127;
        Bl[n * KPAD + k] = (k < 144) ? f2b(Wf[k * 128 + n]) : (unsigned short)0;
    }
    __syncthreads();
    int wv = t >> 6, ln = t & 63;
    int tile = blockIdx.x * 4 + wv;
    if (tile * 16 >= N_NODES) return;
    int c = ln & 15, g = ln >> 4;
    int arow = tile * 16 + c;
    float bia[8];
    #pragma unroll
    for (int j = 0; j < 8; ++j) bia[j] = bfb[j * 16 + c];
    f32x4 acc[8];
    #pragma unroll
    for (int nt = 0; nt < 8; ++nt) acc[nt] = f32x4{0.f, 0.f, 0.f, 0.f};

    const unsigned short* bp = &Bl[c * KPAD + g * 8];
    #pragma unroll
    for (int ks = 0; ks < 5; ++ks) {
        int kb = ks * 32 + g * 8;
        bf16x8 a = {0, 0, 0, 0, 0, 0, 0, 0};
        if (kb < 144) a = *(const bf16x8*)(hb + (size_t)arow * 144 + kb);
        #pragma unroll
        for (int nt = 0; nt < 8; ++nt) {
            bf16x8 b = *(const bf16x8*)(bp + nt * 16 * KPAD + ks * 32);
            acc[nt] = __builtin_amdgcn_mfma_f32_16x16x32_bf16(a, b, acc[nt], 0, 0, 0);
        }
    }
    #pragma unroll
    for (int r = 0; r < 4; ++r) {
        float lg[8];
        #pragma unroll
        for (int nt = 0; nt < 8; ++nt) lg[nt] = acc[nt][r] + bia[nt];
        float m = lg[0];
        #pragma unroll
        for (int nt = 1; nt < 8; ++nt) m = fmaxf(m, lg[nt]);
        #pragma unroll
        for (int o = 1; o < 16; o <<= 1) m = fmaxf(m, __shfl_xor(m, o));
        float s = 0.f;
        #pragma unroll
        for (int nt = 0; nt < 8; ++nt) s += __expf(lg[nt] - m);
        #pragma unroll
        for (int o = 1; o < 16; o <<= 1) s += __shfl_xor(s, o);
        float ls = __logf(s) + m;
        int orow = tile * 16 + g * 4 + r;
        #pragma unroll
        for (int nt = 0; nt < 8; ++nt)
            out[(size_t)orow * 128 + nt * 16 + c] = lg[nt] - ls;
    }
}

// ---------------- launch ----------------

extern "C" void kernel_launch(void* const* d_in, const int* in_sizes, int n_in,
                              void* d_out, int out_size, void* d_ws, size_t ws_size,
                              hipStream_t stream) {
    const float* x   = (const float*)d_in[0];
    const int*   ei  = (const int*)d_in[1];
    const float* ea  = (const float*)d_in[2];
    const float* Wc1 = (const float*)d_in[3];
    const float* bc1 = (const float*)d_in[4];
    const float* Wc2 = (const float*)d_in[5];
    const float* bc2 = (const float*)d_in[6];
    const float* W11 = (const float*)d_in[7];
    const float* b11 = (const float*)d_in[8];
    const float* W12 = (const float*)d_in[9];
    const float* b12 = (const float*)d_in[10];
    const float* W13 = (const float*)d_in[11];
    const float* b13 = (const float*)d_in[12];
    const float* W21 = (const float*)d_in[13];
    const float* b21 = (const float*)d_in[14];
    const float* W22 = (const float*)d_in[15];
    const float* b22 = (const float*)d_in[16];
    const float* W23 = (const float*)d_in[17];
    const float* b23 = (const float*)d_in[18];
    const float* Wf  = (const float*)d_in[19];
    const float* bfb = (const float*)d_in[20];

    const int* esrc = ei;
    const int* edst = ei + N_EDGES;

    // xw bf16 [N][64] lives in d_out (6.4 MB; dead before k_cls writes out).
    unsigned short* xwb = (unsigned short*)d_out;

    // workspace: off(N+2) + cnt(N) + epack(E) + hb(N*144 bf16)  ~= 18.0 MB
    int*            off   = (int*)d_ws;
    int*            cnt   = off + (N_NODES + 2);
    unsigned*       epack = (unsigned*)(cnt + N_NODES);
    unsigned short* hb    = (unsigned short*)(epack + N_EDGES);

    hipMemsetAsync(off, 0, (size_t)(2 * N_NODES + 2) * sizeof(int), stream);
    k_hist <<<(N_EDGES + 255) / 256, 256, 0, stream>>>(edst, off);
    k_scan <<<1, 1024, 0, stream>>>(off);
    k_place<<<(N_EDGES + 255) / 256, 256, 0, stream>>>(esrc, edst, ea, off, cnt, epack);

    const int GD = (3125 + 3) / 4;   // 782 blocks, 4 wave-tiles each
    k_dense<64> <<<GD, 256, 0, stream>>>(x, nullptr, W11, b11, Wc1, W12, b12, W13, b13, hb, xwb);
    k_agg       <<<(N_NODES + 3) / 4, 256, 0, stream>>>(xwb, off, epack, bc1, hb);
    k_dense<144><<<GD, 256, 0, stream>>>(nullptr, hb, W21, b21, Wc2, W22, b22, W23, b23, hb, xwb);
    k_agg       <<<(N_NODES + 3) / 4, 256, 0, stream>>>(xwb, off, epack, bc2, hb);
    k_cls       <<<GD, 256, 0, stream>>>(hb, Wf, bfb, (float*)d_out);
}

// Round 9
// 271.393 us; speedup vs baseline: 3.1610x; 1.3697x over previous
//
#include <hip/hip_runtime.h>
#include <hip/hip_bf16.h>

#define N_NODES 50000
#define N_EDGES 800000

typedef __attribute__((ext_vector_type(8))) short bf16x8;   // MFMA A/B frag (4 VGPR)
typedef __attribute__((ext_vector_type(4))) float f32x4;    // MFMA C/D frag

// bf16 bit helpers (round-to-nearest-even pack, shift unpack)
__device__ __forceinline__ unsigned short f2b(float f) {
    unsigned u = __float_as_uint(f);
    return (unsigned short)((u + 0x7FFF + ((u >> 16) & 1)) >> 16);
}
__device__ __forceinline__ float b2f(unsigned short b) {
    return __uint_as_float(((unsigned)b) << 16);
}

// ---------------- CSR build ----------------

__global__ void k_hist(const int* __restrict__ dst, int* __restrict__ deg) {
    int e = blockIdx.x * 256 + threadIdx.x;
    if (e < N_EDGES) atomicAdd(&deg[dst[e]], 1);
}

__global__ void k_scan(int* __restrict__ off) {
    __shared__ int part[1024];
    int t = threadIdx.x;
    const int chunk = (N_NODES + 1023) / 1024;  // 49
    int beg = t * chunk; if (beg > N_NODES) beg = N_NODES;
    int end = beg + chunk; if (end > N_NODES) end = N_NODES;
    int s = 0;
    for (int i = beg; i < end; ++i) s += off[i];
    part[t] = s;
    __syncthreads();
    for (int d = 1; d < 1024; d <<= 1) {
        int v = (t >= d) ? part[t - d] : 0;
        __syncthreads();
        part[t] += v;
        __syncthreads();
    }
    int run = (t == 0) ? 0 : part[t - 1];
    for (int i = beg; i < end; ++i) { int c = off[i]; off[i] = run; run += c; }
    if (t == 1023) off[N_NODES] = part[1023];
}

__global__ void k_place(const int* __restrict__ src, const int* __restrict__ dst,
                        const float* __restrict__ ea,
                        const int* __restrict__ off, int* __restrict__ cnt,
                        unsigned* __restrict__ epack) {
    int e = blockIdx.x * 256 + threadIdx.x;
    if (e < N_EDGES) {
        int d = dst[e];
        int p = off[d] + atomicAdd(&cnt[d], 1);
        epack[p] = (((unsigned)f2b(ea[e])) << 16) | (unsigned)src[e];
    }
}

// ---------------- weight prep: bf16 B-fragments in per-lane order ----------------
// frag layout: B[((nt*KS + ks)*64 + lane)*8 + i] = W(k, col)
//   k = ks*32 + (lane>>4)*8 + i, col = nt*16 + (lane&15); zero-fill k >= KREAL.
// Same k-map as the A-frags in the dense kernels (proven numerics, round 8).
// sizes: B1 10*2*512=10240, B2 10*5*512=25600, Bc 8*5*512=20480 bf16.

__global__ void k_prep(
    const float* __restrict__ W11, const float* __restrict__ Wc1,
    const float* __restrict__ W12, const float* __restrict__ W13,
    const float* __restrict__ W21, const float* __restrict__ Wc2,
    const float* __restrict__ W22, const float* __restrict__ W23,
    const float* __restrict__ Wf,
    unsigned short* __restrict__ B1, unsigned short* __restrict__ B2,
    unsigned short* __restrict__ Bc) {
    int idx = blockIdx.x * 256 + threadIdx.x;
    if (idx < 10240) {                       // B1: KS=2, K=64, 160 cols
        int i = idx & 7, l = (idx >> 3) & 63, ks = (idx >> 9) & 1, nt = idx >> 10;
        int k = ks * 32 + ((l >> 4) << 3) + i;
        int col = nt * 16 + (l & 15);
        float w = (col < 64) ? W11[k * 64 + col]
                : (col < 128) ? Wc1[k * 64 + col - 64]
                : (col < 144) ? W12[k * 16 + col - 128]
                              : W13[k * 16 + col - 144];
        B1[idx] = f2b(w);
    } else if (idx < 10240 + 25600) {        // B2: KS=5, K=144, 160 cols
        int j = idx - 10240;
        int i = j & 7, l = (j >> 3) & 63;
        int ks = (j >> 9) % 5, nt = j / 2560;
        int k = ks * 32 + ((l >> 4) << 3) + i;
        int col = nt * 16 + (l & 15);
        float w = 0.f;
        if (k < 144)
            w = (col < 64) ? W21[k * 64 + col]
              : (col < 128) ? Wc2[k * 64 + col - 64]
              : (col < 144) ? W22[k * 16 + col - 128]
                            : W23[k * 16 + col - 144];
        B2[j] = f2b(w);
    } else if (idx < 10240 + 25600 + 20480) { // Bc: KS=5, K=144, 128 cols
        int j = idx - 10240 - 25600;
        int i = j & 7, l = (j >> 3) & 63;
        int ks = (j >> 9) % 5, nt = j / 2560;
        int k = ks * 32 + ((l >> 4) << 3) + i;
        int col = nt * 16 + (l & 15);
        Bc[j] = (k < 144) ? f2b(Wf[k * 128 + col]) : (unsigned short)0;
    }
}

// ---------------- MFMA dense layers (no LDS, no barriers) ----------------
// 4 waves/block, wave owns one 16-row M-tile, 10 n-tiles of 16 cols.
// B-frags read from pre-built global layout (L2-broadcast, 1KB coalesced/wave).
// D-frag (verified m89/m91): col = lane&15, row = (lane>>4)*4 + reg.

template<int KREAL>
__global__ __launch_bounds__(256) void k_dense(
    const float* __restrict__ xf,              // KREAL=64: x f32 [N][64]
    const unsigned short* __restrict__ hb_in,  // KREAL=144: h bf16 [N][144]
    const unsigned short* __restrict__ Bw,     // frag-ordered weights
    const float* __restrict__ b1, const float* __restrict__ b2,
    const float* __restrict__ b3,
    unsigned short* __restrict__ hb,           // out: h cols 0-63, 128-143
    unsigned short* __restrict__ xwb) {        // out: xw bf16 [N][64]
    constexpr int KS = (KREAL + 31) / 32;      // 2 or 5
    int t = threadIdx.x;
    int wv = t >> 6, ln = t & 63;
    int tile = blockIdx.x * 4 + wv;
    if (tile >= 3125) return;                  // 50000 = 3125*16 exact
    int c = ln & 15, g = ln >> 4;
    int arow = tile * 16 + c;
    float bia[4];
    #pragma unroll
    for (int j = 0; j < 4; ++j) bia[j] = b1[j * 16 + c];
    float b8 = b2[c], b9 = b3[c];

    f32x4 acc[10];
    #pragma unroll
    for (int nt = 0; nt < 10; ++nt) acc[nt] = f32x4{0.f, 0.f, 0.f, 0.f};

    const bf16x8* bfrag = (const bf16x8*)(Bw + (size_t)ln * 8);
    #pragma unroll
    for (int ks = 0; ks < KS; ++ks) {
        int kb = ks * 32 + g * 8;
        bf16x8 a = {0, 0, 0, 0, 0, 0, 0, 0};
        if constexpr (KREAL == 64) {
            const float* rp = xf + (size_t)arow * 64 + kb;
            float4 q0 = *(const float4*)rp;
            float4 q1 = *(const float4*)(rp + 4);
            union { bf16x8 v; unsigned short u[8]; } af;
            af.u[0] = f2b(q0.x); af.u[1] = f2b(q0.y); af.u[2] = f2b(q0.z); af.u[3] = f2b(q0.w);
            af.u[4] = f2b(q1.x); af.u[5] = f2b(q1.y); af.u[6] = f2b(q1.z); af.u[7] = f2b(q1.w);
            a = af.v;
        } else {
            if (kb < 144) a = *(const bf16x8*)(hb_in + (size_t)arow * 144 + kb);
        }
        #pragma unroll
        for (int nt = 0; nt < 10; ++nt) {
            bf16x8 b = bfrag[(nt * KS + ks) * 64];
            acc[nt] = __builtin_amdgcn_mfma_f32_16x16x32_bf16(a, b, acc[nt], 0, 0, 0);
        }
    }
    #pragma unroll
    for (int r = 0; r < 4; ++r) {
        int orow = tile * 16 + g * 4 + r;
        size_t hbase = (size_t)orow * 144;
        #pragma unroll
        for (int nt = 0; nt < 4; ++nt)
            hb[hbase + nt * 16 + c] = f2b(fmaxf(acc[nt][r] + bia[nt], 0.f));
        #pragma unroll
        for (int nt = 4; nt < 8; ++nt)
            xwb[(size_t)orow * 64 + (nt - 4) * 16 + c] = f2b(acc[nt][r]);
        float p = fmaxf(acc[8][r] + b8, 0.f) * fmaxf(acc[9][r] + b9, 0.f);
        hb[hbase + 128 + c] = f2b(p);
    }
}

// ---------------- aggregation: wave per dst node, 4 edges/iter ----------------

__global__ __launch_bounds__(256) void k_agg(
    const unsigned short* __restrict__ xwb, const int* __restrict__ off,
    const unsigned* __restrict__ epack,
    const float* __restrict__ bc, unsigned short* __restrict__ hb) {
    int node = blockIdx.x * 4 + (threadIdx.x >> 6);
    int lane = threadIdx.x & 63;
    if (node >= N_NODES) return;
    const uint2* xw64 = (const uint2*)xwb;   // 16 uint2 per node row
    int b = off[node], e = off[node + 1];
    int q = lane >> 4, c = lane & 15;
    float a0 = 0.f, a1 = 0.f, a2 = 0.f, a3 = 0.f;
    for (int i = b + q; i < e; i += 4) {
        unsigned u = epack[i];
        float ew = b2f((unsigned short)(u >> 16));
        uint2 wv = xw64[(u & 0xFFFFu) * 16 + c];
        a0 += ew * b2f((unsigned short)(wv.x & 0xFFFFu));
        a1 += ew * b2f((unsigned short)(wv.x >> 16));
        a2 += ew * b2f((unsigned short)(wv.y & 0xFFFFu));
        a3 += ew * b2f((unsigned short)(wv.y >> 16));
    }
    a0 += __shfl_xor(a0, 16); a0 += __shfl_xor(a0, 32);
    a1 += __shfl_xor(a1, 16); a1 += __shfl_xor(a1, 32);
    a2 += __shfl_xor(a2, 16); a2 += __shfl_xor(a2, 32);
    a3 += __shfl_xor(a3, 16); a3 += __shfl_xor(a3, 32);
    if (q == 0) {
        int f0 = 4 * c;
        float4 bv = *(const float4*)&bc[f0];
        ushort4 o;
        o.x = f2b(fmaxf(a0 + bv.x, 0.f));
        o.y = f2b(fmaxf(a1 + bv.y, 0.f));
        o.z = f2b(fmaxf(a2 + bv.z, 0.f));
        o.w = f2b(fmaxf(a3 + bv.w, 0.f));
        *(ushort4*)&hb[(size_t)node * 144 + 64 + f0] = o;
    }
}

// ---------------- classifier MFMA GEMM + log_softmax (no LDS) ----------------
// Row m's 128 logits live in the 16 lanes of its lane-group -> 16-lane
// shuffle softmax. out f32 written from regs.

__global__ __launch_bounds__(256) void k_cls(
    const unsigned short* __restrict__ hb,
    const unsigned short* __restrict__ Bw,
    const float* __restrict__ bfb,
    float* __restrict__ out) {
    int t = threadIdx.x;
    int wv = t >> 6, ln = t & 63;
    int tile = blockIdx.x * 4 + wv;
    if (tile >= 3125) return;
    int c = ln & 15, g = ln >> 4;
    int arow = tile * 16 + c;
    float bia[8];
    #pragma unroll
    for (int j = 0; j < 8; ++j) bia[j] = bfb[j * 16 + c];
    f32x4 acc[8];
    #pragma unroll
    for (int nt = 0; nt < 8; ++nt) acc[nt] = f32x4{0.f, 0.f, 0.f, 0.f};

    const bf16x8* bfrag = (const bf16x8*)(Bw + (size_t)ln * 8);
    #pragma unroll
    for (int ks = 0; ks < 5; ++ks) {
        int kb = ks * 32 + g * 8;
        bf16x8 a = {0, 0, 0, 0, 0, 0, 0, 0};
        if (kb < 144) a = *(const bf16x8*)(hb + (size_t)arow * 144 + kb);
        #pragma unroll
        for (int nt = 0; nt < 8; ++nt) {
            bf16x8 b = bfrag[(nt * 5 + ks) * 64];
            acc[nt] = __builtin_amdgcn_mfma_f32_16x16x32_bf16(a, b, acc[nt], 0, 0, 0);
        }
    }
    #pragma unroll
    for (int r = 0; r < 4; ++r) {
        float lg[8];
        #pragma unroll
        for (int nt = 0; nt < 8; ++nt) lg[nt] = acc[nt][r] + bia[nt];
        float m = lg[0];
        #pragma unroll
        for (int nt = 1; nt < 8; ++nt) m = fmaxf(m, lg[nt]);
        #pragma unroll
        for (int o = 1; o < 16; o <<= 1) m = fmaxf(m, __shfl_xor(m, o));
        float s = 0.f;
        #pragma unroll
        for (int nt = 0; nt < 8; ++nt) s += __expf(lg[nt] - m);
        #pragma unroll
        for (int o = 1; o < 16; o <<= 1) s += __shfl_xor(s, o);
        float ls = __logf(s) + m;
        int orow = tile * 16 + g * 4 + r;
        #pragma unroll
        for (int nt = 0; nt < 8; ++nt)
            out[(size_t)orow * 128 + nt * 16 + c] = lg[nt] - ls;
    }
}

// ---------------- launch ----------------

extern "C" void kernel_launch(void* const* d_in, const int* in_sizes, int n_in,
                              void* d_out, int out_size, void* d_ws, size_t ws_size,
                              hipStream_t stream) {
    const float* x   = (const float*)d_in[0];
    const int*   ei  = (const int*)d_in[1];
    const float* ea  = (const float*)d_in[2];
    const float* Wc1 = (const float*)d_in[3];
    const float* bc1 = (const float*)d_in[4];
    const float* Wc2 = (const float*)d_in[5];
    const float* bc2 = (const float*)d_in[6];
    const float* W11 = (const float*)d_in[7];
    const float* b11 = (const float*)d_in[8];
    const float* W12 = (const float*)d_in[9];
    const float* b12 = (const float*)d_in[10];
    const float* W13 = (const float*)d_in[11];
    const float* b13 = (const float*)d_in[12];
    const float* W21 = (const float*)d_in[13];
    const float* b21 = (const float*)d_in[14];
    const float* W22 = (const float*)d_in[15];
    const float* b22 = (const float*)d_in[16];
    const float* W23 = (const float*)d_in[17];
    const float* b23 = (const float*)d_in[18];
    const float* Wf  = (const float*)d_in[19];
    const float* bfb = (const float*)d_in[20];

    const int* esrc = ei;
    const int* edst = ei + N_EDGES;

    // xw bf16 [N][64] lives in d_out (6.4 MB; dead before k_cls writes out).
    unsigned short* xwb = (unsigned short*)d_out;

    // workspace: off + cnt + epack + hb + B1/B2/Bc   ~= 18.2 MB
    int*            off   = (int*)d_ws;                          // N+2
    int*            cnt   = off + (N_NODES + 2);                 // N
    unsigned*       epack = (unsigned*)(cnt + N_NODES);          // E
    unsigned short* hb    = (unsigned short*)(epack + N_EDGES);  // N*144
    unsigned short* B1    = hb + (size_t)N_NODES * 144;          // 10240
    unsigned short* B2    = B1 + 10240;                          // 25600
    unsigned short* Bc    = B2 + 25600;                          // 20480

    hipMemsetAsync(off, 0, (size_t)(2 * N_NODES + 2) * sizeof(int), stream);
    k_prep <<<(10240 + 25600 + 20480 + 255) / 256, 256, 0, stream>>>(
        W11, Wc1, W12, W13, W21, Wc2, W22, W23, Wf, B1, B2, Bc);
    k_hist <<<(N_EDGES + 255) / 256, 256, 0, stream>>>(edst, off);
    k_scan <<<1, 1024, 0, stream>>>(off);
    k_place<<<(N_EDGES + 255) / 256, 256, 0, stream>>>(esrc, edst, ea, off, cnt, epack);

    const int GD = (3125 + 3) / 4;   // 782 blocks, 4 wave-tiles each
    k_dense<64> <<<GD, 256, 0, stream>>>(x, nullptr, B1, b11, b12, b13, hb, xwb);
    k_agg       <<<(N_NODES + 3) / 4, 256, 0, stream>>>(xwb, off, epack, bc1, hb);
    k_dense<144><<<GD, 256, 0, stream>>>(nullptr, hb, B2, b21, b22, b23, hb, xwb);
    k_agg       <<<(N_NODES + 3) / 4, 256, 0, stream>>>(xwb, off, epack, bc2, hb);
    k_cls       <<<GD, 256, 0, stream>>>(hb, Bc, bfb, (float*)d_out);
}

// Round 10
// 197.562 us; speedup vs baseline: 4.3423x; 1.3737x over previous
//
#include <hip/hip_runtime.h>
#include <hip/hip_bf16.h>

#define N_NODES 50000
#define N_EDGES 800000
#define SCAN_NB 196   // 196*256 = 50176 >= N_NODES+1

typedef __attribute__((ext_vector_type(8))) short bf16x8;   // MFMA A/B frag (4 VGPR)
typedef __attribute__((ext_vector_type(4))) float f32x4;    // MFMA C/D frag

// bf16 bit helpers (round-to-nearest-even pack, shift unpack)
__device__ __forceinline__ unsigned short f2b(float f) {
    unsigned u = __float_as_uint(f);
    return (unsigned short)((u + 0x7FFF + ((u >> 16) & 1)) >> 16);
}
__device__ __forceinline__ float b2f(unsigned short b) {
    return __uint_as_float(((unsigned)b) << 16);
}

// ---------------- CSR build ----------------

__global__ void k_hist(const int* __restrict__ dst, int* __restrict__ deg) {
    int e = blockIdx.x * 256 + threadIdx.x;
    if (e < N_EDGES) atomicAdd(&deg[dst[e]], 1);
}

// hierarchical exclusive scan over off[0..N): scan1 (per-block) -> scan2
// (block sums) -> scan3 (add offsets, write off[N]).

__global__ __launch_bounds__(256) void k_scan1(int* __restrict__ off, int* __restrict__ bsum) {
    __shared__ int wsum[4];
    int t = threadIdx.x, b = blockIdx.x;
    int i = b * 256 + t;
    int v = (i < N_NODES) ? off[i] : 0;
    int lane = t & 63, wid = t >> 6;
    int incl = v;
    #pragma unroll
    for (int d = 1; d < 64; d <<= 1) {
        int u = __shfl_up(incl, d);
        if (lane >= d) incl += u;
    }
    if (lane == 63) wsum[wid] = incl;
    __syncthreads();
    int woff = 0;
    for (int w = 0; w < wid; ++w) woff += wsum[w];
    if (i < N_NODES) off[i] = incl - v + woff;
    if (t == 255) bsum[b] = incl + woff;
}

__global__ void k_scan2(int* __restrict__ bsum) {
    __shared__ int wsum[4];
    int t = threadIdx.x;
    int v = (t < SCAN_NB) ? bsum[t] : 0;
    int lane = t & 63, wid = t >> 6;
    int incl = v;
    #pragma unroll
    for (int d = 1; d < 64; d <<= 1) {
        int u = __shfl_up(incl, d);
        if (lane >= d) incl += u;
    }
    if (lane == 63) wsum[wid] = incl;
    __syncthreads();
    int woff = 0;
    for (int w = 0; w < wid; ++w) woff += wsum[w];
    if (t < SCAN_NB) bsum[t] = incl - v + woff;
    if (t == 255) bsum[SCAN_NB] = incl + woff;   // grand total == N_EDGES
}

__global__ __launch_bounds__(256) void k_scan3(int* __restrict__ off, const int* __restrict__ bsum) {
    int i = blockIdx.x * 256 + threadIdx.x;
    if (i < N_NODES) off[i] += bsum[blockIdx.x];
    else if (i == N_NODES) off[N_NODES] = bsum[SCAN_NB];
}

__global__ void k_place(const int* __restrict__ src, const int* __restrict__ dst,
                        const float* __restrict__ ea,
                        const int* __restrict__ off, int* __restrict__ cnt,
                        unsigned* __restrict__ epack) {
    int e = blockIdx.x * 256 + threadIdx.x;
    if (e < N_EDGES) {
        int d = dst[e];
        int p = off[d] + atomicAdd(&cnt[d], 1);
        epack[p] = (((unsigned)f2b(ea[e])) << 16) | (unsigned)src[e];
    }
}

// ---------------- weight prep: bf16 B-fragments in per-lane order ----------------
// frag layout: B[((nt*KS + ks)*64 + lane)*8 + i] = W(k, col)
//   k = ks*32 + (lane>>4)*8 + i, col = nt*16 + (lane&15); zero-fill k >= KREAL.

__global__ void k_prep(
    const float* __restrict__ W11, const float* __restrict__ Wc1,
    const float* __restrict__ W12, const float* __restrict__ W13,
    const float* __restrict__ W21, const float* __restrict__ Wc2,
    const float* __restrict__ W22, const float* __restrict__ W23,
    const float* __restrict__ Wf,
    unsigned short* __restrict__ B1, unsigned short* __restrict__ B2,
    unsigned short* __restrict__ Bc) {
    int idx = blockIdx.x * 256 + threadIdx.x;
    if (idx < 10240) {                       // B1: KS=2, K=64, 160 cols
        int i = idx & 7, l = (idx >> 3) & 63, ks = (idx >> 9) & 1, nt = idx >> 10;
        int k = ks * 32 + ((l >> 4) << 3) + i;
        int col = nt * 16 + (l & 15);
        float w = (col < 64) ? W11[k * 64 + col]
                : (col < 128) ? Wc1[k * 64 + col - 64]
                : (col < 144) ? W12[k * 16 + col - 128]
                              : W13[k * 16 + col - 144];
        B1[idx] = f2b(w);
    } else if (idx < 10240 + 25600) {        // B2: KS=5, K=144, 160 cols
        int j = idx - 10240;
        int i = j & 7, l = (j >> 3) & 63;
        int ks = (j >> 9) % 5, nt = j / 2560;
        int k = ks * 32 + ((l >> 4) << 3) + i;
        int col = nt * 16 + (l & 15);
        float w = 0.f;
        if (k < 144)
            w = (col < 64) ? W21[k * 64 + col]
              : (col < 128) ? Wc2[k * 64 + col - 64]
              : (col < 144) ? W22[k * 16 + col - 128]
                            : W23[k * 16 + col - 144];
        B2[j] = f2b(w);
    } else if (idx < 10240 + 25600 + 20480) { // Bc: KS=5, K=144, 128 cols
        int j = idx - 10240 - 25600;
        int i = j & 7, l = (j >> 3) & 63;
        int ks = (j >> 9) % 5, nt = j / 2560;
        int k = ks * 32 + ((l >> 4) << 3) + i;
        int col = nt * 16 + (l & 15);
        Bc[j] = (k < 144) ? f2b(Wf[k * 128 + col]) : (unsigned short)0;
    }
}

// ---------------- MFMA dense layers (no LDS, no barriers) ----------------
// 4 waves/block, wave owns one 16-row M-tile, 10 n-tiles of 16 cols.
// B-frags read from pre-built global layout (L2-broadcast, 1KB coalesced/wave).
// D-frag (verified m89/m91): col = lane&15, row = (lane>>4)*4 + reg.

template<int KREAL>
__global__ __launch_bounds__(256) void k_dense(
    const float* __restrict__ xf,              // KREAL=64: x f32 [N][64]
    const unsigned short* __restrict__ hb_in,  // KREAL=144: h bf16 [N][144]
    const unsigned short* __restrict__ Bw,     // frag-ordered weights
    const float* __restrict__ b1, const float* __restrict__ b2,
    const float* __restrict__ b3,
    unsigned short* __restrict__ hb,           // out: h cols 0-63, 128-143
    unsigned short* __restrict__ xwb) {        // out: xw bf16 [N][64]
    constexpr int KS = (KREAL + 31) / 32;      // 2 or 5
    int t = threadIdx.x;
    int wv = t >> 6, ln = t & 63;
    int tile = blockIdx.x * 4 + wv;
    if (tile >= 3125) return;                  // 50000 = 3125*16 exact
    int c = ln & 15, g = ln >> 4;
    int arow = tile * 16 + c;
    float bia[4];
    #pragma unroll
    for (int j = 0; j < 4; ++j) bia[j] = b1[j * 16 + c];
    float b8 = b2[c], b9 = b3[c];

    f32x4 acc[10];
    #pragma unroll
    for (int nt = 0; nt < 10; ++nt) acc[nt] = f32x4{0.f, 0.f, 0.f, 0.f};

    const bf16x8* bfrag = (const bf16x8*)(Bw + (size_t)ln * 8);
    #pragma unroll
    for (int ks = 0; ks < KS; ++ks) {
        int kb = ks * 32 + g * 8;
        bf16x8 a = {0, 0, 0, 0, 0, 0, 0, 0};
        if constexpr (KREAL == 64) {
            const float* rp = xf + (size_t)arow * 64 + kb;
            float4 q0 = *(const float4*)rp;
            float4 q1 = *(const float4*)(rp + 4);
            union { bf16x8 v; unsigned short u[8]; } af;
            af.u[0] = f2b(q0.x); af.u[1] = f2b(q0.y); af.u[2] = f2b(q0.z); af.u[3] = f2b(q0.w);
            af.u[4] = f2b(q1.x); af.u[5] = f2b(q1.y); af.u[6] = f2b(q1.z); af.u[7] = f2b(q1.w);
            a = af.v;
        } else {
            if (kb < 144) a = *(const bf16x8*)(hb_in + (size_t)arow * 144 + kb);
        }
        #pragma unroll
        for (int nt = 0; nt < 10; ++nt) {
            bf16x8 b = bfrag[(nt * KS + ks) * 64];
            acc[nt] = __builtin_amdgcn_mfma_f32_16x16x32_bf16(a, b, acc[nt], 0, 0, 0);
        }
    }
    #pragma unroll
    for (int r = 0; r < 4; ++r) {
        int orow = tile * 16 + g * 4 + r;
        size_t hbase = (size_t)orow * 144;
        #pragma unroll
        for (int nt = 0; nt < 4; ++nt)
            hb[hbase + nt * 16 + c] = f2b(fmaxf(acc[nt][r] + bia[nt], 0.f));
        #pragma unroll
        for (int nt = 4; nt < 8; ++nt)
            xwb[(size_t)orow * 64 + (nt - 4) * 16 + c] = f2b(acc[nt][r]);
        float p = fmaxf(acc[8][r] + b8, 0.f) * fmaxf(acc[9][r] + b9, 0.f);
        hb[hbase + 128 + c] = f2b(p);
    }
}

// ---------------- aggregation: wave per dst node, 4 edges/iter ----------------

__global__ __launch_bounds__(256) void k_agg(
    const unsigned short* __restrict__ xwb, const int* __restrict__ off,
    const unsigned* __restrict__ epack,
    const float* __restrict__ bc, unsigned short* __restrict__ hb) {
    int node = blockIdx.x * 4 + (threadIdx.x >> 6);
    int lane = threadIdx.x & 63;
    if (node >= N_NODES) return;
    const uint2* xw64 = (const uint2*)xwb;   // 16 uint2 per node row
    int b = off[node], e = off[node + 1];
    int q = lane >> 4, c = lane & 15;
    float a0 = 0.f, a1 = 0.f, a2 = 0.f, a3 = 0.f;
    for (int i = b + q; i < e; i += 4) {
        unsigned u = epack[i];
        float ew = b2f((unsigned short)(u >> 16));
        uint2 wv = xw64[(u & 0xFFFFu) * 16 + c];
        a0 += ew * b2f((unsigned short)(wv.x & 0xFFFFu));
        a1 += ew * b2f((unsigned short)(wv.x >> 16));
        a2 += ew * b2f((unsigned short)(wv.y & 0xFFFFu));
        a3 += ew * b2f((unsigned short)(wv.y >> 16));
    }
    a0 += __shfl_xor(a0, 16); a0 += __shfl_xor(a0, 32);
    a1 += __shfl_xor(a1, 16); a1 += __shfl_xor(a1, 32);
    a2 += __shfl_xor(a2, 16); a2 += __shfl_xor(a2, 32);
    a3 += __shfl_xor(a3, 16); a3 += __shfl_xor(a3, 32);
    if (q == 0) {
        int f0 = 4 * c;
        float4 bv = *(const float4*)&bc[f0];
        ushort4 o;
        o.x = f2b(fmaxf(a0 + bv.x, 0.f));
        o.y = f2b(fmaxf(a1 + bv.y, 0.f));
        o.z = f2b(fmaxf(a2 + bv.z, 0.f));
        o.w = f2b(fmaxf(a3 + bv.w, 0.f));
        *(ushort4*)&hb[(size_t)node * 144 + 64 + f0] = o;
    }
}

// ---------------- classifier MFMA GEMM + log_softmax (no LDS) ----------------

__global__ __launch_bounds__(256) void k_cls(
    const unsigned short* __restrict__ hb,
    const unsigned short* __restrict__ Bw,
    const float* __restrict__ bfb,
    float* __restrict__ out) {
    int t = threadIdx.x;
    int wv = t >> 6, ln = t & 63;
    int tile = blockIdx.x * 4 + wv;
    if (tile >= 3125) return;
    int c = ln & 15, g = ln >> 4;
    int arow = tile * 16 + c;
    float bia[8];
    #pragma unroll
    for (int j = 0; j < 8; ++j) bia[j] = bfb[j * 16 + c];
    f32x4 acc[8];
    #pragma unroll
    for (int nt = 0; nt < 8; ++nt) acc[nt] = f32x4{0.f, 0.f, 0.f, 0.f};

    const bf16x8* bfrag = (const bf16x8*)(Bw + (size_t)ln * 8);
    #pragma unroll
    for (int ks = 0; ks < 5; ++ks) {
        int kb = ks * 32 + g * 8;
        bf16x8 a = {0, 0, 0, 0, 0, 0, 0, 0};
        if (kb < 144) a = *(const bf16x8*)(hb + (size_t)arow * 144 + kb);
        #pragma unroll
        for (int nt = 0; nt < 8; ++nt) {
            bf16x8 b = bfrag[(nt * 5 + ks) * 64];
            acc[nt] = __builtin_amdgcn_mfma_f32_16x16x32_bf16(a, b, acc[nt], 0, 0, 0);
        }
    }
    #pragma unroll
    for (int r = 0; r < 4; ++r) {
        float lg[8];
        #pragma unroll
        for (int nt = 0; nt < 8; ++nt) lg[nt] = acc[nt][r] + bia[nt];
        float m = lg[0];
        #pragma unroll
        for (int nt = 1; nt < 8; ++nt) m = fmaxf(m, lg[nt]);
        #pragma unroll
        for (int o = 1; o < 16; o <<= 1) m = fmaxf(m, __shfl_xor(m, o));
        float s = 0.f;
        #pragma unroll
        for (int nt = 0; nt < 8; ++nt) s += __expf(lg[nt] - m);
        #pragma unroll
        for (int o = 1; o < 16; o <<= 1) s += __shfl_xor(s, o);
        float ls = __logf(s) + m;
        int orow = tile * 16 + g * 4 + r;
        #pragma unroll
        for (int nt = 0; nt < 8; ++nt)
            out[(size_t)orow * 128 + nt * 16 + c] = lg[nt] - ls;
    }
}

// ---------------- launch ----------------

extern "C" void kernel_launch(void* const* d_in, const int* in_sizes, int n_in,
                              void* d_out, int out_size, void* d_ws, size_t ws_size,
                              hipStream_t stream) {
    const float* x   = (const float*)d_in[0];
    const int*   ei  = (const int*)d_in[1];
    const float* ea  = (const float*)d_in[2];
    const float* Wc1 = (const float*)d_in[3];
    const float* bc1 = (const float*)d_in[4];
    const float* Wc2 = (const float*)d_in[5];
    const float* bc2 = (const float*)d_in[6];
    const float* W11 = (const float*)d_in[7];
    const float* b11 = (const float*)d_in[8];
    const float* W12 = (const float*)d_in[9];
    const float* b12 = (const float*)d_in[10];
    const float* W13 = (const float*)d_in[11];
    const float* b13 = (const float*)d_in[12];
    const float* W21 = (const float*)d_in[13];
    const float* b21 = (const float*)d_in[14];
    const float* W22 = (const float*)d_in[15];
    const float* b22 = (const float*)d_in[16];
    const float* W23 = (const float*)d_in[17];
    const float* b23 = (const float*)d_in[18];
    const float* Wf  = (const float*)d_in[19];
    const float* bfb = (const float*)d_in[20];

    const int* esrc = ei;
    const int* edst = ei + N_EDGES;

    // xw bf16 [N][64] lives in d_out (6.4 MB; dead before k_cls writes out).
    unsigned short* xwb = (unsigned short*)d_out;

    // workspace carve — sized so epack/hb/B* are 16B-aligned:
    // off 50008 ints | cnt 50000 | bsum 200 | epack E | hb N*144 bf16 | B1/B2/Bc
    int*            off   = (int*)d_ws;
    int*            cnt   = off + 50008;
    int*            bsum  = cnt + 50000;
    unsigned*       epack = (unsigned*)(bsum + 200);
    unsigned short* hb    = (unsigned short*)(epack + N_EDGES);
    unsigned short* B1    = hb + (size_t)N_NODES * 144;          // 10240
    unsigned short* B2    = B1 + 10240;                          // 25600
    unsigned short* Bc    = B2 + 25600;                          // 20480

    hipMemsetAsync(off, 0, (size_t)(50008 + 50000) * sizeof(int), stream);
    k_prep <<<(10240 + 25600 + 20480 + 255) / 256, 256, 0, stream>>>(
        W11, Wc1, W12, W13, W21, Wc2, W22, W23, Wf, B1, B2, Bc);
    k_hist <<<(N_EDGES + 255) / 256, 256, 0, stream>>>(edst, off);
    k_scan1<<<SCAN_NB, 256, 0, stream>>>(off, bsum);
    k_scan2<<<1, 256, 0, stream>>>(bsum);
    k_scan3<<<SCAN_NB, 256, 0, stream>>>(off, bsum);
    k_place<<<(N_EDGES + 255) / 256, 256, 0, stream>>>(esrc, edst, ea, off, cnt, epack);

    const int GD = (3125 + 3) / 4;   // 782 blocks, 4 wave-tiles each
    k_dense<64> <<<GD, 256, 0, stream>>>(x, nullptr, B1, b11, b12, b13, hb, xwb);
    k_agg       <<<(N_NODES + 3) / 4, 256, 0, stream>>>(xwb, off, epack, bc1, hb);
    k_dense<144><<<GD, 256, 0, stream>>>(nullptr, hb, B2, b21, b22, b23, hb, xwb);
    k_agg       <<<(N_NODES + 3) / 4, 256, 0, stream>>>(xwb, off, epack, bc2, hb);
    k_cls       <<<GD, 256, 0, stream>>>(hb, Bc, bfb, (float*)d_out);
}

// Round 11
// 163.409 us; speedup vs baseline: 5.2499x; 1.2090x over previous
//
#include <hip/hip_runtime.h>
#include <hip/hip_bf16.h>

#define N_NODES 50000
#define N_EDGES 800000
#define NBUK 196          // buckets of 256 dst nodes: 196*256 = 50176 >= N
#define NBLK 196          // edge-chunk blocks: 196*4096 = 802816 >= E
#define EPB  4096

typedef __attribute__((ext_vector_type(8))) short bf16x8;   // MFMA A/B frag (4 VGPR)
typedef __attribute__((ext_vector_type(4))) float f32x4;    // MFMA C/D frag

// bf16 bit helpers (round-to-nearest-even pack, shift unpack)
__device__ __forceinline__ unsigned short f2b(float f) {
    unsigned u = __float_as_uint(f);
    return (unsigned short)((u + 0x7FFF + ((u >> 16) & 1)) >> 16);
}
__device__ __forceinline__ float b2f(unsigned short b) {
    return __uint_as_float(((unsigned)b) << 16);
}

// ---------------- CSR build via two-level bucket sort ----------------
// Replaces hist/scan/place: kills the 55MB write-allocate scatter (round-10 PMC).

// 1) per-(block,bucket) counts
__global__ __launch_bounds__(256) void k_cnt(const int* __restrict__ dst,
                                             int* __restrict__ cntM) {
    __shared__ int cl[NBUK];
    int t = threadIdx.x, blk = blockIdx.x;
    for (int i = t; i < NBUK; i += 256) cl[i] = 0;
    __syncthreads();
    int e0 = blk * EPB;
    #pragma unroll
    for (int r = 0; r < EPB / 256; ++r) {
        int e = e0 + r * 256 + t;
        if (e < N_EDGES) atomicAdd(&cl[dst[e] >> 8], 1);
    }
    __syncthreads();
    for (int i = t; i < NBUK; i += 256) cntM[blk * NBUK + i] = cl[i];
}

// 2) column scan (per bucket over blocks) in-place -> chunk bases; bucket bases
__global__ void k_colscan(int* __restrict__ cntM, int* __restrict__ ebase) {
    __shared__ int tot[256];
    __shared__ int wsum[4];
    int k = threadIdx.x;
    int run = 0;
    if (k < NBUK) {
        for (int b = 0; b < NBLK; ++b) {
            int c = cntM[b * NBUK + k];
            cntM[b * NBUK + k] = run;
            run += c;
        }
    }
    tot[k] = (k < NBUK) ? run : 0;
    __syncthreads();
    int v = tot[k];
    int lane = k & 63, wid = k >> 6;
    int incl = v;
    #pragma unroll
    for (int d = 1; d < 64; d <<= 1) {
        int u = __shfl_up(incl, d);
        if (lane >= d) incl += u;
    }
    if (lane == 63) wsum[wid] = incl;
    __syncthreads();
    int woff = 0;
    for (int w = 0; w < wid; ++w) woff += wsum[w];
    int excl = incl - v + woff;
    if (k < NBUK) ebase[k] = excl;
    if (k == 255) ebase[NBUK] = incl + woff;   // == N_EDGES
    __syncthreads();
    if (k < NBUK) {
        for (int b = 0; b < NBLK; ++b) cntM[b * NBUK + k] += excl;
    }
}

// 3) scatter edges into per-(block,bucket) contiguous chunks (line-dense writes)
__global__ __launch_bounds__(256) void k_bucketize(
    const int* __restrict__ src, const int* __restrict__ dst,
    const float* __restrict__ ea, const int* __restrict__ cntM,
    uint2* __restrict__ ebuf) {
    __shared__ int run[NBUK];
    int t = threadIdx.x, blk = blockIdx.x;
    for (int i = t; i < NBUK; i += 256) run[i] = 0;
    __syncthreads();
    int e0 = blk * EPB;
    #pragma unroll
    for (int r = 0; r < EPB / 256; ++r) {
        int e = e0 + r * 256 + t;
        if (e < N_EDGES) {
            int d = dst[e];
            int bk = d >> 8;
            int pos = atomicAdd(&run[bk], 1);
            int p = cntM[blk * NBUK + bk] + pos;
            ebuf[p] = make_uint2((((unsigned)f2b(ea[e])) << 16) | (unsigned)src[e],
                                 (unsigned)(d & 255));
        }
    }
}

// 4) per-bucket: local deg count + scan -> off[]; dst-sorted epack (hot window)
__global__ __launch_bounds__(256) void k_sub(
    const uint2* __restrict__ ebuf, const int* __restrict__ ebase,
    unsigned* __restrict__ epack, int* __restrict__ off) {
    __shared__ int deg[256], lofs[256], cnt[256];
    __shared__ int wsum[4];
    int t = threadIdx.x, b = blockIdx.x;
    deg[t] = 0; cnt[t] = 0;
    __syncthreads();
    int s = ebase[b], e = ebase[b + 1];
    for (int i = s + t; i < e; i += 256) atomicAdd(&deg[ebuf[i].y], 1);
    __syncthreads();
    int v = deg[t];
    int lane = t & 63, wid = t >> 6;
    int incl = v;
    #pragma unroll
    for (int d = 1; d < 64; d <<= 1) {
        int u = __shfl_up(incl, d);
        if (lane >= d) incl += u;
    }
    if (lane == 63) wsum[wid] = incl;
    __syncthreads();
    int woff = 0;
    for (int w = 0; w < wid; ++w) woff += wsum[w];
    lofs[t] = incl - v + woff;
    __syncthreads();
    int gd = b * 256 + t;
    if (gd < N_NODES) off[gd] = s + lofs[t];
    if (b == NBUK - 1 && t == 0) off[N_NODES] = N_EDGES;
    for (int i = s + t; i < e; i += 256) {
        uint2 u = ebuf[i];
        int ld = u.y;
        int pos = atomicAdd(&cnt[ld], 1);
        epack[s + lofs[ld] + pos] = u.x;
    }
}

// ---------------- weight prep: bf16 B-fragments in per-lane order ----------------
// frag layout: B[((nt*KS + ks)*64 + lane)*8 + i] = W(k, col)
//   k = ks*32 + (lane>>4)*8 + i, col = nt*16 + (lane&15); zero-fill k >= KREAL.

__global__ void k_prep(
    const float* __restrict__ W11, const float* __restrict__ Wc1,
    const float* __restrict__ W12, const float* __restrict__ W13,
    const float* __restrict__ W21, const float* __restrict__ Wc2,
    const float* __restrict__ W22, const float* __restrict__ W23,
    const float* __restrict__ Wf,
    unsigned short* __restrict__ B1, unsigned short* __restrict__ B2,
    unsigned short* __restrict__ Bc) {
    int idx = blockIdx.x * 256 + threadIdx.x;
    if (idx < 10240) {                       // B1: KS=2, K=64, 160 cols
        int i = idx & 7, l = (idx >> 3) & 63, ks = (idx >> 9) & 1, nt = idx >> 10;
        int k = ks * 32 + ((l >> 4) << 3) + i;
        int col = nt * 16 + (l & 15);
        float w = (col < 64) ? W11[k * 64 + col]
                : (col < 128) ? Wc1[k * 64 + col - 64]
                : (col < 144) ? W12[k * 16 + col - 128]
                              : W13[k * 16 + col - 144];
        B1[idx] = f2b(w);
    } else if (idx < 10240 + 25600) {        // B2: KS=5, K=144, 160 cols
        int j = idx - 10240;
        int i = j & 7, l = (j >> 3) & 63;
        int ks = (j >> 9) % 5, nt = j / 2560;
        int k = ks * 32 + ((l >> 4) << 3) + i;
        int col = nt * 16 + (l & 15);
        float w = 0.f;
        if (k < 144)
            w = (col < 64) ? W21[k * 64 + col]
              : (col < 128) ? Wc2[k * 64 + col - 64]
              : (col < 144) ? W22[k * 16 + col - 128]
                            : W23[k * 16 + col - 144];
        B2[j] = f2b(w);
    } else if (idx < 10240 + 25600 + 20480) { // Bc: KS=5, K=144, 128 cols
        int j = idx - 10240 - 25600;
        int i = j & 7, l = (j >> 3) & 63;
        int ks = (j >> 9) % 5, nt = j / 2560;
        int k = ks * 32 + ((l >> 4) << 3) + i;
        int col = nt * 16 + (l & 15);
        Bc[j] = (k < 144) ? f2b(Wf[k * 128 + col]) : (unsigned short)0;
    }
}

// ---------------- MFMA dense layers (no LDS, no barriers) ----------------
// 4 waves/block, wave owns one 16-row M-tile, 10 n-tiles of 16 cols.
// B-frags read from pre-built global layout (L2-broadcast, 1KB coalesced/wave).
// D-frag (verified m89/m91): col = lane&15, row = (lane>>4)*4 + reg.

template<int KREAL>
__global__ __launch_bounds__(256) void k_dense(
    const float* __restrict__ xf,              // KREAL=64: x f32 [N][64]
    const unsigned short* __restrict__ hb_in,  // KREAL=144: h bf16 [N][144]
    const unsigned short* __restrict__ Bw,     // frag-ordered weights
    const float* __restrict__ b1, const float* __restrict__ b2,
    const float* __restrict__ b3,
    unsigned short* __restrict__ hb,           // out: h cols 0-63, 128-143
    unsigned short* __restrict__ xwb) {        // out: xw bf16 [N][64]
    constexpr int KS = (KREAL + 31) / 32;      // 2 or 5
    int t = threadIdx.x;
    int wv = t >> 6, ln = t & 63;
    int tile = blockIdx.x * 4 + wv;
    if (tile >= 3125) return;                  // 50000 = 3125*16 exact
    int c = ln & 15, g = ln >> 4;
    int arow = tile * 16 + c;
    float bia[4];
    #pragma unroll
    for (int j = 0; j < 4; ++j) bia[j] = b1[j * 16 + c];
    float b8 = b2[c], b9 = b3[c];

    f32x4 acc[10];
    #pragma unroll
    for (int nt = 0; nt < 10; ++nt) acc[nt] = f32x4{0.f, 0.f, 0.f, 0.f};

    const bf16x8* bfrag = (const bf16x8*)(Bw + (size_t)ln * 8);
    #pragma unroll
    for (int ks = 0; ks < KS; ++ks) {
        int kb = ks * 32 + g * 8;
        bf16x8 a = {0, 0, 0, 0, 0, 0, 0, 0};
        if constexpr (KREAL == 64) {
            const float* rp = xf + (size_t)arow * 64 + kb;
            float4 q0 = *(const float4*)rp;
            float4 q1 = *(const float4*)(rp + 4);
            union { bf16x8 v; unsigned short u[8]; } af;
            af.u[0] = f2b(q0.x); af.u[1] = f2b(q0.y); af.u[2] = f2b(q0.z); af.u[3] = f2b(q0.w);
            af.u[4] = f2b(q1.x); af.u[5] = f2b(q1.y); af.u[6] = f2b(q1.z); af.u[7] = f2b(q1.w);
            a = af.v;
        } else {
            if (kb < 144) a = *(const bf16x8*)(hb_in + (size_t)arow * 144 + kb);
        }
        #pragma unroll
        for (int nt = 0; nt < 10; ++nt) {
            bf16x8 b = bfrag[(nt * KS + ks) * 64];
            acc[nt] = __builtin_amdgcn_mfma_f32_16x16x32_bf16(a, b, acc[nt], 0, 0, 0);
        }
    }
    #pragma unroll
    for (int r = 0; r < 4; ++r) {
        int orow = tile * 16 + g * 4 + r;
        size_t hbase = (size_t)orow * 144;
        #pragma unroll
        for (int nt = 0; nt < 4; ++nt)
            hb[hbase + nt * 16 + c] = f2b(fmaxf(acc[nt][r] + bia[nt], 0.f));
        #pragma unroll
        for (int nt = 4; nt < 8; ++nt)
            xwb[(size_t)orow * 64 + (nt - 4) * 16 + c] = f2b(acc[nt][r]);
        float p = fmaxf(acc[8][r] + b8, 0.f) * fmaxf(acc[9][r] + b9, 0.f);
        hb[hbase + 128 + c] = f2b(p);
    }
}

// ---------------- aggregation: wave per dst node, 4 edges/iter ----------------

__global__ __launch_bounds__(256) void k_agg(
    const unsigned short* __restrict__ xwb, const int* __restrict__ off,
    const unsigned* __restrict__ epack,
    const float* __restrict__ bc, unsigned short* __restrict__ hb) {
    int node = blockIdx.x * 4 + (threadIdx.x >> 6);
    int lane = threadIdx.x & 63;
    if (node >= N_NODES) return;
    const uint2* xw64 = (const uint2*)xwb;   // 16 uint2 per node row
    int b = off[node], e = off[node + 1];
    int q = lane >> 4, c = lane & 15;
    float a0 = 0.f, a1 = 0.f, a2 = 0.f, a3 = 0.f;
    for (int i = b + q; i < e; i += 4) {
        unsigned u = epack[i];
        float ew = b2f((unsigned short)(u >> 16));
        uint2 wv = xw64[(u & 0xFFFFu) * 16 + c];
        a0 += ew * b2f((unsigned short)(wv.x & 0xFFFFu));
        a1 += ew * b2f((unsigned short)(wv.x >> 16));
        a2 += ew * b2f((unsigned short)(wv.y & 0xFFFFu));
        a3 += ew * b2f((unsigned short)(wv.y >> 16));
    }
    a0 += __shfl_xor(a0, 16); a0 += __shfl_xor(a0, 32);
    a1 += __shfl_xor(a1, 16); a1 += __shfl_xor(a1, 32);
    a2 += __shfl_xor(a2, 16); a2 += __shfl_xor(a2, 32);
    a3 += __shfl_xor(a3, 16); a3 += __shfl_xor(a3, 32);
    if (q == 0) {
        int f0 = 4 * c;
        float4 bv = *(const float4*)&bc[f0];
        ushort4 o;
        o.x = f2b(fmaxf(a0 + bv.x, 0.f));
        o.y = f2b(fmaxf(a1 + bv.y, 0.f));
        o.z = f2b(fmaxf(a2 + bv.z, 0.f));
        o.w = f2b(fmaxf(a3 + bv.w, 0.f));
        *(ushort4*)&hb[(size_t)node * 144 + 64 + f0] = o;
    }
}

// ---------------- classifier MFMA GEMM + log_softmax (no LDS) ----------------

__global__ __launch_bounds__(256) void k_cls(
    const unsigned short* __restrict__ hb,
    const unsigned short* __restrict__ Bw,
    const float* __restrict__ bfb,
    float* __restrict__ out) {
    int t = threadIdx.x;
    int wv = t >> 6, ln = t & 63;
    int tile = blockIdx.x * 4 + wv;
    if (tile >= 3125) return;
    int c = ln & 15, g = ln >> 4;
    int arow = tile * 16 + c;
    float bia[8];
    #pragma unroll
    for (int j = 0; j < 8; ++j) bia[j] = bfb[j * 16 + c];
    f32x4 acc[8];
    #pragma unroll
    for (int nt = 0; nt < 8; ++nt) acc[nt] = f32x4{0.f, 0.f, 0.f, 0.f};

    const bf16x8* bfrag = (const bf16x8*)(Bw + (size_t)ln * 8);
    #pragma unroll
    for (int ks = 0; ks < 5; ++ks) {
        int kb = ks * 32 + g * 8;
        bf16x8 a = {0, 0, 0, 0, 0, 0, 0, 0};
        if (kb < 144) a = *(const bf16x8*)(hb + (size_t)arow * 144 + kb);
        #pragma unroll
        for (int nt = 0; nt < 8; ++nt) {
            bf16x8 b = bfrag[(nt * 5 + ks) * 64];
            acc[nt] = __builtin_amdgcn_mfma_f32_16x16x32_bf16(a, b, acc[nt], 0, 0, 0);
        }
    }
    #pragma unroll
    for (int r = 0; r < 4; ++r) {
        float lg[8];
        #pragma unroll
        for (int nt = 0; nt < 8; ++nt) lg[nt] = acc[nt][r] + bia[nt];
        float m = lg[0];
        #pragma unroll
        for (int nt = 1; nt < 8; ++nt) m = fmaxf(m, lg[nt]);
        #pragma unroll
        for (int o = 1; o < 16; o <<= 1) m = fmaxf(m, __shfl_xor(m, o));
        float s = 0.f;
        #pragma unroll
        for (int nt = 0; nt < 8; ++nt) s += __expf(lg[nt] - m);
        #pragma unroll
        for (int o = 1; o < 16; o <<= 1) s += __shfl_xor(s, o);
        float ls = __logf(s) + m;
        int orow = tile * 16 + g * 4 + r;
        #pragma unroll
        for (int nt = 0; nt < 8; ++nt)
            out[(size_t)orow * 128 + nt * 16 + c] = lg[nt] - ls;
    }
}

// ---------------- launch ----------------

extern "C" void kernel_launch(void* const* d_in, const int* in_sizes, int n_in,
                              void* d_out, int out_size, void* d_ws, size_t ws_size,
                              hipStream_t stream) {
    const float* x   = (const float*)d_in[0];
    const int*   ei  = (const int*)d_in[1];
    const float* ea  = (const float*)d_in[2];
    const float* Wc1 = (const float*)d_in[3];
    const float* bc1 = (const float*)d_in[4];
    const float* Wc2 = (const float*)d_in[5];
    const float* bc2 = (const float*)d_in[6];
    const float* W11 = (const float*)d_in[7];
    const float* b11 = (const float*)d_in[8];
    const float* W12 = (const float*)d_in[9];
    const float* b12 = (const float*)d_in[10];
    const float* W13 = (const float*)d_in[11];
    const float* b13 = (const float*)d_in[12];
    const float* W21 = (const float*)d_in[13];
    const float* b21 = (const float*)d_in[14];
    const float* W22 = (const float*)d_in[15];
    const float* b22 = (const float*)d_in[16];
    const float* W23 = (const float*)d_in[17];
    const float* b23 = (const float*)d_in[18];
    const float* Wf  = (const float*)d_in[19];
    const float* bfb = (const float*)d_in[20];

    const int* esrc = ei;
    const int* edst = ei + N_EDGES;

    // xw bf16 [N][64] lives in d_out (6.4 MB; dead before k_cls writes out).
    unsigned short* xwb = (unsigned short*)d_out;

    // workspace carve (16B-alignment maintained for ebuf/hb/B*):
    // off 50008 | cntM 196*196 | ebase 200 | ebuf uint2[E] | epack u32[E] | hb | B1/B2/Bc
    int*            off   = (int*)d_ws;                          // 50008 ints
    int*            cntM  = off + 50008;                         // 38416 ints
    int*            ebase = cntM + NBLK * NBUK;                  // 200 ints
    uint2*          ebuf  = (uint2*)(ebase + 200);               // E * 8B
    unsigned*       epack = (unsigned*)(ebuf + N_EDGES);         // E * 4B
    unsigned short* hb    = (unsigned short*)(epack + N_EDGES);  // N*144 bf16
    unsigned short* B1    = hb + (size_t)N_NODES * 144;          // 10240
    unsigned short* B2    = B1 + 10240;                          // 25600
    unsigned short* Bc    = B2 + 25600;                          // 20480

    k_prep     <<<(10240 + 25600 + 20480 + 255) / 256, 256, 0, stream>>>(
        W11, Wc1, W12, W13, W21, Wc2, W22, W23, Wf, B1, B2, Bc);
    k_cnt      <<<NBLK, 256, 0, stream>>>(edst, cntM);
    k_colscan  <<<1, 256, 0, stream>>>(cntM, ebase);
    k_bucketize<<<NBLK, 256, 0, stream>>>(esrc, edst, ea, cntM, ebuf);
    k_sub      <<<NBUK, 256, 0, stream>>>(ebuf, ebase, epack, off);

    const int GD = (3125 + 3) / 4;   // 782 blocks, 4 wave-tiles each
    k_dense<64> <<<GD, 256, 0, stream>>>(x, nullptr, B1, b11, b12, b13, hb, xwb);
    k_agg       <<<(N_NODES + 3) / 4, 256, 0, stream>>>(xwb, off, epack, bc1, hb);
    k_dense<144><<<GD, 256, 0, stream>>>(nullptr, hb, B2, b21, b22, b23, hb, xwb);
    k_agg       <<<(N_NODES + 3) / 4, 256, 0, stream>>>(xwb, off, epack, bc2, hb);
    k_cls       <<<GD, 256, 0, stream>>>(hb, Bc, bfb, (float*)d_out);
}

// Round 12
// 143.463 us; speedup vs baseline: 5.9798x; 1.1390x over previous
//
#include <hip/hip_runtime.h>
#include <hip/hip_bf16.h>

#define N_NODES 50000
#define N_EDGES 800000
#define NBUK 196          // buckets of 256 dst nodes: 196*256 = 50176 >= N
#define NBLK 196          // edge-chunk blocks: 196*4096 = 802816 >= E
#define EPB  4096
#define PREP_NB 220       // (10240+25600+20480+255)/256

typedef __attribute__((ext_vector_type(8))) short bf16x8;   // MFMA A/B frag (4 VGPR)
typedef __attribute__((ext_vector_type(4))) float f32x4;    // MFMA C/D frag

// bf16 bit helpers (round-to-nearest-even pack, shift unpack)
__device__ __forceinline__ unsigned short f2b(float f) {
    unsigned u = __float_as_uint(f);
    return (unsigned short)((u + 0x7FFF + ((u >> 16) & 1)) >> 16);
}
__device__ __forceinline__ float b2f(unsigned short b) {
    return __uint_as_float(((unsigned)b) << 16);
}

// ---------------- CSR build via two-level bucket sort ----------------
// (kills the 55MB write-allocate scatter; round-10 PMC evidence)

// 1) per-(block,bucket) counts; blocks >= NBLK do weight-fragment prep
__global__ __launch_bounds__(256) void k_cnt(
    const int* __restrict__ dst, int* __restrict__ cntM,
    const float* __restrict__ W11, const float* __restrict__ Wc1,
    const float* __restrict__ W12, const float* __restrict__ W13,
    const float* __restrict__ W21, const float* __restrict__ Wc2,
    const float* __restrict__ W22, const float* __restrict__ W23,
    const float* __restrict__ Wf,
    unsigned short* __restrict__ B1, unsigned short* __restrict__ B2,
    unsigned short* __restrict__ Bc) {
    int t = threadIdx.x, blk = blockIdx.x;
    if (blk >= NBLK) {
        // ---- weight prep: B[((nt*KS+ks)*64+lane)*8+i] = W(k, col),
        //      k = ks*32 + (lane>>4)*8 + i, col = nt*16 + (lane&15)
        int idx = (blk - NBLK) * 256 + t;
        if (idx < 10240) {                       // B1: KS=2, K=64, 160 cols
            int i = idx & 7, l = (idx >> 3) & 63, ks = (idx >> 9) & 1, nt = idx >> 10;
            int k = ks * 32 + ((l >> 4) << 3) + i;
            int col = nt * 16 + (l & 15);
            float w = (col < 64) ? W11[k * 64 + col]
                    : (col < 128) ? Wc1[k * 64 + col - 64]
                    : (col < 144) ? W12[k * 16 + col - 128]
                                  : W13[k * 16 + col - 144];
            B1[idx] = f2b(w);
        } else if (idx < 10240 + 25600) {        // B2: KS=5, K=144, 160 cols
            int j = idx - 10240;
            int i = j & 7, l = (j >> 3) & 63;
            int ks = (j >> 9) % 5, nt = j / 2560;
            int k = ks * 32 + ((l >> 4) << 3) + i;
            int col = nt * 16 + (l & 15);
            float w = 0.f;
            if (k < 144)
                w = (col < 64) ? W21[k * 64 + col]
                  : (col < 128) ? Wc2[k * 64 + col - 64]
                  : (col < 144) ? W22[k * 16 + col - 128]
                                : W23[k * 16 + col - 144];
            B2[j] = f2b(w);
        } else if (idx < 10240 + 25600 + 20480) { // Bc: KS=5, K=144, 128 cols
            int j = idx - 10240 - 25600;
            int i = j & 7, l = (j >> 3) & 63;
            int ks = (j >> 9) % 5, nt = j / 2560;
            int k = ks * 32 + ((l >> 4) << 3) + i;
            int col = nt * 16 + (l & 15);
            Bc[j] = (k < 144) ? f2b(Wf[k * 128 + col]) : (unsigned short)0;
        }
        return;
    }
    __shared__ int cl[NBUK];
    for (int i = t; i < NBUK; i += 256) cl[i] = 0;
    __syncthreads();
    int e0 = blk * EPB;
    #pragma unroll
    for (int r = 0; r < EPB / 256; ++r) {
        int e = e0 + r * 256 + t;
        if (e < N_EDGES) atomicAdd(&cl[dst[e] >> 8], 1);
    }
    __syncthreads();
    for (int i = t; i < NBUK; i += 256) cntM[blk * NBUK + i] = cl[i];
}

// 2) column scan (per bucket over blocks) in-place -> chunk bases; bucket bases
__global__ void k_colscan(int* __restrict__ cntM, int* __restrict__ ebase) {
    __shared__ int tot[256];
    __shared__ int wsum[4];
    int k = threadIdx.x;
    int run = 0;
    if (k < NBUK) {
        for (int b = 0; b < NBLK; ++b) {
            int c = cntM[b * NBUK + k];
            cntM[b * NBUK + k] = run;
            run += c;
        }
    }
    tot[k] = (k < NBUK) ? run : 0;
    __syncthreads();
    int v = tot[k];
    int lane = k & 63, wid = k >> 6;
    int incl = v;
    #pragma unroll
    for (int d = 1; d < 64; d <<= 1) {
        int u = __shfl_up(incl, d);
        if (lane >= d) incl += u;
    }
    if (lane == 63) wsum[wid] = incl;
    __syncthreads();
    int woff = 0;
    for (int w = 0; w < wid; ++w) woff += wsum[w];
    int excl = incl - v + woff;
    if (k < NBUK) ebase[k] = excl;
    if (k == 255) ebase[NBUK] = incl + woff;   // == N_EDGES
    __syncthreads();
    if (k < NBUK) {
        for (int b = 0; b < NBLK; ++b) cntM[b * NBUK + k] += excl;
    }
}

// 3) scatter edges into per-(block,bucket) contiguous chunks (line-dense writes)
__global__ __launch_bounds__(256) void k_bucketize(
    const int* __restrict__ src, const int* __restrict__ dst,
    const float* __restrict__ ea, const int* __restrict__ cntM,
    uint2* __restrict__ ebuf) {
    __shared__ int run[NBUK];
    int t = threadIdx.x, blk = blockIdx.x;
    for (int i = t; i < NBUK; i += 256) run[i] = 0;
    __syncthreads();
    int e0 = blk * EPB;
    #pragma unroll
    for (int r = 0; r < EPB / 256; ++r) {
        int e = e0 + r * 256 + t;
        if (e < N_EDGES) {
            int d = dst[e];
            int bk = d >> 8;
            int pos = atomicAdd(&run[bk], 1);
            int p = cntM[blk * NBUK + bk] + pos;
            ebuf[p] = make_uint2((((unsigned)f2b(ea[e])) << 16) | (unsigned)src[e],
                                 (unsigned)(d & 255));
        }
    }
}

// 4) per-bucket: local deg count + scan -> off[]; dst-sorted epack (hot window)
__global__ __launch_bounds__(256) void k_sub(
    const uint2* __restrict__ ebuf, const int* __restrict__ ebase,
    unsigned* __restrict__ epack, int* __restrict__ off) {
    __shared__ int deg[256], lofs[256], cnt[256];
    __shared__ int wsum[4];
    int t = threadIdx.x, b = blockIdx.x;
    deg[t] = 0; cnt[t] = 0;
    __syncthreads();
    int s = ebase[b], e = ebase[b + 1];
    for (int i = s + t; i < e; i += 256) atomicAdd(&deg[ebuf[i].y], 1);
    __syncthreads();
    int v = deg[t];
    int lane = t & 63, wid = t >> 6;
    int incl = v;
    #pragma unroll
    for (int d = 1; d < 64; d <<= 1) {
        int u = __shfl_up(incl, d);
        if (lane >= d) incl += u;
    }
    if (lane == 63) wsum[wid] = incl;
    __syncthreads();
    int woff = 0;
    for (int w = 0; w < wid; ++w) woff += wsum[w];
    lofs[t] = incl - v + woff;
    __syncthreads();
    int gd = b * 256 + t;
    if (gd < N_NODES) off[gd] = s + lofs[t];
    if (b == NBUK - 1 && t == 0) off[N_NODES] = N_EDGES;
    for (int i = s + t; i < e; i += 256) {
        uint2 u = ebuf[i];
        int ld = u.y;
        int pos = atomicAdd(&cnt[ld], 1);
        epack[s + lofs[ld] + pos] = u.x;
    }
}

// ---------------- MFMA dense layers (no LDS, no barriers) ----------------
// 4 waves/block, wave owns one 16-row M-tile, 10 n-tiles of 16 cols.
// B-frags read from pre-built global layout (L2-broadcast, 1KB coalesced/wave).
// D-frag (verified m89/m91): col = lane&15, row = (lane>>4)*4 + reg.

template<int KREAL>
__global__ __launch_bounds__(256) void k_dense(
    const float* __restrict__ xf,              // KREAL=64: x f32 [N][64]
    const unsigned short* __restrict__ hb_in,  // KREAL=144: h bf16 [N][144]
    const unsigned short* __restrict__ Bw,     // frag-ordered weights
    const float* __restrict__ b1, const float* __restrict__ b2,
    const float* __restrict__ b3,
    unsigned short* __restrict__ hb,           // out: h cols 0-63, 128-143
    unsigned short* __restrict__ xwb) {        // out: xw bf16 [N][64]
    constexpr int KS = (KREAL + 31) / 32;      // 2 or 5
    int t = threadIdx.x;
    int wv = t >> 6, ln = t & 63;
    int tile = blockIdx.x * 4 + wv;
    if (tile >= 3125) return;                  // 50000 = 3125*16 exact
    int c = ln & 15, g = ln >> 4;
    int arow = tile * 16 + c;
    float bia[4];
    #pragma unroll
    for (int j = 0; j < 4; ++j) bia[j] = b1[j * 16 + c];
    float b8 = b2[c], b9 = b3[c];

    f32x4 acc[10];
    #pragma unroll
    for (int nt = 0; nt < 10; ++nt) acc[nt] = f32x4{0.f, 0.f, 0.f, 0.f};

    const bf16x8* bfrag = (const bf16x8*)(Bw + (size_t)ln * 8);
    #pragma unroll
    for (int ks = 0; ks < KS; ++ks) {
        int kb = ks * 32 + g * 8;
        bf16x8 a = {0, 0, 0, 0, 0, 0, 0, 0};
        if constexpr (KREAL == 64) {
            const float* rp = xf + (size_t)arow * 64 + kb;
            float4 q0 = *(const float4*)rp;
            float4 q1 = *(const float4*)(rp + 4);
            union { bf16x8 v; unsigned short u[8]; } af;
            af.u[0] = f2b(q0.x); af.u[1] = f2b(q0.y); af.u[2] = f2b(q0.z); af.u[3] = f2b(q0.w);
            af.u[4] = f2b(q1.x); af.u[5] = f2b(q1.y); af.u[6] = f2b(q1.z); af.u[7] = f2b(q1.w);
            a = af.v;
        } else {
            if (kb < 144) a = *(const bf16x8*)(hb_in + (size_t)arow * 144 + kb);
        }
        #pragma unroll
        for (int nt = 0; nt < 10; ++nt) {
            bf16x8 b = bfrag[(nt * KS + ks) * 64];
            acc[nt] = __builtin_amdgcn_mfma_f32_16x16x32_bf16(a, b, acc[nt], 0, 0, 0);
        }
    }
    #pragma unroll
    for (int r = 0; r < 4; ++r) {
        int orow = tile * 16 + g * 4 + r;
        size_t hbase = (size_t)orow * 144;
        #pragma unroll
        for (int nt = 0; nt < 4; ++nt)
            hb[hbase + nt * 16 + c] = f2b(fmaxf(acc[nt][r] + bia[nt], 0.f));
        #pragma unroll
        for (int nt = 4; nt < 8; ++nt)
            xwb[(size_t)orow * 64 + (nt - 4) * 16 + c] = f2b(acc[nt][r]);
        float p = fmaxf(acc[8][r] + b8, 0.f) * fmaxf(acc[9][r] + b9, 0.f);
        hb[hbase + 128 + c] = f2b(p);
    }
}

// ---------------- aggregation: wave per dst node, 8 edges/iter, 2x unroll ----
// octet q = lane>>3 handles edge b+i*8+q; 8 lanes x uint4 (8 bf16 feats)/edge.
// Up to 16 gathers in flight per wave before first use (MLP fix, round-11 PMC).

__global__ __launch_bounds__(256) void k_agg(
    const unsigned short* __restrict__ xwb, const int* __restrict__ off,
    const unsigned* __restrict__ epack,
    const float* __restrict__ bc, unsigned short* __restrict__ hb) {
    int node = blockIdx.x * 4 + (threadIdx.x >> 6);
    int lane = threadIdx.x & 63;
    if (node >= N_NODES) return;
    const uint4* xw128 = (const uint4*)xwb;   // 8 uint4 per node row
    int b = off[node], e = off[node + 1];
    int q = lane >> 3, c = lane & 7;
    float a[8] = {0.f, 0.f, 0.f, 0.f, 0.f, 0.f, 0.f, 0.f};
    int i = b + q;
    for (; i + 8 < e; i += 16) {
        unsigned u0 = epack[i];
        unsigned u1 = epack[i + 8];
        uint4 w0 = xw128[(u0 & 0xFFFFu) * 8 + c];
        uint4 w1 = xw128[(u1 & 0xFFFFu) * 8 + c];
        float e0 = b2f((unsigned short)(u0 >> 16));
        float e1 = b2f((unsigned short)(u1 >> 16));
        a[0] += e0 * b2f((unsigned short)(w0.x & 0xFFFFu));
        a[1] += e0 * b2f((unsigned short)(w0.x >> 16));
        a[2] += e0 * b2f((unsigned short)(w0.y & 0xFFFFu));
        a[3] += e0 * b2f((unsigned short)(w0.y >> 16));
        a[4] += e0 * b2f((unsigned short)(w0.z & 0xFFFFu));
        a[5] += e0 * b2f((unsigned short)(w0.z >> 16));
        a[6] += e0 * b2f((unsigned short)(w0.w & 0xFFFFu));
        a[7] += e0 * b2f((unsigned short)(w0.w >> 16));
        a[0] += e1 * b2f((unsigned short)(w1.x & 0xFFFFu));
        a[1] += e1 * b2f((unsigned short)(w1.x >> 16));
        a[2] += e1 * b2f((unsigned short)(w1.y & 0xFFFFu));
        a[3] += e1 * b2f((unsigned short)(w1.y >> 16));
        a[4] += e1 * b2f((unsigned short)(w1.z & 0xFFFFu));
        a[5] += e1 * b2f((unsigned short)(w1.z >> 16));
        a[6] += e1 * b2f((unsigned short)(w1.w & 0xFFFFu));
        a[7] += e1 * b2f((unsigned short)(w1.w >> 16));
    }
    if (i < e) {
        unsigned u0 = epack[i];
        uint4 w0 = xw128[(u0 & 0xFFFFu) * 8 + c];
        float e0 = b2f((unsigned short)(u0 >> 16));
        a[0] += e0 * b2f((unsigned short)(w0.x & 0xFFFFu));
        a[1] += e0 * b2f((unsigned short)(w0.x >> 16));
        a[2] += e0 * b2f((unsigned short)(w0.y & 0xFFFFu));
        a[3] += e0 * b2f((unsigned short)(w0.y >> 16));
        a[4] += e0 * b2f((unsigned short)(w0.z & 0xFFFFu));
        a[5] += e0 * b2f((unsigned short)(w0.z >> 16));
        a[6] += e0 * b2f((unsigned short)(w0.w & 0xFFFFu));
        a[7] += e0 * b2f((unsigned short)(w0.w >> 16));
    }
    #pragma unroll
    for (int j = 0; j < 8; ++j) {
        a[j] += __shfl_xor(a[j], 8);
        a[j] += __shfl_xor(a[j], 16);
        a[j] += __shfl_xor(a[j], 32);
    }
    if (q == 0) {
        int f0 = 8 * c;
        float4 bv0 = *(const float4*)&bc[f0];
        float4 bv1 = *(const float4*)&bc[f0 + 4];
        union { uint4 v; unsigned short u[8]; } o;
        o.u[0] = f2b(fmaxf(a[0] + bv0.x, 0.f));
        o.u[1] = f2b(fmaxf(a[1] + bv0.y, 0.f));
        o.u[2] = f2b(fmaxf(a[2] + bv0.z, 0.f));
        o.u[3] = f2b(fmaxf(a[3] + bv0.w, 0.f));
        o.u[4] = f2b(fmaxf(a[4] + bv1.x, 0.f));
        o.u[5] = f2b(fmaxf(a[5] + bv1.y, 0.f));
        o.u[6] = f2b(fmaxf(a[6] + bv1.z, 0.f));
        o.u[7] = f2b(fmaxf(a[7] + bv1.w, 0.f));
        *(uint4*)&hb[(size_t)node * 144 + 64 + f0] = o.v;
    }
}

// ---------------- classifier MFMA GEMM + log_softmax (no LDS) ----------------

__global__ __launch_bounds__(256) void k_cls(
    const unsigned short* __restrict__ hb,
    const unsigned short* __restrict__ Bw,
    const float* __restrict__ bfb,
    float* __restrict__ out) {
    int t = threadIdx.x;
    int wv = t >> 6, ln = t & 63;
    int tile = blockIdx.x * 4 + wv;
    if (tile >= 3125) return;
    int c = ln & 15, g = ln >> 4;
    int arow = tile * 16 + c;
    float bia[8];
    #pragma unroll
    for (int j = 0; j < 8; ++j) bia[j] = bfb[j * 16 + c];
    f32x4 acc[8];
    #pragma unroll
    for (int nt = 0; nt < 8; ++nt) acc[nt] = f32x4{0.f, 0.f, 0.f, 0.f};

    const bf16x8* bfrag = (const bf16x8*)(Bw + (size_t)ln * 8);
    #pragma unroll
    for (int ks = 0; ks < 5; ++ks) {
        int kb = ks * 32 + g * 8;
        bf16x8 a = {0, 0, 0, 0, 0, 0, 0, 0};
        if (kb < 144) a = *(const bf16x8*)(hb + (size_t)arow * 144 + kb);
        #pragma unroll
        for (int nt = 0; nt < 8; ++nt) {
            bf16x8 b = bfrag[(nt * 5 + ks) * 64];
            acc[nt] = __builtin_amdgcn_mfma_f32_16x16x32_bf16(a, b, acc[nt], 0, 0, 0);
        }
    }
    #pragma unroll
    for (int r = 0; r < 4; ++r) {
        float lg[8];
        #pragma unroll
        for (int nt = 0; nt < 8; ++nt) lg[nt] = acc[nt][r] + bia[nt];
        float m = lg[0];
        #pragma unroll
        for (int nt = 1; nt < 8; ++nt) m = fmaxf(m, lg[nt]);
        #pragma unroll
        for (int o = 1; o < 16; o <<= 1) m = fmaxf(m, __shfl_xor(m, o));
        float s = 0.f;
        #pragma unroll
        for (int nt = 0; nt < 8; ++nt) s += __expf(lg[nt] - m);
        #pragma unroll
        for (int o = 1; o < 16; o <<= 1) s += __shfl_xor(s, o);
        float ls = __logf(s) + m;
        int orow = tile * 16 + g * 4 + r;
        #pragma unroll
        for (int nt = 0; nt < 8; ++nt)
            out[(size_t)orow * 128 + nt * 16 + c] = lg[nt] - ls;
    }
}

// ---------------- launch ----------------

extern "C" void kernel_launch(void* const* d_in, const int* in_sizes, int n_in,
                              void* d_out, int out_size, void* d_ws, size_t ws_size,
                              hipStream_t stream) {
    const float* x   = (const float*)d_in[0];
    const int*   ei  = (const int*)d_in[1];
    const float* ea  = (const float*)d_in[2];
    const float* Wc1 = (const float*)d_in[3];
    const float* bc1 = (const float*)d_in[4];
    const float* Wc2 = (const float*)d_in[5];
    const float* bc2 = (const float*)d_in[6];
    const float* W11 = (const float*)d_in[7];
    const float* b11 = (const float*)d_in[8];
    const float* W12 = (const float*)d_in[9];
    const float* b12 = (const float*)d_in[10];
    const float* W13 = (const float*)d_in[11];
    const float* b13 = (const float*)d_in[12];
    const float* W21 = (const float*)d_in[13];
    const float* b21 = (const float*)d_in[14];
    const float* W22 = (const float*)d_in[15];
    const float* b22 = (const float*)d_in[16];
    const float* W23 = (const float*)d_in[17];
    const float* b23 = (const float*)d_in[18];
    const float* Wf  = (const float*)d_in[19];
    const float* bfb = (const float*)d_in[20];

    const int* esrc = ei;
    const int* edst = ei + N_EDGES;

    // xw bf16 [N][64] lives in d_out (6.4 MB; dead before k_cls writes out).
    unsigned short* xwb = (unsigned short*)d_out;

    // workspace carve (16B-alignment maintained for ebuf/hb/B*):
    int*            off   = (int*)d_ws;                          // 50008 ints
    int*            cntM  = off + 50008;                         // 38416 ints
    int*            ebase = cntM + NBLK * NBUK;                  // 200 ints
    uint2*          ebuf  = (uint2*)(ebase + 200);               // E * 8B
    unsigned*       epack = (unsigned*)(ebuf + N_EDGES);         // E * 4B
    unsigned short* hb    = (unsigned short*)(epack + N_EDGES);  // N*144 bf16
    unsigned short* B1    = hb + (size_t)N_NODES * 144;          // 10240
    unsigned short* B2    = B1 + 10240;                          // 25600
    unsigned short* Bc    = B2 + 25600;                          // 20480

    k_cnt      <<<NBLK + PREP_NB, 256, 0, stream>>>(edst, cntM,
        W11, Wc1, W12, W13, W21, Wc2, W22, W23, Wf, B1, B2, Bc);
    k_colscan  <<<1, 256, 0, stream>>>(cntM, ebase);
    k_bucketize<<<NBLK, 256, 0, stream>>>(esrc, edst, ea, cntM, ebuf);
    k_sub      <<<NBUK, 256, 0, stream>>>(ebuf, ebase, epack, off);

    const int GD = (3125 + 3) / 4;   // 782 blocks, 4 wave-tiles each
    k_dense<64> <<<GD, 256, 0, stream>>>(x, nullptr, B1, b11, b12, b13, hb, xwb);
    k_agg       <<<(N_NODES + 3) / 4, 256, 0, stream>>>(xwb, off, epack, bc1, hb);
    k_dense<144><<<GD, 256, 0, stream>>>(nullptr, hb, B2, b21, b22, b23, hb, xwb);
    k_agg       <<<(N_NODES + 3) / 4, 256, 0, stream>>>(xwb, off, epack, bc2, hb);
    k_cls       <<<GD, 256, 0, stream>>>(hb, Bc, bfb, (float*)d_out);
}

// Round 13
// 136.980 us; speedup vs baseline: 6.2628x; 1.0473x over previous
//
#include <hip/hip_runtime.h>
#include <hip/hip_bf16.h>

#define N_NODES 50000
#define N_EDGES 800000
#define NBUK 196          // buckets of 256 dst nodes: 196*256 = 50176 >= N
#define NBLK 196          // edge-chunk blocks: 196*4096 = 802816 >= E
#define EPB  4096
#define PREP_NB 220       // (10240+25600+20480+255)/256
#define GD 782            // dense grid: 782*4 wave-tiles >= 3125

typedef __attribute__((ext_vector_type(8))) short bf16x8;   // MFMA A/B frag (4 VGPR)
typedef __attribute__((ext_vector_type(4))) float f32x4;    // MFMA C/D frag

// bf16 bit helpers (round-to-nearest-even pack, shift unpack)
__device__ __forceinline__ unsigned short f2b(float f) {
    unsigned u = __float_as_uint(f);
    return (unsigned short)((u + 0x7FFF + ((u >> 16) & 1)) >> 16);
}
__device__ __forceinline__ float b2f(unsigned short b) {
    return __uint_as_float(((unsigned)b) << 16);
}

// ---------------- MFMA dense body (shared by merged kernel and k_dense<144>) ----
// Wave owns one 16-row M-tile, 10 n-tiles of 16 cols. B-frags from pre-built
// global layout (L2-broadcast). D-frag (verified m89/m91): col=lane&15,
// row=(lane>>4)*4+reg.

template<int KREAL>
__device__ __forceinline__ void dense_body(
    int tile, int ln,
    const float* __restrict__ xf, const unsigned short* __restrict__ hb_in,
    const unsigned short* __restrict__ Bw,
    const float* __restrict__ b1, const float* __restrict__ b2,
    const float* __restrict__ b3,
    unsigned short* __restrict__ hb, unsigned short* __restrict__ xwb) {
    constexpr int KS = (KREAL + 31) / 32;      // 2 or 5
    if (tile >= 3125) return;                  // 50000 = 3125*16 exact
    int c = ln & 15, g = ln >> 4;
    int arow = tile * 16 + c;
    float bia[4];
    #pragma unroll
    for (int j = 0; j < 4; ++j) bia[j] = b1[j * 16 + c];
    float b8 = b2[c], b9 = b3[c];

    f32x4 acc[10];
    #pragma unroll
    for (int nt = 0; nt < 10; ++nt) acc[nt] = f32x4{0.f, 0.f, 0.f, 0.f};

    const bf16x8* bfrag = (const bf16x8*)(Bw + (size_t)ln * 8);
    #pragma unroll
    for (int ks = 0; ks < KS; ++ks) {
        int kb = ks * 32 + g * 8;
        bf16x8 a = {0, 0, 0, 0, 0, 0, 0, 0};
        if constexpr (KREAL == 64) {
            const float* rp = xf + (size_t)arow * 64 + kb;
            float4 q0 = *(const float4*)rp;
            float4 q1 = *(const float4*)(rp + 4);
            union { bf16x8 v; unsigned short u[8]; } af;
            af.u[0] = f2b(q0.x); af.u[1] = f2b(q0.y); af.u[2] = f2b(q0.z); af.u[3] = f2b(q0.w);
            af.u[4] = f2b(q1.x); af.u[5] = f2b(q1.y); af.u[6] = f2b(q1.z); af.u[7] = f2b(q1.w);
            a = af.v;
        } else {
            if (kb < 144) a = *(const bf16x8*)(hb_in + (size_t)arow * 144 + kb);
        }
        #pragma unroll
        for (int nt = 0; nt < 10; ++nt) {
            bf16x8 b = bfrag[(nt * KS + ks) * 64];
            acc[nt] = __builtin_amdgcn_mfma_f32_16x16x32_bf16(a, b, acc[nt], 0, 0, 0);
        }
    }
    #pragma unroll
    for (int r = 0; r < 4; ++r) {
        int orow = tile * 16 + g * 4 + r;
        size_t hbase = (size_t)orow * 144;
        #pragma unroll
        for (int nt = 0; nt < 4; ++nt)
            hb[hbase + nt * 16 + c] = f2b(fmaxf(acc[nt][r] + bia[nt], 0.f));
        #pragma unroll
        for (int nt = 4; nt < 8; ++nt)
            xwb[(size_t)orow * 64 + (nt - 4) * 16 + c] = f2b(acc[nt][r]);
        float p = fmaxf(acc[8][r] + b8, 0.f) * fmaxf(acc[9][r] + b9, 0.f);
        hb[hbase + 128 + c] = f2b(p);
    }
}

// ---------------- CSR build via two-level bucket sort ----------------

// 1) per-(block,bucket) counts; blocks >= NBLK do weight-fragment prep
__global__ __launch_bounds__(256) void k_cnt(
    const int* __restrict__ dst, int* __restrict__ cntM,
    const float* __restrict__ W11, const float* __restrict__ Wc1,
    const float* __restrict__ W12, const float* __restrict__ W13,
    const float* __restrict__ W21, const float* __restrict__ Wc2,
    const float* __restrict__ W22, const float* __restrict__ W23,
    const float* __restrict__ Wf,
    unsigned short* __restrict__ B1, unsigned short* __restrict__ B2,
    unsigned short* __restrict__ Bc) {
    int t = threadIdx.x, blk = blockIdx.x;
    if (blk >= NBLK) {
        // weight prep: B[((nt*KS+ks)*64+lane)*8+i] = W(k, col),
        // k = ks*32 + (lane>>4)*8 + i, col = nt*16 + (lane&15)
        int idx = (blk - NBLK) * 256 + t;
        if (idx < 10240) {                       // B1: KS=2, K=64, 160 cols
            int i = idx & 7, l = (idx >> 3) & 63, ks = (idx >> 9) & 1, nt = idx >> 10;
            int k = ks * 32 + ((l >> 4) << 3) + i;
            int col = nt * 16 + (l & 15);
            float w = (col < 64) ? W11[k * 64 + col]
                    : (col < 128) ? Wc1[k * 64 + col - 64]
                    : (col < 144) ? W12[k * 16 + col - 128]
                                  : W13[k * 16 + col - 144];
            B1[idx] = f2b(w);
        } else if (idx < 10240 + 25600) {        // B2: KS=5, K=144, 160 cols
            int j = idx - 10240;
            int i = j & 7, l = (j >> 3) & 63;
            int ks = (j >> 9) % 5, nt = j / 2560;
            int k = ks * 32 + ((l >> 4) << 3) + i;
            int col = nt * 16 + (l & 15);
            float w = 0.f;
            if (k < 144)
                w = (col < 64) ? W21[k * 64 + col]
                  : (col < 128) ? Wc2[k * 64 + col - 64]
                  : (col < 144) ? W22[k * 16 + col - 128]
                                : W23[k * 16 + col - 144];
            B2[j] = f2b(w);
        } else if (idx < 10240 + 25600 + 20480) { // Bc: KS=5, K=144, 128 cols
            int j = idx - 10240 - 25600;
            int i = j & 7, l = (j >> 3) & 63;
            int ks = (j >> 9) % 5, nt = j / 2560;
            int k = ks * 32 + ((l >> 4) << 3) + i;
            int col = nt * 16 + (l & 15);
            Bc[j] = (k < 144) ? f2b(Wf[k * 128 + col]) : (unsigned short)0;
        }
        return;
    }
    __shared__ int cl[NBUK];
    for (int i = t; i < NBUK; i += 256) cl[i] = 0;
    __syncthreads();
    int e0 = blk * EPB;
    #pragma unroll
    for (int r = 0; r < EPB / 256; ++r) {
        int e = e0 + r * 256 + t;
        if (e < N_EDGES) atomicAdd(&cl[dst[e] >> 8], 1);
    }
    __syncthreads();
    for (int i = t; i < NBUK; i += 256) cntM[blk * NBUK + i] = cl[i];
}

// 2) column scan (per bucket over blocks) in-place -> chunk bases; bucket bases
__global__ void k_colscan(int* __restrict__ cntM, int* __restrict__ ebase) {
    __shared__ int tot[256];
    __shared__ int wsum[4];
    int k = threadIdx.x;
    int run = 0;
    if (k < NBUK) {
        for (int b = 0; b < NBLK; ++b) {
            int c = cntM[b * NBUK + k];
            cntM[b * NBUK + k] = run;
            run += c;
        }
    }
    tot[k] = (k < NBUK) ? run : 0;
    __syncthreads();
    int v = tot[k];
    int lane = k & 63, wid = k >> 6;
    int incl = v;
    #pragma unroll
    for (int d = 1; d < 64; d <<= 1) {
        int u = __shfl_up(incl, d);
        if (lane >= d) incl += u;
    }
    if (lane == 63) wsum[wid] = incl;
    __syncthreads();
    int woff = 0;
    for (int w = 0; w < wid; ++w) woff += wsum[w];
    int excl = incl - v + woff;
    if (k < NBUK) ebase[k] = excl;
    if (k == 255) ebase[NBUK] = incl + woff;   // == N_EDGES
    __syncthreads();
    if (k < NBUK) {
        for (int b = 0; b < NBLK; ++b) cntM[b * NBUK + k] += excl;
    }
}

// 3) MERGED: blocks [0,NBLK) bucketize edges into per-(block,bucket) chunks;
//    blocks [NBLK, NBLK+GD) run dense layer-1 (independent of CSR: reads x/B1).
__global__ __launch_bounds__(256) void k_bd1(
    const int* __restrict__ src, const int* __restrict__ dst,
    const float* __restrict__ ea, const int* __restrict__ cntM,
    uint2* __restrict__ ebuf,
    const float* __restrict__ xf, const unsigned short* __restrict__ B1,
    const float* __restrict__ b11, const float* __restrict__ b12,
    const float* __restrict__ b13,
    unsigned short* __restrict__ hb, unsigned short* __restrict__ xwb) {
    __shared__ int run[NBUK];
    int t = threadIdx.x, blk = blockIdx.x;
    if (blk >= NBLK) {
        int tile = (blk - NBLK) * 4 + (t >> 6);
        dense_body<64>(tile, t & 63, xf, nullptr, B1, b11, b12, b13, hb, xwb);
        return;
    }
    for (int i = t; i < NBUK; i += 256) run[i] = 0;
    __syncthreads();
    int e0 = blk * EPB;
    #pragma unroll
    for (int r = 0; r < EPB / 256; ++r) {
        int e = e0 + r * 256 + t;
        if (e < N_EDGES) {
            int d = dst[e];
            int bk = d >> 8;
            int pos = atomicAdd(&run[bk], 1);
            int p = cntM[blk * NBUK + bk] + pos;
            ebuf[p] = make_uint2((((unsigned)f2b(ea[e])) << 16) | (unsigned)src[e],
                                 (unsigned)(d & 255));
        }
    }
}

// 4) per-bucket: local deg count + scan -> off[]; dst-sorted epack (hot window)
__global__ __launch_bounds__(256) void k_sub(
    const uint2* __restrict__ ebuf, const int* __restrict__ ebase,
    unsigned* __restrict__ epack, int* __restrict__ off) {
    __shared__ int deg[256], lofs[256], cnt[256];
    __shared__ int wsum[4];
    int t = threadIdx.x, b = blockIdx.x;
    deg[t] = 0; cnt[t] = 0;
    __syncthreads();
    int s = ebase[b], e = ebase[b + 1];
    for (int i = s + t; i < e; i += 256) atomicAdd(&deg[ebuf[i].y], 1);
    __syncthreads();
    int v = deg[t];
    int lane = t & 63, wid = t >> 6;
    int incl = v;
    #pragma unroll
    for (int d = 1; d < 64; d <<= 1) {
        int u = __shfl_up(incl, d);
        if (lane >= d) incl += u;
    }
    if (lane == 63) wsum[wid] = incl;
    __syncthreads();
    int woff = 0;
    for (int w = 0; w < wid; ++w) woff += wsum[w];
    lofs[t] = incl - v + woff;
    __syncthreads();
    int gd = b * 256 + t;
    if (gd < N_NODES) off[gd] = s + lofs[t];
    if (b == NBUK - 1 && t == 0) off[N_NODES] = N_EDGES;
    for (int i = s + t; i < e; i += 256) {
        uint2 u = ebuf[i];
        int ld = u.y;
        int pos = atomicAdd(&cnt[ld], 1);
        epack[s + lofs[ld] + pos] = u.x;
    }
}

// ---------------- dense layer-2 (standalone; depends on agg1) ----------------

__global__ __launch_bounds__(256) void k_dense2(
    const unsigned short* __restrict__ hb_in, const unsigned short* __restrict__ B2,
    const float* __restrict__ b21, const float* __restrict__ b22,
    const float* __restrict__ b23,
    unsigned short* __restrict__ hb, unsigned short* __restrict__ xwb) {
    int t = threadIdx.x;
    int tile = blockIdx.x * 4 + (t >> 6);
    dense_body<144>(tile, t & 63, nullptr, hb_in, B2, b21, b22, b23, hb, xwb);
}

// ---------------- aggregation: wave per dst node, 8 edges/iter, 2x unroll ----
// octet q = lane>>3 handles edge b+i*8+q; 8 lanes x uint4 (8 bf16 feats)/edge.

__global__ __launch_bounds__(256) void k_agg(
    const unsigned short* __restrict__ xwb, const int* __restrict__ off,
    const unsigned* __restrict__ epack,
    const float* __restrict__ bc, unsigned short* __restrict__ hb) {
    int node = blockIdx.x * 4 + (threadIdx.x >> 6);
    int lane = threadIdx.x & 63;
    if (node >= N_NODES) return;
    const uint4* xw128 = (const uint4*)xwb;   // 8 uint4 per node row
    int b = off[node], e = off[node + 1];
    int q = lane >> 3, c = lane & 7;
    float a[8] = {0.f, 0.f, 0.f, 0.f, 0.f, 0.f, 0.f, 0.f};
    int i = b + q;
    for (; i + 8 < e; i += 16) {
        unsigned u0 = epack[i];
        unsigned u1 = epack[i + 8];
        uint4 w0 = xw128[(u0 & 0xFFFFu) * 8 + c];
        uint4 w1 = xw128[(u1 & 0xFFFFu) * 8 + c];
        float e0 = b2f((unsigned short)(u0 >> 16));
        float e1 = b2f((unsigned short)(u1 >> 16));
        a[0] += e0 * b2f((unsigned short)(w0.x & 0xFFFFu));
        a[1] += e0 * b2f((unsigned short)(w0.x >> 16));
        a[2] += e0 * b2f((unsigned short)(w0.y & 0xFFFFu));
        a[3] += e0 * b2f((unsigned short)(w0.y >> 16));
        a[4] += e0 * b2f((unsigned short)(w0.z & 0xFFFFu));
        a[5] += e0 * b2f((unsigned short)(w0.z >> 16));
        a[6] += e0 * b2f((unsigned short)(w0.w & 0xFFFFu));
        a[7] += e0 * b2f((unsigned short)(w0.w >> 16));
        a[0] += e1 * b2f((unsigned short)(w1.x & 0xFFFFu));
        a[1] += e1 * b2f((unsigned short)(w1.x >> 16));
        a[2] += e1 * b2f((unsigned short)(w1.y & 0xFFFFu));
        a[3] += e1 * b2f((unsigned short)(w1.y >> 16));
        a[4] += e1 * b2f((unsigned short)(w1.z & 0xFFFFu));
        a[5] += e1 * b2f((unsigned short)(w1.z >> 16));
        a[6] += e1 * b2f((unsigned short)(w1.w & 0xFFFFu));
        a[7] += e1 * b2f((unsigned short)(w1.w >> 16));
    }
    if (i < e) {
        unsigned u0 = epack[i];
        uint4 w0 = xw128[(u0 & 0xFFFFu) * 8 + c];
        float e0 = b2f((unsigned short)(u0 >> 16));
        a[0] += e0 * b2f((unsigned short)(w0.x & 0xFFFFu));
        a[1] += e0 * b2f((unsigned short)(w0.x >> 16));
        a[2] += e0 * b2f((unsigned short)(w0.y & 0xFFFFu));
        a[3] += e0 * b2f((unsigned short)(w0.y >> 16));
        a[4] += e0 * b2f((unsigned short)(w0.z & 0xFFFFu));
        a[5] += e0 * b2f((unsigned short)(w0.z >> 16));
        a[6] += e0 * b2f((unsigned short)(w0.w & 0xFFFFu));
        a[7] += e0 * b2f((unsigned short)(w0.w >> 16));
    }
    #pragma unroll
    for (int j = 0; j < 8; ++j) {
        a[j] += __shfl_xor(a[j], 8);
        a[j] += __shfl_xor(a[j], 16);
        a[j] += __shfl_xor(a[j], 32);
    }
    if (q == 0) {
        int f0 = 8 * c;
        float4 bv0 = *(const float4*)&bc[f0];
        float4 bv1 = *(const float4*)&bc[f0 + 4];
        union { uint4 v; unsigned short u[8]; } o;
        o.u[0] = f2b(fmaxf(a[0] + bv0.x, 0.f));
        o.u[1] = f2b(fmaxf(a[1] + bv0.y, 0.f));
        o.u[2] = f2b(fmaxf(a[2] + bv0.z, 0.f));
        o.u[3] = f2b(fmaxf(a[3] + bv0.w, 0.f));
        o.u[4] = f2b(fmaxf(a[4] + bv1.x, 0.f));
        o.u[5] = f2b(fmaxf(a[5] + bv1.y, 0.f));
        o.u[6] = f2b(fmaxf(a[6] + bv1.z, 0.f));
        o.u[7] = f2b(fmaxf(a[7] + bv1.w, 0.f));
        *(uint4*)&hb[(size_t)node * 144 + 64 + f0] = o.v;
    }
}

// ---------------- classifier MFMA GEMM + log_softmax (no LDS) ----------------

__global__ __launch_bounds__(256) void k_cls(
    const unsigned short* __restrict__ hb,
    const unsigned short* __restrict__ Bw,
    const float* __restrict__ bfb,
    float* __restrict__ out) {
    int t = threadIdx.x;
    int wv = t >> 6, ln = t & 63;
    int tile = blockIdx.x * 4 + wv;
    if (tile >= 3125) return;
    int c = ln & 15, g = ln >> 4;
    int arow = tile * 16 + c;
    float bia[8];
    #pragma unroll
    for (int j = 0; j < 8; ++j) bia[j] = bfb[j * 16 + c];
    f32x4 acc[8];
    #pragma unroll
    for (int nt = 0; nt < 8; ++nt) acc[nt] = f32x4{0.f, 0.f, 0.f, 0.f};

    const bf16x8* bfrag = (const bf16x8*)(Bw + (size_t)ln * 8);
    #pragma unroll
    for (int ks = 0; ks < 5; ++ks) {
        int kb = ks * 32 + g * 8;
        bf16x8 a = {0, 0, 0, 0, 0, 0, 0, 0};
        if (kb < 144) a = *(const bf16x8*)(hb + (size_t)arow * 144 + kb);
        #pragma unroll
        for (int nt = 0; nt < 8; ++nt) {
            bf16x8 b = bfrag[(nt * 5 + ks) * 64];
            acc[nt] = __builtin_amdgcn_mfma_f32_16x16x32_bf16(a, b, acc[nt], 0, 0, 0);
        }
    }
    #pragma unroll
    for (int r = 0; r < 4; ++r) {
        float lg[8];
        #pragma unroll
        for (int nt = 0; nt < 8; ++nt) lg[nt] = acc[nt][r] + bia[nt];
        float m = lg[0];
        #pragma unroll
        for (int nt = 1; nt < 8; ++nt) m = fmaxf(m, lg[nt]);
        #pragma unroll
        for (int o = 1; o < 16; o <<= 1) m = fmaxf(m, __shfl_xor(m, o));
        float s = 0.f;
        #pragma unroll
        for (int nt = 0; nt < 8; ++nt) s += __expf(lg[nt] - m);
        #pragma unroll
        for (int o = 1; o < 16; o <<= 1) s += __shfl_xor(s, o);
        float ls = __logf(s) + m;
        int orow = tile * 16 + g * 4 + r;
        #pragma unroll
        for (int nt = 0; nt < 8; ++nt)
            out[(size_t)orow * 128 + nt * 16 + c] = lg[nt] - ls;
    }
}

// ---------------- launch ----------------

extern "C" void kernel_launch(void* const* d_in, const int* in_sizes, int n_in,
                              void* d_out, int out_size, void* d_ws, size_t ws_size,
                              hipStream_t stream) {
    const float* x   = (const float*)d_in[0];
    const int*   ei  = (const int*)d_in[1];
    const float* ea  = (const float*)d_in[2];
    const float* Wc1 = (const float*)d_in[3];
    const float* bc1 = (const float*)d_in[4];
    const float* Wc2 = (const float*)d_in[5];
    const float* bc2 = (const float*)d_in[6];
    const float* W11 = (const float*)d_in[7];
    const float* b11 = (const float*)d_in[8];
    const float* W12 = (const float*)d_in[9];
    const float* b12 = (const float*)d_in[10];
    const float* W13 = (const float*)d_in[11];
    const float* b13 = (const float*)d_in[12];
    const float* W21 = (const float*)d_in[13];
    const float* b21 = (const float*)d_in[14];
    const float* W22 = (const float*)d_in[15];
    const float* b22 = (const float*)d_in[16];
    const float* W23 = (const float*)d_in[17];
    const float* b23 = (const float*)d_in[18];
    const float* Wf  = (const float*)d_in[19];
    const float* bfb = (const float*)d_in[20];

    const int* esrc = ei;
    const int* edst = ei + N_EDGES;

    // xw bf16 [N][64] lives in d_out (6.4 MB; dead before k_cls writes out).
    unsigned short* xwb = (unsigned short*)d_out;

    // workspace carve (16B-alignment maintained for ebuf/hb/B*):
    int*            off   = (int*)d_ws;                          // 50008 ints
    int*            cntM  = off + 50008;                         // 38416 ints
    int*            ebase = cntM + NBLK * NBUK;                  // 200 ints
    uint2*          ebuf  = (uint2*)(ebase + 200);               // E * 8B
    unsigned*       epack = (unsigned*)(ebuf + N_EDGES);         // E * 4B
    unsigned short* hb    = (unsigned short*)(epack + N_EDGES);  // N*144 bf16
    unsigned short* B1    = hb + (size_t)N_NODES * 144;          // 10240
    unsigned short* B2    = B1 + 10240;                          // 25600
    unsigned short* Bc    = B2 + 25600;                          // 20480

    k_cnt    <<<NBLK + PREP_NB, 256, 0, stream>>>(edst, cntM,
        W11, Wc1, W12, W13, W21, Wc2, W22, W23, Wf, B1, B2, Bc);
    k_colscan<<<1, 256, 0, stream>>>(cntM, ebase);
    k_bd1    <<<NBLK + GD, 256, 0, stream>>>(esrc, edst, ea, cntM, ebuf,
        x, B1, b11, b12, b13, hb, xwb);
    k_sub    <<<NBUK, 256, 0, stream>>>(ebuf, ebase, epack, off);

    k_agg    <<<(N_NODES + 3) / 4, 256, 0, stream>>>(xwb, off, epack, bc1, hb);
    k_dense2 <<<GD, 256, 0, stream>>>(hb, B2, b21, b22, b23, hb, xwb);
    k_agg    <<<(N_NODES + 3) / 4, 256, 0, stream>>>(xwb, off, epack, bc2, hb);
    k_cls    <<<GD, 256, 0, stream>>>(hb, Bc, bfb, (float*)d_out);
}

// Round 14
// 115.853 us; speedup vs baseline: 7.4049x; 1.1824x over previous
//
#include <hip/hip_runtime.h>
#include <hip/hip_bf16.h>

#define N_NODES 50000
#define N_EDGES 800000
#define NBUK 196          // buckets of 256 dst nodes: 196*256 = 50176 >= N
#define NBLK 196          // edge-chunk blocks: 196*4096 = 802816 >= E
#define EPB  4096
#define PREP_NB 220       // (10240+25600+20480+255)/256
#define GD 782            // dense grid: 782*4 wave-tiles >= 3125
#define SUBCAP 4608       // LDS edge-cache cap in k_sub (bucket mean 4081, std ~64)

typedef __attribute__((ext_vector_type(8))) short bf16x8;   // MFMA A/B frag (4 VGPR)
typedef __attribute__((ext_vector_type(4))) float f32x4;    // MFMA C/D frag

// bf16 bit helpers (round-to-nearest-even pack, shift unpack)
__device__ __forceinline__ unsigned short f2b(float f) {
    unsigned u = __float_as_uint(f);
    return (unsigned short)((u + 0x7FFF + ((u >> 16) & 1)) >> 16);
}
__device__ __forceinline__ float b2f(unsigned short b) {
    return __uint_as_float(((unsigned)b) << 16);
}

// ---------------- MFMA dense body ----------------
// Wave owns one 16-row M-tile, 10 n-tiles of 16 cols. B-frags from pre-built
// global layout (L2-broadcast). D-frag (verified m89/m91): col=lane&15,
// row=(lane>>4)*4+reg.

template<int KREAL>
__device__ __forceinline__ void dense_body(
    int tile, int ln,
    const float* __restrict__ xf, const unsigned short* __restrict__ hb_in,
    const unsigned short* __restrict__ Bw,
    const float* __restrict__ b1, const float* __restrict__ b2,
    const float* __restrict__ b3,
    unsigned short* __restrict__ hb, unsigned short* __restrict__ xwb) {
    constexpr int KS = (KREAL + 31) / 32;      // 2 or 5
    if (tile >= 3125) return;                  // 50000 = 3125*16 exact
    int c = ln & 15, g = ln >> 4;
    int arow = tile * 16 + c;
    float bia[4];
    #pragma unroll
    for (int j = 0; j < 4; ++j) bia[j] = b1[j * 16 + c];
    float b8 = b2[c], b9 = b3[c];

    f32x4 acc[10];
    #pragma unroll
    for (int nt = 0; nt < 10; ++nt) acc[nt] = f32x4{0.f, 0.f, 0.f, 0.f};

    const bf16x8* bfrag = (const bf16x8*)(Bw + (size_t)ln * 8);
    #pragma unroll
    for (int ks = 0; ks < KS; ++ks) {
        int kb = ks * 32 + g * 8;
        bf16x8 a = {0, 0, 0, 0, 0, 0, 0, 0};
        if constexpr (KREAL == 64) {
            const float* rp = xf + (size_t)arow * 64 + kb;
            float4 q0 = *(const float4*)rp;
            float4 q1 = *(const float4*)(rp + 4);
            union { bf16x8 v; unsigned short u[8]; } af;
            af.u[0] = f2b(q0.x); af.u[1] = f2b(q0.y); af.u[2] = f2b(q0.z); af.u[3] = f2b(q0.w);
            af.u[4] = f2b(q1.x); af.u[5] = f2b(q1.y); af.u[6] = f2b(q1.z); af.u[7] = f2b(q1.w);
            a = af.v;
        } else {
            if (kb < 144) a = *(const bf16x8*)(hb_in + (size_t)arow * 144 + kb);
        }
        #pragma unroll
        for (int nt = 0; nt < 10; ++nt) {
            bf16x8 b = bfrag[(nt * KS + ks) * 64];
            acc[nt] = __builtin_amdgcn_mfma_f32_16x16x32_bf16(a, b, acc[nt], 0, 0, 0);
        }
    }
    #pragma unroll
    for (int r = 0; r < 4; ++r) {
        int orow = tile * 16 + g * 4 + r;
        size_t hbase = (size_t)orow * 144;
        #pragma unroll
        for (int nt = 0; nt < 4; ++nt)
            hb[hbase + nt * 16 + c] = f2b(fmaxf(acc[nt][r] + bia[nt], 0.f));
        #pragma unroll
        for (int nt = 4; nt < 8; ++nt)
            xwb[(size_t)orow * 64 + (nt - 4) * 16 + c] = f2b(acc[nt][r]);
        float p = fmaxf(acc[8][r] + b8, 0.f) * fmaxf(acc[9][r] + b9, 0.f);
        hb[hbase + 128 + c] = f2b(p);
    }
}

// ---------------- CSR build via two-level bucket sort ----------------

// 1) per-(block,bucket) counts, TRANSPOSED (cntM[bucket*NBLK + blk]) so the
//    per-bucket scan reads contiguous rows; blocks >= NBLK do weight prep.
__global__ __launch_bounds__(256) void k_cnt(
    const int* __restrict__ dst, int* __restrict__ cntM,
    const float* __restrict__ W11, const float* __restrict__ Wc1,
    const float* __restrict__ W12, const float* __restrict__ W13,
    const float* __restrict__ W21, const float* __restrict__ Wc2,
    const float* __restrict__ W22, const float* __restrict__ W23,
    const float* __restrict__ Wf,
    unsigned short* __restrict__ B1, unsigned short* __restrict__ B2,
    unsigned short* __restrict__ Bc) {
    int t = threadIdx.x, blk = blockIdx.x;
    if (blk >= NBLK) {
        // weight prep: B[((nt*KS+ks)*64+lane)*8+i] = W(k, col),
        // k = ks*32 + (lane>>4)*8 + i, col = nt*16 + (lane&15)
        int idx = (blk - NBLK) * 256 + t;
        if (idx < 10240) {                       // B1: KS=2, K=64, 160 cols
            int i = idx & 7, l = (idx >> 3) & 63, ks = (idx >> 9) & 1, nt = idx >> 10;
            int k = ks * 32 + ((l >> 4) << 3) + i;
            int col = nt * 16 + (l & 15);
            float w = (col < 64) ? W11[k * 64 + col]
                    : (col < 128) ? Wc1[k * 64 + col - 64]
                    : (col < 144) ? W12[k * 16 + col - 128]
                                  : W13[k * 16 + col - 144];
            B1[idx] = f2b(w);
        } else if (idx < 10240 + 25600) {        // B2: KS=5, K=144, 160 cols
            int j = idx - 10240;
            int i = j & 7, l = (j >> 3) & 63;
            int ks = (j >> 9) % 5, nt = j / 2560;
            int k = ks * 32 + ((l >> 4) << 3) + i;
            int col = nt * 16 + (l & 15);
            float w = 0.f;
            if (k < 144)
                w = (col < 64) ? W21[k * 64 + col]
                  : (col < 128) ? Wc2[k * 64 + col - 64]
                  : (col < 144) ? W22[k * 16 + col - 128]
                                : W23[k * 16 + col - 144];
            B2[j] = f2b(w);
        } else if (idx < 10240 + 25600 + 20480) { // Bc: KS=5, K=144, 128 cols
            int j = idx - 10240 - 25600;
            int i = j & 7, l = (j >> 3) & 63;
            int ks = (j >> 9) % 5, nt = j / 2560;
            int k = ks * 32 + ((l >> 4) << 3) + i;
            int col = nt * 16 + (l & 15);
            Bc[j] = (k < 144) ? f2b(Wf[k * 128 + col]) : (unsigned short)0;
        }
        return;
    }
    __shared__ int cl[NBUK];
    for (int i = t; i < NBUK; i += 256) cl[i] = 0;
    __syncthreads();
    int e0 = blk * EPB;
    #pragma unroll
    for (int r = 0; r < EPB / 256; ++r) {
        int e = e0 + r * 256 + t;
        if (e < N_EDGES) atomicAdd(&cl[dst[e] >> 8], 1);
    }
    __syncthreads();
    for (int i = t; i < NBUK; i += 256) cntM[i * NBLK + blk] = cl[i];
}

// 2a) per-bucket scan over blocks (wave per bucket, int4 rows). Leaves cntM
//     as within-bucket exclusive offsets; writes bucket totals.
__global__ __launch_bounds__(256) void k_colA(int* __restrict__ cntM,
                                              int* __restrict__ btot) {
    int t = threadIdx.x;
    int k = blockIdx.x * 4 + (t >> 6);   // 49 blocks * 4 waves = 196 buckets
    int lane = t & 63;
    int* row = cntM + k * NBLK;          // 196 ints, 16B-aligned (784 = 49*16)
    int4 v = {0, 0, 0, 0};
    if (lane < 49) v = *(const int4*)&row[lane * 4];
    int s = v.x + v.y + v.z + v.w;
    int incl = s;
    #pragma unroll
    for (int d = 1; d < 64; d <<= 1) {
        int u = __shfl_up(incl, d);
        if (lane >= d) incl += u;
    }
    int excl = incl - s;
    if (lane < 49) {
        int4 o;
        o.x = excl;
        o.y = excl + v.x;
        o.z = excl + v.x + v.y;
        o.w = excl + v.x + v.y + v.z;
        *(int4*)&row[lane * 4] = o;
    }
    if (lane == 63) btot[k] = incl;      // bucket total
}

// 2b) scan 196 bucket totals -> ebase[0..196]
__global__ void k_colB(const int* __restrict__ btot, int* __restrict__ ebase) {
    __shared__ int wsum[4];
    int t = threadIdx.x;
    int v = (t < NBUK) ? btot[t] : 0;
    int lane = t & 63, wid = t >> 6;
    int incl = v;
    #pragma unroll
    for (int d = 1; d < 64; d <<= 1) {
        int u = __shfl_up(incl, d);
        if (lane >= d) incl += u;
    }
    if (lane == 63) wsum[wid] = incl;
    __syncthreads();
    int woff = 0;
    for (int w = 0; w < wid; ++w) woff += wsum[w];
    if (t < NBUK) ebase[t] = incl - v + woff;
    if (t == 255) ebase[NBUK] = incl + woff;   // == N_EDGES
}

// 3) MERGED: blocks [0,NBLK) bucketize edges into per-(block,bucket) chunks;
//    blocks [NBLK, NBLK+GD) run dense layer-1 (independent: reads x/B1).
__global__ __launch_bounds__(256) void k_bd1(
    const int* __restrict__ src, const int* __restrict__ dst,
    const float* __restrict__ ea, const int* __restrict__ cntM,
    const int* __restrict__ ebase, uint2* __restrict__ ebuf,
    const float* __restrict__ xf, const unsigned short* __restrict__ B1,
    const float* __restrict__ b11, const float* __restrict__ b12,
    const float* __restrict__ b13,
    unsigned short* __restrict__ hb, unsigned short* __restrict__ xwb) {
    __shared__ int base[NBUK];
    __shared__ int run[NBUK];
    int t = threadIdx.x, blk = blockIdx.x;
    if (blk >= NBLK) {
        int tile = (blk - NBLK) * 4 + (t >> 6);
        dense_body<64>(tile, t & 63, xf, nullptr, B1, b11, b12, b13, hb, xwb);
        return;
    }
    for (int i = t; i < NBUK; i += 256) {
        base[i] = ebase[i] + cntM[i * NBLK + blk];
        run[i] = 0;
    }
    __syncthreads();
    int e0 = blk * EPB;
    #pragma unroll
    for (int r = 0; r < EPB / 256; ++r) {
        int e = e0 + r * 256 + t;
        if (e < N_EDGES) {
            int d = dst[e];
            int bk = d >> 8;
            int pos = atomicAdd(&run[bk], 1);
            ebuf[base[bk] + pos] =
                make_uint2((((unsigned)f2b(ea[e])) << 16) | (unsigned)src[e],
                           (unsigned)(d & 255));
        }
    }
}

// 4) per-bucket: LDS-cached edges; deg count + scan -> off[]; dst-sorted epack
__global__ __launch_bounds__(256) void k_sub(
    const uint2* __restrict__ ebuf, const int* __restrict__ ebase,
    unsigned* __restrict__ epack, int* __restrict__ off) {
    __shared__ uint2 ebl[SUBCAP];                 // 36864 B
    __shared__ int deg[256], lofs[256], cnt[256];
    __shared__ int wsum[4];
    int t = threadIdx.x, b = blockIdx.x;
    deg[t] = 0; cnt[t] = 0;
    __syncthreads();
    int s = ebase[b], e = ebase[b + 1];
    int n = e - s;
    bool lds = (n <= SUBCAP);
    if (lds) {
        for (int i = t; i < n; i += 256) {
            uint2 u = ebuf[s + i];
            ebl[i] = u;
            atomicAdd(&deg[u.y], 1);
        }
    } else {
        for (int i = s + t; i < e; i += 256) atomicAdd(&deg[ebuf[i].y], 1);
    }
    __syncthreads();
    int v = deg[t];
    int lane = t & 63, wid = t >> 6;
    int incl = v;
    #pragma unroll
    for (int d = 1; d < 64; d <<= 1) {
        int u = __shfl_up(incl, d);
        if (lane >= d) incl += u;
    }
    if (lane == 63) wsum[wid] = incl;
    __syncthreads();
    int woff = 0;
    for (int w = 0; w < wid; ++w) woff += wsum[w];
    lofs[t] = incl - v + woff;
    __syncthreads();
    int gd = b * 256 + t;
    if (gd < N_NODES) off[gd] = s + lofs[t];
    if (b == NBUK - 1 && t == 0) off[N_NODES] = N_EDGES;
    if (lds) {
        for (int i = t; i < n; i += 256) {
            uint2 u = ebl[i];
            int ld = u.y;
            int pos = atomicAdd(&cnt[ld], 1);
            epack[s + lofs[ld] + pos] = u.x;
        }
    } else {
        for (int i = s + t; i < e; i += 256) {
            uint2 u = ebuf[i];
            int ld = u.y;
            int pos = atomicAdd(&cnt[ld], 1);
            epack[s + lofs[ld] + pos] = u.x;
        }
    }
}

// ---------------- dense layer-2 (standalone; depends on agg1) ----------------

__global__ __launch_bounds__(256) void k_dense2(
    const unsigned short* __restrict__ hb_in, const unsigned short* __restrict__ B2,
    const float* __restrict__ b21, const float* __restrict__ b22,
    const float* __restrict__ b23,
    unsigned short* __restrict__ hb, unsigned short* __restrict__ xwb) {
    int t = threadIdx.x;
    int tile = blockIdx.x * 4 + (t >> 6);
    dense_body<144>(tile, t & 63, nullptr, hb_in, B2, b21, b22, b23, hb, xwb);
}

// ---------------- aggregation: wave per dst node, 8 edges/iter, 2x unroll ----

__global__ __launch_bounds__(256) void k_agg(
    const unsigned short* __restrict__ xwb, const int* __restrict__ off,
    const unsigned* __restrict__ epack,
    const float* __restrict__ bc, unsigned short* __restrict__ hb) {
    int node = blockIdx.x * 4 + (threadIdx.x >> 6);
    int lane = threadIdx.x & 63;
    if (node >= N_NODES) return;
    const uint4* xw128 = (const uint4*)xwb;   // 8 uint4 per node row
    int b = off[node], e = off[node + 1];
    int q = lane >> 3, c = lane & 7;
    float a[8] = {0.f, 0.f, 0.f, 0.f, 0.f, 0.f, 0.f, 0.f};
    int i = b + q;
    for (; i + 8 < e; i += 16) {
        unsigned u0 = epack[i];
        unsigned u1 = epack[i + 8];
        uint4 w0 = xw128[(u0 & 0xFFFFu) * 8 + c];
        uint4 w1 = xw128[(u1 & 0xFFFFu) * 8 + c];
        float e0 = b2f((unsigned short)(u0 >> 16));
        float e1 = b2f((unsigned short)(u1 >> 16));
        a[0] += e0 * b2f((unsigned short)(w0.x & 0xFFFFu));
        a[1] += e0 * b2f((unsigned short)(w0.x >> 16));
        a[2] += e0 * b2f((unsigned short)(w0.y & 0xFFFFu));
        a[3] += e0 * b2f((unsigned short)(w0.y >> 16));
        a[4] += e0 * b2f((unsigned short)(w0.z & 0xFFFFu));
        a[5] += e0 * b2f((unsigned short)(w0.z >> 16));
        a[6] += e0 * b2f((unsigned short)(w0.w & 0xFFFFu));
        a[7] += e0 * b2f((unsigned short)(w0.w >> 16));
        a[0] += e1 * b2f((unsigned short)(w1.x & 0xFFFFu));
        a[1] += e1 * b2f((unsigned short)(w1.x >> 16));
        a[2] += e1 * b2f((unsigned short)(w1.y & 0xFFFFu));
        a[3] += e1 * b2f((unsigned short)(w1.y >> 16));
        a[4] += e1 * b2f((unsigned short)(w1.z & 0xFFFFu));
        a[5] += e1 * b2f((unsigned short)(w1.z >> 16));
        a[6] += e1 * b2f((unsigned short)(w1.w & 0xFFFFu));
        a[7] += e1 * b2f((unsigned short)(w1.w >> 16));
    }
    if (i < e) {
        unsigned u0 = epack[i];
        uint4 w0 = xw128[(u0 & 0xFFFFu) * 8 + c];
        float e0 = b2f((unsigned short)(u0 >> 16));
        a[0] += e0 * b2f((unsigned short)(w0.x & 0xFFFFu));
        a[1] += e0 * b2f((unsigned short)(w0.x >> 16));
        a[2] += e0 * b2f((unsigned short)(w0.y & 0xFFFFu));
        a[3] += e0 * b2f((unsigned short)(w0.y >> 16));
        a[4] += e0 * b2f((unsigned short)(w0.z & 0xFFFFu));
        a[5] += e0 * b2f((unsigned short)(w0.z >> 16));
        a[6] += e0 * b2f((unsigned short)(w0.w & 0xFFFFu));
        a[7] += e0 * b2f((unsigned short)(w0.w >> 16));
    }
    #pragma unroll
    for (int j = 0; j < 8; ++j) {
        a[j] += __shfl_xor(a[j], 8);
        a[j] += __shfl_xor(a[j], 16);
        a[j] += __shfl_xor(a[j], 32);
    }
    if (q == 0) {
        int f0 = 8 * c;
        float4 bv0 = *(const float4*)&bc[f0];
        float4 bv1 = *(const float4*)&bc[f0 + 4];
        union { uint4 v; unsigned short u[8]; } o;
        o.u[0] = f2b(fmaxf(a[0] + bv0.x, 0.f));
        o.u[1] = f2b(fmaxf(a[1] + bv0.y, 0.f));
        o.u[2] = f2b(fmaxf(a[2] + bv0.z, 0.f));
        o.u[3] = f2b(fmaxf(a[3] + bv0.w, 0.f));
        o.u[4] = f2b(fmaxf(a[4] + bv1.x, 0.f));
        o.u[5] = f2b(fmaxf(a[5] + bv1.y, 0.f));
        o.u[6] = f2b(fmaxf(a[6] + bv1.z, 0.f));
        o.u[7] = f2b(fmaxf(a[7] + bv1.w, 0.f));
        *(uint4*)&hb[(size_t)node * 144 + 64 + f0] = o.v;
    }
}

// ---------------- classifier MFMA GEMM + log_softmax (no LDS) ----------------

__global__ __launch_bounds__(256) void k_cls(
    const unsigned short* __restrict__ hb,
    const unsigned short* __restrict__ Bw,
    const float* __restrict__ bfb,
    float* __restrict__ out) {
    int t = threadIdx.x;
    int wv = t >> 6, ln = t & 63;
    int tile = blockIdx.x * 4 + wv;
    if (tile >= 3125) return;
    int c = ln & 15, g = ln >> 4;
    int arow = tile * 16 + c;
    float bia[8];
    #pragma unroll
    for (int j = 0; j < 8; ++j) bia[j] = bfb[j * 16 + c];
    f32x4 acc[8];
    #pragma unroll
    for (int nt = 0; nt < 8; ++nt) acc[nt] = f32x4{0.f, 0.f, 0.f, 0.f};

    const bf16x8* bfrag = (const bf16x8*)(Bw + (size_t)ln * 8);
    #pragma unroll
    for (int ks = 0; ks < 5; ++ks) {
        int kb = ks * 32 + g * 8;
        bf16x8 a = {0, 0, 0, 0, 0, 0, 0, 0};
        if (kb < 144) a = *(const bf16x8*)(hb + (size_t)arow * 144 + kb);
        #pragma unroll
        for (int nt = 0; nt < 8; ++nt) {
            bf16x8 b = bfrag[(nt * 5 + ks) * 64];
            acc[nt] = __builtin_amdgcn_mfma_f32_16x16x32_bf16(a, b, acc[nt], 0, 0, 0);
        }
    }
    #pragma unroll
    for (int r = 0; r < 4; ++r) {
        float lg[8];
        #pragma unroll
        for (int nt = 0; nt < 8; ++nt) lg[nt] = acc[nt][r] + bia[nt];
        float m = lg[0];
        #pragma unroll
        for (int nt = 1; nt < 8; ++nt) m = fmaxf(m, lg[nt]);
        #pragma unroll
        for (int o = 1; o < 16; o <<= 1) m = fmaxf(m, __shfl_xor(m, o));
        float s = 0.f;
        #pragma unroll
        for (int nt = 0; nt < 8; ++nt) s += __expf(lg[nt] - m);
        #pragma unroll
        for (int o = 1; o < 16; o <<= 1) s += __shfl_xor(s, o);
        float ls = __logf(s) + m;
        int orow = tile * 16 + g * 4 + r;
        #pragma unroll
        for (int nt = 0; nt < 8; ++nt)
            out[(size_t)orow * 128 + nt * 16 + c] = lg[nt] - ls;
    }
}

// ---------------- launch ----------------

extern "C" void kernel_launch(void* const* d_in, const int* in_sizes, int n_in,
                              void* d_out, int out_size, void* d_ws, size_t ws_size,
                              hipStream_t stream) {
    const float* x   = (const float*)d_in[0];
    const int*   ei  = (const int*)d_in[1];
    const float* ea  = (const float*)d_in[2];
    const float* Wc1 = (const float*)d_in[3];
    const float* bc1 = (const float*)d_in[4];
    const float* Wc2 = (const float*)d_in[5];
    const float* bc2 = (const float*)d_in[6];
    const float* W11 = (const float*)d_in[7];
    const float* b11 = (const float*)d_in[8];
    const float* W12 = (const float*)d_in[9];
    const float* b12 = (const float*)d_in[10];
    const float* W13 = (const float*)d_in[11];
    const float* b13 = (const float*)d_in[12];
    const float* W21 = (const float*)d_in[13];
    const float* b21 = (const float*)d_in[14];
    const float* W22 = (const float*)d_in[15];
    const float* b22 = (const float*)d_in[16];
    const float* W23 = (const float*)d_in[17];
    const float* b23 = (const float*)d_in[18];
    const float* Wf  = (const float*)d_in[19];
    const float* bfb = (const float*)d_in[20];

    const int* esrc = ei;
    const int* edst = ei + N_EDGES;

    // xw bf16 [N][64] lives in d_out (6.4 MB; dead before k_cls writes out).
    unsigned short* xwb = (unsigned short*)d_out;

    // workspace carve (16B-alignment maintained for ebuf/hb/B*):
    int*            off   = (int*)d_ws;                          // 50008 ints
    int*            cntM  = off + 50008;                         // 38416 ints
    int*            ebase = cntM + NBLK * NBUK;                  // 200 ints
    int*            btot  = ebase + 200;                         // 196 (+pad 4)
    uint2*          ebuf  = (uint2*)(btot + 200);                // E * 8B
    unsigned*       epack = (unsigned*)(ebuf + N_EDGES);         // E * 4B
    unsigned short* hb    = (unsigned short*)(epack + N_EDGES);  // N*144 bf16
    unsigned short* B1    = hb + (size_t)N_NODES * 144;          // 10240
    unsigned short* B2    = B1 + 10240;                          // 25600
    unsigned short* Bc    = B2 + 25600;                          // 20480

    k_cnt    <<<NBLK + PREP_NB, 256, 0, stream>>>(edst, cntM,
        W11, Wc1, W12, W13, W21, Wc2, W22, W23, Wf, B1, B2, Bc);
    k_colA   <<<49, 256, 0, stream>>>(cntM, btot);
    k_colB   <<<1, 256, 0, stream>>>(btot, ebase);
    k_bd1    <<<NBLK + GD, 256, 0, stream>>>(esrc, edst, ea, cntM, ebase, ebuf,
        x, B1, b11, b12, b13, hb, xwb);
    k_sub    <<<NBUK, 256, 0, stream>>>(ebuf, ebase, epack, off);

    k_agg    <<<(N_NODES + 3) / 4, 256, 0, stream>>>(xwb, off, epack, bc1, hb);
    k_dense2 <<<GD, 256, 0, stream>>>(hb, B2, b21, b22, b23, hb, xwb);
    k_agg    <<<(N_NODES + 3) / 4, 256, 0, stream>>>(xwb, off, epack, bc2, hb);
    k_cls    <<<GD, 256, 0, stream>>>(hb, Bc, bfb, (float*)d_out);
}